// Round 2
// baseline (2009.089 us; speedup 1.0000x reference)
//
#include <hip/hip_runtime.h>
#include <hip/hip_bf16.h>

typedef __hip_bfloat16 bf16;
typedef __attribute__((ext_vector_type(8))) __bf16 bf16x8;
typedef __attribute__((ext_vector_type(4))) float f32x4;

__device__ __forceinline__ float b2f(bf16 v){ return __bfloat162float(v); }
__device__ __forceinline__ bf16  f2b(float v){ return __float2bfloat16(v); }

template<typename T> __device__ __forceinline__ float ldf(const T* p, size_t i);
template<> __device__ __forceinline__ float ldf<float>(const float* p, size_t i){ return p[i]; }
template<> __device__ __forceinline__ float ldf<bf16 >(const bf16*  p, size_t i){ return b2f(p[i]); }

template<typename T> __device__ __forceinline__ void stf(T* p, size_t i, float v);
template<> __device__ __forceinline__ void stf<float>(float* p, size_t i, float v){ p[i] = v; }
template<> __device__ __forceinline__ void stf<bf16 >(bf16*  p, size_t i, float v){ p[i] = f2b(v); }

#define NATM 32
#define RECON_OFF 262144          // 2*2048*64 elements (mu, logvar)
#define RL_OFF    5898240         // + 2048*2752

// ---------------- K0: dtype detect ----------------
// bf16 arrays: every u16 is a bf16 of N(0,1): exp field in [110,132].
// f32 arrays: odd halves look bf16-ish, even halves have uniform exponents.
__global__ __launch_bounds__(64) void k_detect(const void* emb, int* flag)
{
    __shared__ int cnt[64];
    const int t = threadIdx.x;
    const unsigned short* p = (const unsigned short*)emb;
    int c = 0;
    for (int i = t; i < 256; i += 64){
        int e = (p[i] >> 7) & 0xFF;
        c += (e >= 110 && e <= 132) ? 1 : 0;
    }
    cnt[t] = c;
    __syncthreads();
    if (t == 0){
        int s = 0;
        for (int i = 0; i < 64; i++) s += cnt[i];
        *flag = (s >= 200) ? 1 : 0;   // 1 = bf16, 0 = f32
    }
}

// ---------------- K1: atom encoder + mean pool -> gbuf[b][128] ----------------
template<typename T>
__device__ __forceinline__ void enc_impl(
    const int* elements, const T* coords, const T* emb,
    const T* w1, const T* b1, const T* w2, const T* b2c,
    const T* w3, const T* b3, float* gbuf, char* smem)
{
    float (*af)[19]   = (float(*)[19])(smem);            // 2432 B
    float (*h1)[256]  = (float(*)[256])(smem + 2432);    // 32768 B
    float (*h2s)[128] = (float(*)[128])(smem + 35200);   // 16384 B
    float* hsum       = (float*)(smem + 51584);          // 512 B
    const int b = blockIdx.x, t = threadIdx.x;

    for (int idx = t; idx < NATM*19; idx += 256){
        int n = idx/19, f = idx - n*19;
        af[n][f] = (f < 16) ? ldf(emb, (size_t)elements[b*NATM+n]*16 + f)
                            : ldf(coords, (size_t)(b*NATM+n)*3 + (f-16));
    }
    __syncthreads();
    {
        float wc[19];
        #pragma unroll
        for (int f=0; f<19; f++) wc[f] = ldf(w1, f*256 + t);
        float bb = ldf(b1, t);
        for (int n=0; n<NATM; n++){
            float a = bb;
            #pragma unroll
            for (int f=0; f<19; f++) a += af[n][f]*wc[f];
            h1[n][t] = fmaxf(a, 0.f);
        }
    }
    __syncthreads();
    {
        const int j = t & 127, half = t >> 7;
        float bb = ldf(b2c, j);
        float acc[16];
        #pragma unroll
        for (int n=0;n<16;n++) acc[n] = bb;
        for (int k=0;k<256;k+=4){
            float wa = ldf(w2, (k+0)*128+j);
            float wb = ldf(w2, (k+1)*128+j);
            float wcv= ldf(w2, (k+2)*128+j);
            float wd = ldf(w2, (k+3)*128+j);
            #pragma unroll
            for (int n=0;n<16;n++){
                float4 hv = *(const float4*)(&h1[half*16+n][k]);
                acc[n] += hv.x*wa + hv.y*wb + hv.z*wcv + hv.w*wd;
            }
        }
        #pragma unroll
        for (int n=0;n<16;n++) h2s[half*16+n][j] = fmaxf(acc[n], 0.f);
    }
    __syncthreads();
    if (t < 128){
        float s = 0.f;
        for (int n=0;n<NATM;n++) s += h2s[n][t];
        hsum[t] = s;
    }
    __syncthreads();
    if (t < 128){
        float a = 0.f;
        for (int k=0;k<128;k++) a += hsum[k]*ldf(w3, k*128+t);
        gbuf[b*128+t] = a*(1.f/32.f) + ldf(b3, t);
    }
}

__global__ __launch_bounds__(256) void k_encoder(
    const int* flag, const int* elements, const void* coords, const void* emb,
    const void* w1, const void* b1, const void* w2, const void* b2,
    const void* w3, const void* b3, float* gbuf)
{
    __shared__ __align__(16) char smem[52096];
    if (*flag) enc_impl<bf16>(elements,(const bf16*)coords,(const bf16*)emb,
        (const bf16*)w1,(const bf16*)b1,(const bf16*)w2,(const bf16*)b2,
        (const bf16*)w3,(const bf16*)b3, gbuf, smem);
    else       enc_impl<float>(elements,(const float*)coords,(const float*)emb,
        (const float*)w1,(const float*)b1,(const float*)w2,(const float*)b2,
        (const float*)w3,(const float*)b3, gbuf, smem);
}

// ---------------- K2: lattice enc + mu/logvar/z + recon_lattice ----------------
template<typename T>
__device__ __forceinline__ void lat_impl(
    const T* lattice, const T* eps,
    const T* lw1, const T* lb1, const T* lw2, const T* lb2,
    const T* muw, const T* mub, const T* lvw, const T* lvb,
    const T* dw1, const T* db1, const T* dw2, const T* db2,
    const float* gbuf, float* zbuf, void* d_out, char* smem)
{
    float* comb = (float*)(smem);          // 192
    float* lat  = (float*)(smem + 768);    // 16
    float* l1   = (float*)(smem + 832);    // 64
    float* zz   = (float*)(smem + 1088);   // 64
    float* r1   = (float*)(smem + 1344);   // 64
    T* out_mu = (T*)d_out;
    T* out_lv = out_mu + 131072;
    T* out_rl = out_mu + RL_OFF;
    const int b = blockIdx.x, t = threadIdx.x;
    comb[t]    = gbuf[b*128 + t];
    comb[64+t] = gbuf[b*128 + 64 + t];
    if (t < 9) lat[t] = ldf(lattice, b*9 + t);
    __syncthreads();
    {
        float a = ldf(lb1, t);
        #pragma unroll
        for (int f=0; f<9; f++) a += lat[f]*ldf(lw1, f*64+t);
        l1[t] = fmaxf(a, 0.f);
    }
    __syncthreads();
    {
        float a = ldf(lb2, t);
        for (int k=0;k<64;k++) a += l1[k]*ldf(lw2, k*64+t);
        comb[128+t] = a;
    }
    __syncthreads();
    float mu = ldf(mub, t), lv = ldf(lvb, t);
    for (int k=0;k<192;k++){
        float c = comb[k];
        mu += c*ldf(muw, k*64+t);
        lv += c*ldf(lvw, k*64+t);
    }
    float z = mu + ldf(eps, b*64+t)*expf(0.5f*lv);
    stf(out_mu, (size_t)b*64+t, mu);
    stf(out_lv, (size_t)b*64+t, lv);
    zbuf[b*64+t] = z;
    zz[t] = z;
    __syncthreads();
    {
        float a = ldf(db1, t);
        for (int k=0;k<64;k++) a += zz[k]*ldf(dw1, k*64+t);
        r1[t] = fmaxf(a, 0.f);
    }
    __syncthreads();
    if (t < 9){
        float a = ldf(db2, t);
        for (int k=0;k<64;k++) a += r1[k]*ldf(dw2, k*9+t);
        stf(out_rl, (size_t)b*9+t, a);
    }
}

__global__ __launch_bounds__(64) void k_latent(
    const int* flag, const void* lattice, const void* eps,
    const void* lw1, const void* lb1, const void* lw2, const void* lb2,
    const void* muw, const void* mub, const void* lvw, const void* lvb,
    const void* dw1, const void* db1, const void* dw2, const void* db2,
    const float* gbuf, float* zbuf, void* d_out)
{
    __shared__ __align__(16) char smem[1600];
    if (*flag) lat_impl<bf16>((const bf16*)lattice,(const bf16*)eps,
        (const bf16*)lw1,(const bf16*)lb1,(const bf16*)lw2,(const bf16*)lb2,
        (const bf16*)muw,(const bf16*)mub,(const bf16*)lvw,(const bf16*)lvb,
        (const bf16*)dw1,(const bf16*)db1,(const bf16*)dw2,(const bf16*)db2,
        gbuf, zbuf, d_out, smem);
    else       lat_impl<float>((const float*)lattice,(const float*)eps,
        (const float*)lw1,(const float*)lb1,(const float*)lw2,(const float*)lb2,
        (const float*)muw,(const float*)mub,(const float*)lvw,(const float*)lvb,
        (const float*)dw1,(const float*)db1,(const float*)dw2,(const float*)db2,
        gbuf, zbuf, d_out, smem);
}

// ---------------- K3: dec_w1 + convT1 + convT2 -> Amat (bf16, [b][8192]) ----------------
template<typename T>
__device__ __forceinline__ void conv_impl(
    const float* zbuf, const T* comp,
    const T* dw1, const T* db1, const T* c1w, const T* c1b,
    const T* c2w, const T* c2b, bf16* Amat, char* smem)
{
    float* zc        = (float*)(smem);            // 147 (pad 160)
    float (*d0s)[8]  = (float(*)[8])(smem + 640);
    float (*c1s)[64] = (float(*)[64])(smem + 2688);
    bf16* w2s        = (bf16*)(smem + 10880);     // 13824 bf16
    const int b = blockIdx.x, t = threadIdx.x;
    for (int i=t; i<16*32*27; i+=256) w2s[i] = f2b(ldf(c2w, i));
    if (t < 147) zc[t] = (t < 64) ? zbuf[b*64+t] : ldf(comp, b*83 + (t-64));
    __syncthreads();
    #pragma unroll
    for (int jj=0; jj<2; jj++){
        int j = t + (jj<<8);
        float a = ldf(db1, j);
        for (int k=0;k<147;k++) a += zc[k]*ldf(dw1, k*512+j);
        d0s[j>>3][j&7] = a;
    }
    __syncthreads();
    {   // convT1: (64,2,2,2) -> relu (32,4,4,4)
        const int o = t>>3;
        const float bias = ldf(c1b, o);
        const T* wb = c1w + o*64*27;
        for (int u=0; u<8; u++){
            int sp = (t&7) + (u<<3);
            int zd = sp>>4, zh = (sp>>2)&3, zw = sp&3;
            float acc = bias;
            for (int kd=0;kd<3;kd++){
                int qd = zd+kd-1; if (qd<0 || (qd&1) || qd>=4) continue; int td=qd>>1;
                for (int kh=0;kh<3;kh++){
                    int qh = zh+kh-1; if (qh<0 || (qh&1) || qh>=4) continue; int th=qh>>1;
                    for (int kw=0;kw<3;kw++){
                        int qw = zw+kw-1; if (qw<0 || (qw&1) || qw>=4) continue; int tw=qw>>1;
                        const int koff = kd*9+kh*3+kw;
                        const int spi = td*4+th*2+tw;
                        float s = 0.f;
                        #pragma unroll 8
                        for (int i=0;i<64;i++) s += ldf(wb, i*27+koff)*d0s[i][spi];
                        acc += s;
                    }
                }
            }
            c1s[o][sp] = fmaxf(acc, 0.f);
        }
    }
    __syncthreads();
    {   // convT2: (32,4,4,4) -> relu (16,8,8,8) -> Amat bf16
        const int o = t>>4;
        const float bias = ldf(c2b, o);
        for (int u=0; u<32; u++){
            int sp = (t&15) + (u<<4);
            int zd = sp>>6, zh=(sp>>3)&7, zw=sp&7;
            float acc = bias;
            for (int kd=0;kd<3;kd++){
                int qd = zd+kd-1; if (qd<0 || (qd&1) || qd>=8) continue; int td=qd>>1;
                for (int kh=0;kh<3;kh++){
                    int qh = zh+kh-1; if (qh<0 || (qh&1) || qh>=8) continue; int th=qh>>1;
                    for (int kw=0;kw<3;kw++){
                        int qw = zw+kw-1; if (qw<0 || (qw&1) || qw>=8) continue; int tw=qw>>1;
                        const int koff = kd*9+kh*3+kw;
                        const int spi = td*16+th*4+tw;
                        const int wbase = (o*32)*27 + koff;
                        float s = 0.f;
                        #pragma unroll 8
                        for (int i=0;i<32;i++) s += b2f(w2s[wbase + i*27])*c1s[i][spi];
                        acc += s;
                    }
                }
            }
            Amat[(size_t)b*8192 + o*512 + sp] = f2b(fmaxf(acc, 0.f));
        }
    }
}

__global__ __launch_bounds__(256) void k_conv(
    const int* flag, const float* zbuf, const void* comp,
    const void* dw1, const void* db1, const void* c1w, const void* c1b,
    const void* c2w, const void* c2b, bf16* Amat)
{
    __shared__ __align__(16) char smem[38528];
    if (*flag) conv_impl<bf16>(zbuf,(const bf16*)comp,(const bf16*)dw1,(const bf16*)db1,
        (const bf16*)c1w,(const bf16*)c1b,(const bf16*)c2w,(const bf16*)c2b, Amat, smem);
    else       conv_impl<float>(zbuf,(const float*)comp,(const float*)dw1,(const float*)db1,
        (const float*)c1w,(const float*)c1b,(const float*)c2w,(const float*)c2b, Amat, smem);
}

// ---------------- K4: raw = Amat(2048x8192) @ dec_w2(8192x2752) + bias -> out_recon ----------------
template<typename T> struct BStage;
template<> struct BStage<bf16>{
    static __device__ __forceinline__ void go(const bf16* p, bf16* v8){
        union{ int4 q; bf16 e[8]; } u; u.q = *(const int4*)p;
        #pragma unroll
        for (int j=0;j<8;j++) v8[j] = u.e[j];
    }
};
template<> struct BStage<float>{
    static __device__ __forceinline__ void go(const float* p, bf16* v8){
        float4 a = *(const float4*)p, b = *(const float4*)(p+4);
        v8[0]=f2b(a.x); v8[1]=f2b(a.y); v8[2]=f2b(a.z); v8[3]=f2b(a.w);
        v8[4]=f2b(b.x); v8[5]=f2b(b.y); v8[6]=f2b(b.z); v8[7]=f2b(b.w);
    }
};

__device__ __forceinline__ bf16x8 readBfrag(const bf16 (*Bs)[42], int n, int k0){
    union { bf16x8 v; unsigned int u[4]; } r;
    const unsigned int* p = (const unsigned int*)(&Bs[n][k0]);   // 4B-aligned (42*2*n + 2*k0, k0 mult of 8)
    r.u[0]=p[0]; r.u[1]=p[1]; r.u[2]=p[2]; r.u[3]=p[3];
    return r.v;
}

template<typename T>
__device__ __forceinline__ void gemm_impl(
    const bf16* A, const T* B, const T* bias, void* d_out, char* smem)
{
    bf16 (*As)[40] = (bf16(*)[40])(smem);             // 128x40 = 10240 B
    bf16 (*Bs)[42] = (bf16(*)[42])(smem + 10240);     // 64x42  = 5376 B
    T* out_recon = (T*)d_out + RECON_OFF;
    const int t = threadIdx.x;
    const int bm = blockIdx.x << 7;
    const int bn = blockIdx.y << 6;
    const int w = t >> 6, lane = t & 63;
    const int ml = lane & 15, mq = lane >> 4;
    f32x4 acc[2][4];
    #pragma unroll
    for (int i=0;i<2;i++)
        #pragma unroll
        for (int j=0;j<4;j++) acc[i][j] = (f32x4){0.f,0.f,0.f,0.f};

    const int sm = t >> 2;              // 0..63   (A staging)
    const int sk = (t & 3) << 3;        // 0,8,16,24
    const int kk = t >> 3;              // 0..31   (B staging)
    const int nn = (t & 7) << 3;        // 0,8,...,56

    for (int kt = 0; kt < 8192; kt += 32){
        __syncthreads();
        {
            int4 v0 = *(const int4*)(A + (size_t)(bm + sm     )*8192 + kt + sk);
            int4 v1 = *(const int4*)(A + (size_t)(bm + sm + 64)*8192 + kt + sk);
            *(int4*)(&As[sm][sk])    = v0;
            *(int4*)(&As[sm+64][sk]) = v1;
            bf16 bv[8];
            BStage<T>::go(B + (size_t)(kt + kk)*2752 + bn + nn, bv);
            #pragma unroll
            for (int j=0;j<8;j++) Bs[nn+j][kk] = bv[j];   // transpose to [n][k]
        }
        __syncthreads();
        bf16x8 a0 = *(const bf16x8*)(&As[(w<<5) + ml     ][mq<<3]);
        bf16x8 a1 = *(const bf16x8*)(&As[(w<<5) + 16 + ml][mq<<3]);
        bf16x8 b0 = readBfrag(Bs, ml,      mq<<3);
        bf16x8 b1 = readBfrag(Bs, 16 + ml, mq<<3);
        bf16x8 b2 = readBfrag(Bs, 32 + ml, mq<<3);
        bf16x8 b3 = readBfrag(Bs, 48 + ml, mq<<3);
        acc[0][0] = __builtin_amdgcn_mfma_f32_16x16x32_bf16(a0,b0,acc[0][0],0,0,0);
        acc[0][1] = __builtin_amdgcn_mfma_f32_16x16x32_bf16(a0,b1,acc[0][1],0,0,0);
        acc[0][2] = __builtin_amdgcn_mfma_f32_16x16x32_bf16(a0,b2,acc[0][2],0,0,0);
        acc[0][3] = __builtin_amdgcn_mfma_f32_16x16x32_bf16(a0,b3,acc[0][3],0,0,0);
        acc[1][0] = __builtin_amdgcn_mfma_f32_16x16x32_bf16(a1,b0,acc[1][0],0,0,0);
        acc[1][1] = __builtin_amdgcn_mfma_f32_16x16x32_bf16(a1,b1,acc[1][1],0,0,0);
        acc[1][2] = __builtin_amdgcn_mfma_f32_16x16x32_bf16(a1,b2,acc[1][2],0,0,0);
        acc[1][3] = __builtin_amdgcn_mfma_f32_16x16x32_bf16(a1,b3,acc[1][3],0,0,0);
    }
    #pragma unroll
    for (int nt=0; nt<4; nt++){
        const int col = bn + (nt<<4) + ml;
        const int atom = col / 86;
        const int f = col - atom*86;
        const float bv = ldf(bias, col);
        #pragma unroll
        for (int mt=0; mt<2; mt++){
            #pragma unroll
            for (int r=0; r<4; r++){
                const int row = bm + (w<<5) + (mt<<4) + (mq<<2) + r;
                float v = acc[mt][nt][r] + bv;
                if (f >= 83) v = 1.f/(1.f + expf(-v));   // init_coords = sigmoid(raw)
                stf(out_recon, (size_t)row*2752 + col, v);
            }
        }
    }
}

__global__ __launch_bounds__(256) void k_gemm(
    const int* flag, const bf16* A, const void* B, const void* bias, void* d_out)
{
    __shared__ __align__(16) char smem[15616];
    if (*flag) gemm_impl<bf16>(A, (const bf16*)B, (const bf16*)bias, d_out, smem);
    else       gemm_impl<float>(A, (const float*)B, (const float*)bias, d_out, smem);
}

// ---------------- K5: argmax, GAT1, GAT2, coords out ----------------
template<typename T>
__device__ __forceinline__ void gat_impl(
    const T* emb, const T* g1w, const T* g1b, const T* g1as, const T* g1ad,
    const T* g2w, const T* g2b, const T* g2as, const T* g2ad,
    void* d_out, char* smem)
{
    float* ic    = (float*)(smem);            // 96
    int*   amaxs = (int*)  (smem + 384);      // 32
    float* hs    = (float*)(smem + 512);      // 6144  P3-P6
    float* xs    = (float*)(smem + 25088);    // 6144  P6-P7 (also lg staging P0-P1)
    float* U     = (float*)(smem + 49664);    // 3072  node(P2-P3)/att(P5-P6)/att2(P9-P10)
    float* sa    = (float*)(smem + 61952);    // 96
    float* da    = (float*)(smem + 62336);    // 96
    float* hh    = (float*)(smem + 62720);    // 96
    float* s2    = (float*)(smem + 63104);    // 32
    float* d2    = (float*)(smem + 63232);    // 32
    float* lg    = xs;                        // 2656 logits staging
    float* node  = U;
    float* att   = U;
    float* att2  = U;

    T* out_recon = (T*)d_out + RECON_OFF;
    const int b = blockIdx.x, t = threadIdx.x;

    // P0: stage logits (f32) + init_coords
    for (int i=t; i<2656; i+=256){
        int n = i/83, f = i - n*83;
        lg[i] = ldf(out_recon, (size_t)b*2752 + n*86 + f);
    }
    if (t < 96){
        int n = t/3, c = t - 3*(t/3);
        ic[t] = ldf(out_recon, (size_t)b*2752 + n*86 + 83 + c);
    }
    __syncthreads();
    // P1: argmax (first max wins, as jnp.argmax)
    if (t < 32){
        const float* lp = lg + t*83;
        float best = lp[0]; int bi = 0;
        for (int f=1; f<83; f++){ float v = lp[f]; if (v > best){ best=v; bi=f; } }
        amaxs[t] = bi;
    }
    __syncthreads();
    // P2: node = [emb[argmax], init_coords]
    for (int i=t; i<608; i+=256){
        int n = i/19, f = i - n*19;
        node[n*19+f] = (f<16) ? ldf(emb, amaxs[n]*16+f) : ic[n*3 + (f-16)];
    }
    __syncthreads();
    // P3: hs = node @ g1w  (32 x 192)
    if (t < 192){
        float wc[19];
        #pragma unroll
        for (int f=0;f<19;f++) wc[f] = ldf(g1w, f*192+t);
        for (int n=0;n<32;n++){
            float a = 0.f;
            #pragma unroll
            for (int f=0;f<19;f++) a += node[n*19+f]*wc[f];
            hs[n*192+t] = a;
        }
    }
    __syncthreads();
    // P4: attention src/dst
    if (t < 96){
        int n = t/3, hd = t - 3*(t/3);
        float s=0.f, d=0.f;
        for (int c=0;c<64;c++){
            float hv = hs[n*192 + hd*64 + c];
            s += hv*ldf(g1as, hd*64+c);
            d += hv*ldf(g1ad, hd*64+c);
        }
        sa[n*3+hd] = s; da[n*3+hd] = d;
    }
    __syncthreads();
    // P5: att[i][hd][:] = softmax_j(lrelu(d_i + s_j))
    if (t < 96){
        int i = t/3, hd = t - 3*(t/3);
        float di = da[i*3+hd];
        float ev[32]; float m = -1e30f;
        for (int j=0;j<32;j++){
            float e = di + sa[j*3+hd];
            e = (e > 0.f) ? e : 0.2f*e;
            ev[j] = e; m = fmaxf(m, e);
        }
        float ssum = 0.f;
        for (int j=0;j<32;j++){ float p = expf(ev[j]-m); ev[j]=p; ssum += p; }
        float inv = 1.f/ssum;
        for (int j=0;j<32;j++) att[(i*3+hd)*32 + j] = ev[j]*inv;
    }
    __syncthreads();
    // P6: xs = elu(att @ hs + g1b)
    if (t < 192){
        int hd = t >> 6;
        float bb = ldf(g1b, t);
        for (int i=0;i<32;i++){
            float a = 0.f;
            for (int j=0;j<32;j++) a += att[(i*3+hd)*32 + j]*hs[j*192+t];
            a += bb;
            xs[i*192+t] = (a > 0.f) ? a : (expf(a) - 1.f);
        }
    }
    __syncthreads();
    // P7: hh = xs @ g2w (32 x 3)
    if (t < 96){
        int n = t/3, c = t - 3*(t/3);
        float a = 0.f;
        for (int f=0;f<192;f++) a += xs[n*192+f]*ldf(g2w, f*3+c);
        hh[n*3+c] = a;
    }
    __syncthreads();
    // P8: s2/d2
    if (t < 32){
        float s=0.f,d=0.f;
        #pragma unroll
        for (int c=0;c<3;c++){ s += hh[t*3+c]*ldf(g2as,c); d += hh[t*3+c]*ldf(g2ad,c); }
        s2[t]=s; d2[t]=d;
    }
    __syncthreads();
    // P9: att2
    if (t < 32){
        float di = d2[t];
        float ev[32]; float m=-1e30f;
        for (int j=0;j<32;j++){
            float e = di + s2[j]; e = (e>0.f)?e:0.2f*e; ev[j]=e; m=fmaxf(m,e);
        }
        float ssum=0.f;
        for (int j=0;j<32;j++){ float p=expf(ev[j]-m); ev[j]=p; ssum+=p; }
        float inv = 1.f/ssum;
        for (int j=0;j<32;j++) att2[t*32+j] = ev[j]*inv;
    }
    __syncthreads();
    // P10: adj = tanh(att2 @ hh + g2b)*0.1 ; coords = mod(ic+adj, 1)
    if (t < 96){
        int i = t/3, c = t - 3*(t/3);
        float a = 0.f;
        for (int j=0;j<32;j++) a += att2[i*32+j]*hh[j*3+c];
        a += ldf(g2b, c);
        float adj = tanhf(a)*0.1f;
        float cr = ic[i*3+c] + adj;
        cr -= floorf(cr);
        stf(out_recon, (size_t)b*2752 + i*86 + 83 + c, cr);
    }
}

__global__ __launch_bounds__(256) void k_gat(
    const int* flag, const void* emb,
    const void* g1w, const void* g1b, const void* g1as, const void* g1ad,
    const void* g2w, const void* g2b, const void* g2as, const void* g2ad,
    void* d_out)
{
    __shared__ __align__(16) char smem[63360];
    if (*flag) gat_impl<bf16>((const bf16*)emb,(const bf16*)g1w,(const bf16*)g1b,
        (const bf16*)g1as,(const bf16*)g1ad,(const bf16*)g2w,(const bf16*)g2b,
        (const bf16*)g2as,(const bf16*)g2ad, d_out, smem);
    else       gat_impl<float>((const float*)emb,(const float*)g1w,(const float*)g1b,
        (const float*)g1as,(const float*)g1ad,(const float*)g2w,(const float*)g2b,
        (const float*)g2as,(const float*)g2ad, d_out, smem);
}

extern "C" void kernel_launch(void* const* d_in, const int* in_sizes, int n_in,
                              void* d_out, int out_size, void* d_ws, size_t ws_size,
                              hipStream_t stream)
{
    (void)in_sizes; (void)n_in; (void)out_size; (void)ws_size;
    char* ws = (char*)d_ws;
    bf16*  Amat = (bf16*)(ws);                 // 33,554,432 B
    float* gbuf = (float*)(ws + 33554432);     //  1,048,576 B
    float* zbuf = (float*)(ws + 34603008);     //    524,288 B
    int*   flag = (int*)  (ws + 35127296);     // total ~35.1 MB

    k_detect<<<1, 64, 0, stream>>>(d_in[5], flag);
    k_encoder<<<2048, 256, 0, stream>>>(flag, (const int*)d_in[0], d_in[1], d_in[5],
        d_in[6], d_in[7], d_in[8], d_in[9], d_in[10], d_in[11], gbuf);
    k_latent<<<2048, 64, 0, stream>>>(flag, d_in[2], d_in[4],
        d_in[12], d_in[13], d_in[14], d_in[15],
        d_in[16], d_in[17], d_in[18], d_in[19],
        d_in[28], d_in[29], d_in[30], d_in[31],
        gbuf, zbuf, d_out);
    k_conv<<<2048, 256, 0, stream>>>(flag, zbuf, d_in[3],
        d_in[20], d_in[21], d_in[22], d_in[23], d_in[24], d_in[25], Amat);
    k_gemm<<<dim3(16,43), 256, 0, stream>>>(flag, Amat, d_in[26], d_in[27], d_out);
    k_gat<<<2048, 256, 0, stream>>>(flag, d_in[5],
        d_in[32], d_in[33], d_in[34], d_in[35],
        d_in[36], d_in[37], d_in[38], d_in[39], d_out);
}

// Round 3
// 888.035 us; speedup vs baseline: 2.2624x; 2.2624x over previous
//
#include <hip/hip_runtime.h>
#include <hip/hip_bf16.h>

typedef __hip_bfloat16 bf16;
typedef __attribute__((ext_vector_type(8))) __bf16 bf16x8;
typedef __attribute__((ext_vector_type(4))) float f32x4;

__device__ __forceinline__ float b2f(bf16 v){ return __bfloat162float(v); }
__device__ __forceinline__ bf16  f2b(float v){ return __float2bfloat16(v); }

template<typename T> __device__ __forceinline__ float ldf(const T* p, size_t i);
template<> __device__ __forceinline__ float ldf<float>(const float* p, size_t i){ return p[i]; }
template<> __device__ __forceinline__ float ldf<bf16 >(const bf16*  p, size_t i){ return b2f(p[i]); }

template<typename T> __device__ __forceinline__ void stf(T* p, size_t i, float v);
template<> __device__ __forceinline__ void stf<float>(float* p, size_t i, float v){ p[i] = v; }
template<> __device__ __forceinline__ void stf<bf16 >(bf16*  p, size_t i, float v){ p[i] = f2b(v); }

#define NATM 32
#define RECON_OFF 262144          // 2*2048*64 elements (mu, logvar)
#define RL_OFF    5898240         // + 2048*2752

// ---------------- K0: dtype detect ----------------
__global__ __launch_bounds__(64) void k_detect(const void* emb, int* flag)
{
    __shared__ int cnt[64];
    const int t = threadIdx.x;
    const unsigned short* p = (const unsigned short*)emb;
    int c = 0;
    for (int i = t; i < 256; i += 64){
        int e = (p[i] >> 7) & 0xFF;
        c += (e >= 110 && e <= 132) ? 1 : 0;
    }
    cnt[t] = c;
    __syncthreads();
    if (t == 0){
        int s = 0;
        for (int i = 0; i < 64; i++) s += cnt[i];
        *flag = (s >= 200) ? 1 : 0;   // 1 = bf16, 0 = f32
    }
}

// ---------------- K1: atom encoder + mean pool -> gbuf[b][128] ----------------
template<typename T>
__device__ __forceinline__ void enc_impl(
    const int* elements, const T* coords, const T* emb,
    const T* w1, const T* b1, const T* w2, const T* b2c,
    const T* w3, const T* b3, float* gbuf, char* smem)
{
    float (*af)[19]   = (float(*)[19])(smem);
    float (*h1)[256]  = (float(*)[256])(smem + 2432);
    float (*h2s)[128] = (float(*)[128])(smem + 35200);
    float* hsum       = (float*)(smem + 51584);
    const int b = blockIdx.x, t = threadIdx.x;

    for (int idx = t; idx < NATM*19; idx += 256){
        int n = idx/19, f = idx - n*19;
        af[n][f] = (f < 16) ? ldf(emb, (size_t)elements[b*NATM+n]*16 + f)
                            : ldf(coords, (size_t)(b*NATM+n)*3 + (f-16));
    }
    __syncthreads();
    {
        float wc[19];
        #pragma unroll
        for (int f=0; f<19; f++) wc[f] = ldf(w1, f*256 + t);
        float bb = ldf(b1, t);
        for (int n=0; n<NATM; n++){
            float a = bb;
            #pragma unroll
            for (int f=0; f<19; f++) a += af[n][f]*wc[f];
            h1[n][t] = fmaxf(a, 0.f);
        }
    }
    __syncthreads();
    {
        const int j = t & 127, half = t >> 7;
        float bb = ldf(b2c, j);
        float acc[16];
        #pragma unroll
        for (int n=0;n<16;n++) acc[n] = bb;
        for (int k=0;k<256;k+=4){
            float wa = ldf(w2, (k+0)*128+j);
            float wb = ldf(w2, (k+1)*128+j);
            float wcv= ldf(w2, (k+2)*128+j);
            float wd = ldf(w2, (k+3)*128+j);
            #pragma unroll
            for (int n=0;n<16;n++){
                float4 hv = *(const float4*)(&h1[half*16+n][k]);
                acc[n] += hv.x*wa + hv.y*wb + hv.z*wcv + hv.w*wd;
            }
        }
        #pragma unroll
        for (int n=0;n<16;n++) h2s[half*16+n][j] = fmaxf(acc[n], 0.f);
    }
    __syncthreads();
    if (t < 128){
        float s = 0.f;
        for (int n=0;n<NATM;n++) s += h2s[n][t];
        hsum[t] = s;
    }
    __syncthreads();
    if (t < 128){
        float a = 0.f;
        for (int k=0;k<128;k++) a += hsum[k]*ldf(w3, k*128+t);
        gbuf[b*128+t] = a*(1.f/32.f) + ldf(b3, t);
    }
}

__global__ __launch_bounds__(256) void k_encoder(
    const int* flag, const int* elements, const void* coords, const void* emb,
    const void* w1, const void* b1, const void* w2, const void* b2,
    const void* w3, const void* b3, float* gbuf)
{
    __shared__ __align__(16) char smem[52096];
    if (*flag) enc_impl<bf16>(elements,(const bf16*)coords,(const bf16*)emb,
        (const bf16*)w1,(const bf16*)b1,(const bf16*)w2,(const bf16*)b2,
        (const bf16*)w3,(const bf16*)b3, gbuf, smem);
    else       enc_impl<float>(elements,(const float*)coords,(const float*)emb,
        (const float*)w1,(const float*)b1,(const float*)w2,(const float*)b2,
        (const float*)w3,(const float*)b3, gbuf, smem);
}

// ---------------- K2: lattice enc + mu/logvar/z + recon_lattice (+ zc row) ----------------
template<typename T>
__device__ __forceinline__ void lat_impl(
    const T* lattice, const T* eps, const T* comp,
    const T* lw1, const T* lb1, const T* lw2, const T* lb2,
    const T* muw, const T* mub, const T* lvw, const T* lvb,
    const T* dw1, const T* db1, const T* dw2, const T* db2,
    const float* gbuf, float* zbuf, bf16* zc, void* d_out, char* smem)
{
    float* comb = (float*)(smem);
    float* lat  = (float*)(smem + 768);
    float* l1   = (float*)(smem + 832);
    float* zz   = (float*)(smem + 1088);
    float* r1   = (float*)(smem + 1344);
    T* out_mu = (T*)d_out;
    T* out_lv = out_mu + 131072;
    T* out_rl = out_mu + RL_OFF;
    const int b = blockIdx.x, t = threadIdx.x;
    comb[t]    = gbuf[b*128 + t];
    comb[64+t] = gbuf[b*128 + 64 + t];
    if (t < 9) lat[t] = ldf(lattice, b*9 + t);
    __syncthreads();
    {
        float a = ldf(lb1, t);
        #pragma unroll
        for (int f=0; f<9; f++) a += lat[f]*ldf(lw1, f*64+t);
        l1[t] = fmaxf(a, 0.f);
    }
    __syncthreads();
    {
        float a = ldf(lb2, t);
        for (int k=0;k<64;k++) a += l1[k]*ldf(lw2, k*64+t);
        comb[128+t] = a;
    }
    __syncthreads();
    float mu = ldf(mub, t), lv = ldf(lvb, t);
    for (int k=0;k<192;k++){
        float c = comb[k];
        mu += c*ldf(muw, k*64+t);
        lv += c*ldf(lvw, k*64+t);
    }
    float z = mu + ldf(eps, b*64+t)*expf(0.5f*lv);
    stf(out_mu, (size_t)b*64+t, mu);
    stf(out_lv, (size_t)b*64+t, lv);
    zbuf[b*64+t] = z;
    zz[t] = z;
    __syncthreads();
    if (zc){
        for (int i=t; i<160; i+=64){
            float v = (i<64) ? zz[i] : ((i<147) ? ldf(comp, b*83 + (i-64)) : 0.f);
            zc[(size_t)b*160 + i] = f2b(v);
        }
    }
    {
        float a = ldf(db1, t);
        for (int k=0;k<64;k++) a += zz[k]*ldf(dw1, k*64+t);
        r1[t] = fmaxf(a, 0.f);
    }
    __syncthreads();
    if (t < 9){
        float a = ldf(db2, t);
        for (int k=0;k<64;k++) a += r1[k]*ldf(dw2, k*9+t);
        stf(out_rl, (size_t)b*9+t, a);
    }
}

__global__ __launch_bounds__(64) void k_latent(
    const int* flag, const void* lattice, const void* eps, const void* comp,
    const void* lw1, const void* lb1, const void* lw2, const void* lb2,
    const void* muw, const void* mub, const void* lvw, const void* lvb,
    const void* dw1, const void* db1, const void* dw2, const void* db2,
    const float* gbuf, float* zbuf, bf16* zc, void* d_out)
{
    __shared__ __align__(16) char smem[1600];
    if (*flag) lat_impl<bf16>((const bf16*)lattice,(const bf16*)eps,(const bf16*)comp,
        (const bf16*)lw1,(const bf16*)lb1,(const bf16*)lw2,(const bf16*)lb2,
        (const bf16*)muw,(const bf16*)mub,(const bf16*)lvw,(const bf16*)lvb,
        (const bf16*)dw1,(const bf16*)db1,(const bf16*)dw2,(const bf16*)db2,
        gbuf, zbuf, zc, d_out, smem);
    else       lat_impl<float>((const float*)lattice,(const float*)eps,(const float*)comp,
        (const float*)lw1,(const float*)lb1,(const float*)lw2,(const float*)lb2,
        (const float*)muw,(const float*)mub,(const float*)lvw,(const float*)lvb,
        (const float*)dw1,(const float*)db1,(const float*)dw2,(const float*)db2,
        gbuf, zbuf, zc, d_out, smem);
}

// ---------------- K-prep: biases->f32, BtW1 (dec_w1 transposed, K-padded) ----------------
// biasf layout (floats): [0..511]=dec_b1, [512..543]=ct1_b, [544..559]=ct2_b
template<typename T>
__device__ __forceinline__ void prep_impl(
    const T* db1, const T* c1b, const T* c2b, const T* dw1,
    float* biasf, bf16* BtW1)
{
    const int gt = blockIdx.x*256 + threadIdx.x;
    const int gs = gridDim.x*256;
    for (int i = gt; i < 560; i += gs){
        float v = (i < 512) ? ldf(db1, i) : (i < 544 ? ldf(c1b, i-512) : ldf(c2b, i-544));
        biasf[i] = v;
    }
    for (int e = gt; e < 512*160; e += gs){
        int n = e/160, k = e - n*160;
        BtW1[e] = f2b((k < 147) ? ldf(dw1, (size_t)k*512 + n) : 0.f);
    }
}

__global__ __launch_bounds__(256) void k_prep(
    const int* flag, const void* db1, const void* c1b, const void* c2b,
    const void* dw1, float* biasf, bf16* BtW1)
{
    if (*flag) prep_impl<bf16>((const bf16*)db1,(const bf16*)c1b,(const bf16*)c2b,
        (const bf16*)dw1, biasf, BtW1);
    else       prep_impl<float>((const float*)db1,(const float*)c1b,(const float*)c2b,
        (const float*)dw1, biasf, BtW1);
}

// ---------------- K-exp1: Wc1T[n=o*64+spo][k=i*8+spi] from ct1_w (32,64,3,3,3) ----------------
template<typename T>
__device__ __forceinline__ void expWc1_impl(const T* w, bf16* Wc1T)
{
    const int t = threadIdx.x;
    const int n = blockIdx.x*4 + (t >> 6);      // 2048 rows
    const int k0 = (t & 63) << 3;               // 512 cols / 8
    const int o = n >> 6, spo = n & 63;
    const int zd = spo >> 4, zh = (spo >> 2) & 3, zw = spo & 3;
    bf16 v8[8];
    #pragma unroll
    for (int j = 0; j < 8; j++){
        int k = k0 + j;
        int i = k >> 3, sp = k & 7;
        int td = sp >> 2, th = (sp >> 1) & 1, tw = sp & 1;
        int kd = 2*td + 1 - zd, kh = 2*th + 1 - zh, kw = 2*tw + 1 - zw;
        float v = 0.f;
        if (kd >= 0 && kd < 3 && kh >= 0 && kh < 3 && kw >= 0 && kw < 3)
            v = ldf(w, (size_t)(o*64 + i)*27 + kd*9 + kh*3 + kw);
        v8[j] = f2b(v);
    }
    *(int4*)(&Wc1T[(size_t)n*512 + k0]) = *(int4*)v8;
}

__global__ __launch_bounds__(256) void k_expWc1(const int* flag, const void* w, bf16* Wc1T)
{
    if (*flag) expWc1_impl<bf16>((const bf16*)w, Wc1T);
    else       expWc1_impl<float>((const float*)w, Wc1T);
}

// ---------------- K-exp2: Wc2T[n=o*512+spo][k=i*64+spi] from ct2_w (16,32,3,3,3) ----------------
template<typename T>
__device__ __forceinline__ void expWc2_impl(const T* w, bf16* Wc2T)
{
    const int n = blockIdx.x;                    // 8192 rows
    const int k0 = threadIdx.x << 3;             // 2048 cols / 8
    const int o = n >> 9, spo = n & 511;
    const int zd = spo >> 6, zh = (spo >> 3) & 7, zw = spo & 7;
    bf16 v8[8];
    #pragma unroll
    for (int j = 0; j < 8; j++){
        int k = k0 + j;
        int i = k >> 6, sp = k & 63;
        int td = sp >> 4, th = (sp >> 2) & 3, tw = sp & 3;
        int kd = 2*td + 1 - zd, kh = 2*th + 1 - zh, kw = 2*tw + 1 - zw;
        float v = 0.f;
        if (kd >= 0 && kd < 3 && kh >= 0 && kh < 3 && kw >= 0 && kw < 3)
            v = ldf(w, (size_t)(o*32 + i)*27 + kd*9 + kh*3 + kw);
        v8[j] = f2b(v);
    }
    *(int4*)(&Wc2T[(size_t)n*2048 + k0]) = *(int4*)v8;
}

__global__ __launch_bounds__(256) void k_expWc2(const int* flag, const void* w, bf16* Wc2T)
{
    if (*flag) expWc2_impl<bf16>((const bf16*)w, Wc2T);
    else       expWc2_impl<float>((const float*)w, Wc2T);
}

// ---------------- Generic MFMA GEMM: C[M][N] = act(A[M][K] @ Bt[N][K]^T + bias) ----------------
// grid (M/128, N/64), 256 threads. K mult of 32, N mult of 64. lda==K.
template<typename OutT, int ACT>   // ACT: 0 none, 1 relu
__global__ __launch_bounds__(256) void k_gemm_g(
    const bf16* __restrict__ A, const bf16* __restrict__ Bt, int K,
    const float* __restrict__ biasf, int bshift,
    OutT* __restrict__ C, int ldc)
{
    __shared__ __align__(16) bf16 As[128][40];
    __shared__ __align__(16) bf16 Bs[64][40];
    const int t = threadIdx.x;
    const int bm = blockIdx.x << 7;
    const int bn = blockIdx.y << 6;
    const int w = t >> 6, lane = t & 63;
    const int ml = lane & 15, mq = lane >> 4;
    f32x4 acc[2][4];
    #pragma unroll
    for (int i=0;i<2;i++)
        #pragma unroll
        for (int j=0;j<4;j++) acc[i][j] = (f32x4){0.f,0.f,0.f,0.f};

    const int sm = t >> 2;              // 0..63
    const int sk = (t & 3) << 3;        // 0,8,16,24
    for (int kt = 0; kt < K; kt += 32){
        __syncthreads();
        {
            int4 v0 = *(const int4*)(A  + (size_t)(bm + sm     )*K + kt + sk);
            int4 v1 = *(const int4*)(A  + (size_t)(bm + sm + 64)*K + kt + sk);
            int4 vb = *(const int4*)(Bt + (size_t)(bn + sm     )*K + kt + sk);
            *(int4*)(&As[sm][sk])    = v0;
            *(int4*)(&As[sm+64][sk]) = v1;
            *(int4*)(&Bs[sm][sk])    = vb;
        }
        __syncthreads();
        bf16x8 a0 = *(const bf16x8*)(&As[(w<<5) + ml     ][mq<<3]);
        bf16x8 a1 = *(const bf16x8*)(&As[(w<<5) + 16 + ml][mq<<3]);
        bf16x8 b0 = *(const bf16x8*)(&Bs[ml     ][mq<<3]);
        bf16x8 b1 = *(const bf16x8*)(&Bs[16 + ml][mq<<3]);
        bf16x8 b2 = *(const bf16x8*)(&Bs[32 + ml][mq<<3]);
        bf16x8 b3 = *(const bf16x8*)(&Bs[48 + ml][mq<<3]);
        acc[0][0] = __builtin_amdgcn_mfma_f32_16x16x32_bf16(a0,b0,acc[0][0],0,0,0);
        acc[0][1] = __builtin_amdgcn_mfma_f32_16x16x32_bf16(a0,b1,acc[0][1],0,0,0);
        acc[0][2] = __builtin_amdgcn_mfma_f32_16x16x32_bf16(a0,b2,acc[0][2],0,0,0);
        acc[0][3] = __builtin_amdgcn_mfma_f32_16x16x32_bf16(a0,b3,acc[0][3],0,0,0);
        acc[1][0] = __builtin_amdgcn_mfma_f32_16x16x32_bf16(a1,b0,acc[1][0],0,0,0);
        acc[1][1] = __builtin_amdgcn_mfma_f32_16x16x32_bf16(a1,b1,acc[1][1],0,0,0);
        acc[1][2] = __builtin_amdgcn_mfma_f32_16x16x32_bf16(a1,b2,acc[1][2],0,0,0);
        acc[1][3] = __builtin_amdgcn_mfma_f32_16x16x32_bf16(a1,b3,acc[1][3],0,0,0);
    }
    #pragma unroll
    for (int nt=0; nt<4; nt++){
        const int col = bn + (nt<<4) + ml;
        const float bv = biasf[col >> bshift];
        #pragma unroll
        for (int mt=0; mt<2; mt++){
            #pragma unroll
            for (int r=0; r<4; r++){
                const int row = bm + (w<<5) + (mt<<4) + (mq<<2) + r;
                float v = acc[mt][nt][r] + bv;
                if (ACT == 1) v = fmaxf(v, 0.f);
                stf(C, (size_t)row*ldc + col, v);
            }
        }
    }
}

// ---------------- K3 (fallback only): dec_w1 + convT1 + convT2 -> Amat ----------------
template<typename T>
__device__ __forceinline__ void conv_impl(
    const float* zbuf, const T* comp,
    const T* dw1, const T* db1, const T* c1w, const T* c1b,
    const T* c2w, const T* c2b, bf16* Amat, char* smem)
{
    float* zc        = (float*)(smem);
    float (*d0s)[8]  = (float(*)[8])(smem + 640);
    float (*c1s)[64] = (float(*)[64])(smem + 2688);
    bf16* w2s        = (bf16*)(smem + 10880);
    const int b = blockIdx.x, t = threadIdx.x;
    for (int i=t; i<16*32*27; i+=256) w2s[i] = f2b(ldf(c2w, i));
    if (t < 147) zc[t] = (t < 64) ? zbuf[b*64+t] : ldf(comp, b*83 + (t-64));
    __syncthreads();
    #pragma unroll
    for (int jj=0; jj<2; jj++){
        int j = t + (jj<<8);
        float a = ldf(db1, j);
        for (int k=0;k<147;k++) a += zc[k]*ldf(dw1, k*512+j);
        d0s[j>>3][j&7] = a;
    }
    __syncthreads();
    {
        const int o = t>>3;
        const float bias = ldf(c1b, o);
        const T* wb = c1w + o*64*27;
        for (int u=0; u<8; u++){
            int sp = (t&7) + (u<<3);
            int zd = sp>>4, zh = (sp>>2)&3, zw = sp&3;
            float acc = bias;
            for (int kd=0;kd<3;kd++){
                int qd = zd+kd-1; if (qd<0 || (qd&1) || qd>=4) continue; int td=qd>>1;
                for (int kh=0;kh<3;kh++){
                    int qh = zh+kh-1; if (qh<0 || (qh&1) || qh>=4) continue; int th=qh>>1;
                    for (int kw=0;kw<3;kw++){
                        int qw = zw+kw-1; if (qw<0 || (qw&1) || qw>=4) continue; int tw=qw>>1;
                        const int koff = kd*9+kh*3+kw;
                        const int spi = td*4+th*2+tw;
                        float s = 0.f;
                        #pragma unroll 8
                        for (int i=0;i<64;i++) s += ldf(wb, i*27+koff)*d0s[i][spi];
                        acc += s;
                    }
                }
            }
            c1s[o][sp] = fmaxf(acc, 0.f);
        }
    }
    __syncthreads();
    {
        const int o = t>>4;
        const float bias = ldf(c2b, o);
        for (int u=0; u<32; u++){
            int sp = (t&15) + (u<<4);
            int zd = sp>>6, zh=(sp>>3)&7, zw=sp&7;
            float acc = bias;
            for (int kd=0;kd<3;kd++){
                int qd = zd+kd-1; if (qd<0 || (qd&1) || qd>=8) continue; int td=qd>>1;
                for (int kh=0;kh<3;kh++){
                    int qh = zh+kh-1; if (qh<0 || (qh&1) || qh>=8) continue; int th=qh>>1;
                    for (int kw=0;kw<3;kw++){
                        int qw = zw+kw-1; if (qw<0 || (qw&1) || qw>=8) continue; int tw=qw>>1;
                        const int koff = kd*9+kh*3+kw;
                        const int spi = td*16+th*4+tw;
                        const int wbase = (o*32)*27 + koff;
                        float s = 0.f;
                        #pragma unroll 8
                        for (int i=0;i<32;i++) s += b2f(w2s[wbase + i*27])*c1s[i][spi];
                        acc += s;
                    }
                }
            }
            Amat[(size_t)b*8192 + o*512 + sp] = f2b(fmaxf(acc, 0.f));
        }
    }
}

__global__ __launch_bounds__(256) void k_conv(
    const int* flag, const float* zbuf, const void* comp,
    const void* dw1, const void* db1, const void* c1w, const void* c1b,
    const void* c2w, const void* c2b, bf16* Amat)
{
    __shared__ __align__(16) char smem[38528];
    if (*flag) conv_impl<bf16>(zbuf,(const bf16*)comp,(const bf16*)dw1,(const bf16*)db1,
        (const bf16*)c1w,(const bf16*)c1b,(const bf16*)c2w,(const bf16*)c2b, Amat, smem);
    else       conv_impl<float>(zbuf,(const float*)comp,(const float*)dw1,(const float*)db1,
        (const float*)c1w,(const float*)c1b,(const float*)c2w,(const float*)c2b, Amat, smem);
}

// ---------------- K4: raw = Amat @ dec_w2 + bias -> out_recon (in-kernel B transpose) ----------------
template<typename T> struct BStage;
template<> struct BStage<bf16>{
    static __device__ __forceinline__ void go(const bf16* p, bf16* v8){
        union{ int4 q; bf16 e[8]; } u; u.q = *(const int4*)p;
        #pragma unroll
        for (int j=0;j<8;j++) v8[j] = u.e[j];
    }
};
template<> struct BStage<float>{
    static __device__ __forceinline__ void go(const float* p, bf16* v8){
        float4 a = *(const float4*)p, b = *(const float4*)(p+4);
        v8[0]=f2b(a.x); v8[1]=f2b(a.y); v8[2]=f2b(a.z); v8[3]=f2b(a.w);
        v8[4]=f2b(b.x); v8[5]=f2b(b.y); v8[6]=f2b(b.z); v8[7]=f2b(b.w);
    }
};

__device__ __forceinline__ bf16x8 readBfrag(const bf16 (*Bs)[42], int n, int k0){
    union { bf16x8 v; unsigned int u[4]; } r;
    const unsigned int* p = (const unsigned int*)(&Bs[n][k0]);
    r.u[0]=p[0]; r.u[1]=p[1]; r.u[2]=p[2]; r.u[3]=p[3];
    return r.v;
}

template<typename T>
__device__ __forceinline__ void gemm_impl(
    const bf16* A, const T* B, const T* bias, void* d_out, char* smem)
{
    bf16 (*As)[40] = (bf16(*)[40])(smem);
    bf16 (*Bs)[42] = (bf16(*)[42])(smem + 10240);
    T* out_recon = (T*)d_out + RECON_OFF;
    const int t = threadIdx.x;
    const int bm = blockIdx.x << 7;
    const int bn = blockIdx.y << 6;
    const int w = t >> 6, lane = t & 63;
    const int ml = lane & 15, mq = lane >> 4;
    f32x4 acc[2][4];
    #pragma unroll
    for (int i=0;i<2;i++)
        #pragma unroll
        for (int j=0;j<4;j++) acc[i][j] = (f32x4){0.f,0.f,0.f,0.f};

    const int sm = t >> 2;
    const int sk = (t & 3) << 3;
    const int kk = t >> 3;
    const int nn = (t & 7) << 3;

    for (int kt = 0; kt < 8192; kt += 32){
        __syncthreads();
        {
            int4 v0 = *(const int4*)(A + (size_t)(bm + sm     )*8192 + kt + sk);
            int4 v1 = *(const int4*)(A + (size_t)(bm + sm + 64)*8192 + kt + sk);
            *(int4*)(&As[sm][sk])    = v0;
            *(int4*)(&As[sm+64][sk]) = v1;
            bf16 bv[8];
            BStage<T>::go(B + (size_t)(kt + kk)*2752 + bn + nn, bv);
            #pragma unroll
            for (int j=0;j<8;j++) Bs[nn+j][kk] = bv[j];
        }
        __syncthreads();
        bf16x8 a0 = *(const bf16x8*)(&As[(w<<5) + ml     ][mq<<3]);
        bf16x8 a1 = *(const bf16x8*)(&As[(w<<5) + 16 + ml][mq<<3]);
        bf16x8 b0 = readBfrag(Bs, ml,      mq<<3);
        bf16x8 b1 = readBfrag(Bs, 16 + ml, mq<<3);
        bf16x8 b2 = readBfrag(Bs, 32 + ml, mq<<3);
        bf16x8 b3 = readBfrag(Bs, 48 + ml, mq<<3);
        acc[0][0] = __builtin_amdgcn_mfma_f32_16x16x32_bf16(a0,b0,acc[0][0],0,0,0);
        acc[0][1] = __builtin_amdgcn_mfma_f32_16x16x32_bf16(a0,b1,acc[0][1],0,0,0);
        acc[0][2] = __builtin_amdgcn_mfma_f32_16x16x32_bf16(a0,b2,acc[0][2],0,0,0);
        acc[0][3] = __builtin_amdgcn_mfma_f32_16x16x32_bf16(a0,b3,acc[0][3],0,0,0);
        acc[1][0] = __builtin_amdgcn_mfma_f32_16x16x32_bf16(a1,b0,acc[1][0],0,0,0);
        acc[1][1] = __builtin_amdgcn_mfma_f32_16x16x32_bf16(a1,b1,acc[1][1],0,0,0);
        acc[1][2] = __builtin_amdgcn_mfma_f32_16x16x32_bf16(a1,b2,acc[1][2],0,0,0);
        acc[1][3] = __builtin_amdgcn_mfma_f32_16x16x32_bf16(a1,b3,acc[1][3],0,0,0);
    }
    #pragma unroll
    for (int nt=0; nt<4; nt++){
        const int col = bn + (nt<<4) + ml;
        const int atom = col / 86;
        const int f = col - atom*86;
        const float bv = ldf(bias, col);
        #pragma unroll
        for (int mt=0; mt<2; mt++){
            #pragma unroll
            for (int r=0; r<4; r++){
                const int row = bm + (w<<5) + (mt<<4) + (mq<<2) + r;
                float v = acc[mt][nt][r] + bv;
                if (f >= 83) v = 1.f/(1.f + expf(-v));
                stf(out_recon, (size_t)row*2752 + col, v);
            }
        }
    }
}

__global__ __launch_bounds__(256) void k_gemm(
    const int* flag, const bf16* A, const void* B, const void* bias, void* d_out)
{
    __shared__ __align__(16) char smem[15616];
    if (*flag) gemm_impl<bf16>(A, (const bf16*)B, (const bf16*)bias, d_out, smem);
    else       gemm_impl<float>(A, (const float*)B, (const float*)bias, d_out, smem);
}

// ---------------- K5: argmax, GAT1, GAT2, coords out ----------------
template<typename T>
__device__ __forceinline__ void gat_impl(
    const T* emb, const T* g1w, const T* g1b, const T* g1as, const T* g1ad,
    const T* g2w, const T* g2b, const T* g2as, const T* g2ad,
    void* d_out, char* smem)
{
    float* ic    = (float*)(smem);
    int*   amaxs = (int*)  (smem + 384);
    float* hs    = (float*)(smem + 512);
    float* xs    = (float*)(smem + 25088);
    float* U     = (float*)(smem + 49664);
    float* sa    = (float*)(smem + 61952);
    float* da    = (float*)(smem + 62336);
    float* hh    = (float*)(smem + 62720);
    float* s2    = (float*)(smem + 63104);
    float* d2    = (float*)(smem + 63232);
    float* lg    = xs;
    float* node  = U;
    float* att   = U;
    float* att2  = U;

    T* out_recon = (T*)d_out + RECON_OFF;
    const int b = blockIdx.x, t = threadIdx.x;

    for (int i=t; i<2656; i+=256){
        int n = i/83, f = i - n*83;
        lg[i] = ldf(out_recon, (size_t)b*2752 + n*86 + f);
    }
    if (t < 96){
        int n = t/3, c = t - 3*(t/3);
        ic[t] = ldf(out_recon, (size_t)b*2752 + n*86 + 83 + c);
    }
    __syncthreads();
    if (t < 32){
        const float* lp = lg + t*83;
        float best = lp[0]; int bi = 0;
        for (int f=1; f<83; f++){ float v = lp[f]; if (v > best){ best=v; bi=f; } }
        amaxs[t] = bi;
    }
    __syncthreads();
    for (int i=t; i<608; i+=256){
        int n = i/19, f = i - n*19;
        node[n*19+f] = (f<16) ? ldf(emb, amaxs[n]*16+f) : ic[n*3 + (f-16)];
    }
    __syncthreads();
    if (t < 192){
        float wc[19];
        #pragma unroll
        for (int f=0;f<19;f++) wc[f] = ldf(g1w, f*192+t);
        for (int n=0;n<32;n++){
            float a = 0.f;
            #pragma unroll
            for (int f=0;f<19;f++) a += node[n*19+f]*wc[f];
            hs[n*192+t] = a;
        }
    }
    __syncthreads();
    if (t < 96){
        int n = t/3, hd = t - 3*(t/3);
        float s=0.f, d=0.f;
        for (int c=0;c<64;c++){
            float hv = hs[n*192 + hd*64 + c];
            s += hv*ldf(g1as, hd*64+c);
            d += hv*ldf(g1ad, hd*64+c);
        }
        sa[n*3+hd] = s; da[n*3+hd] = d;
    }
    __syncthreads();
    if (t < 96){
        int i = t/3, hd = t - 3*(t/3);
        float di = da[i*3+hd];
        float ev[32]; float m = -1e30f;
        for (int j=0;j<32;j++){
            float e = di + sa[j*3+hd];
            e = (e > 0.f) ? e : 0.2f*e;
            ev[j] = e; m = fmaxf(m, e);
        }
        float ssum = 0.f;
        for (int j=0;j<32;j++){ float p = expf(ev[j]-m); ev[j]=p; ssum += p; }
        float inv = 1.f/ssum;
        for (int j=0;j<32;j++) att[(i*3+hd)*32 + j] = ev[j]*inv;
    }
    __syncthreads();
    if (t < 192){
        int hd = t >> 6;
        float bb = ldf(g1b, t);
        for (int i=0;i<32;i++){
            float a = 0.f;
            for (int j=0;j<32;j++) a += att[(i*3+hd)*32 + j]*hs[j*192+t];
            a += bb;
            xs[i*192+t] = (a > 0.f) ? a : (expf(a) - 1.f);
        }
    }
    __syncthreads();
    if (t < 96){
        int n = t/3, c = t - 3*(t/3);
        float a = 0.f;
        for (int f=0;f<192;f++) a += xs[n*192+f]*ldf(g2w, f*3+c);
        hh[n*3+c] = a;
    }
    __syncthreads();
    if (t < 32){
        float s=0.f,d=0.f;
        #pragma unroll
        for (int c=0;c<3;c++){ s += hh[t*3+c]*ldf(g2as,c); d += hh[t*3+c]*ldf(g2ad,c); }
        s2[t]=s; d2[t]=d;
    }
    __syncthreads();
    if (t < 32){
        float di = d2[t];
        float ev[32]; float m=-1e30f;
        for (int j=0;j<32;j++){
            float e = di + s2[j]; e = (e>0.f)?e:0.2f*e; ev[j]=e; m=fmaxf(m,e);
        }
        float ssum=0.f;
        for (int j=0;j<32;j++){ float p=expf(ev[j]-m); ev[j]=p; ssum+=p; }
        float inv = 1.f/ssum;
        for (int j=0;j<32;j++) att2[t*32+j] = ev[j]*inv;
    }
    __syncthreads();
    if (t < 96){
        int i = t/3, c = t - 3*(t/3);
        float a = 0.f;
        for (int j=0;j<32;j++) a += att2[i*32+j]*hh[j*3+c];
        a += ldf(g2b, c);
        float adj = tanhf(a)*0.1f;
        float cr = ic[i*3+c] + adj;
        cr -= floorf(cr);
        stf(out_recon, (size_t)b*2752 + i*86 + 83 + c, cr);
    }
}

__global__ __launch_bounds__(256) void k_gat(
    const int* flag, const void* emb,
    const void* g1w, const void* g1b, const void* g1as, const void* g1ad,
    const void* g2w, const void* g2b, const void* g2as, const void* g2ad,
    void* d_out)
{
    __shared__ __align__(16) char smem[63360];
    if (*flag) gat_impl<bf16>((const bf16*)emb,(const bf16*)g1w,(const bf16*)g1b,
        (const bf16*)g1as,(const bf16*)g1ad,(const bf16*)g2w,(const bf16*)g2b,
        (const bf16*)g2as,(const bf16*)g2ad, d_out, smem);
    else       gat_impl<float>((const float*)emb,(const float*)g1w,(const float*)g1b,
        (const float*)g1as,(const float*)g1ad,(const float*)g2w,(const float*)g2b,
        (const float*)g2as,(const float*)g2ad, d_out, smem);
}

extern "C" void kernel_launch(void* const* d_in, const int* in_sizes, int n_in,
                              void* d_out, int out_size, void* d_ws, size_t ws_size,
                              hipStream_t stream)
{
    (void)in_sizes; (void)n_in; (void)out_size;
    char* ws = (char*)d_ws;
    const bool big = (ws_size >= 83000000ull);

    if (big){
        bf16*  Amat  = (bf16*)(ws);                    // 33,554,432
        bf16*  Wc2T  = (bf16*)(ws + 33554432);         // 33,554,432
        bf16*  c1    = (bf16*)(ws + 67108864);         //  8,388,608
        bf16*  d0    = (bf16*)(ws + 75497472);         //  2,097,152
        bf16*  Wc1T  = (bf16*)(ws + 77594624);         //  2,097,152
        bf16*  zc    = (bf16*)(ws + 79691776);         //    655,360
        bf16*  BtW1  = (bf16*)(ws + 80347136);         //    163,840
        float* biasf = (float*)(ws + 80510976);        //      4,096
        float* gbuf  = (float*)(ws + 80515072);        //  1,048,576
        float* zbuf  = (float*)(ws + 81563648);        //    524,288
        int*   flag  = (int*)  (ws + 82087936);

        k_detect<<<1, 64, 0, stream>>>(d_in[5], flag);
        k_prep<<<64, 256, 0, stream>>>(flag, d_in[21], d_in[23], d_in[25], d_in[20], biasf, BtW1);
        k_expWc1<<<512, 256, 0, stream>>>(flag, d_in[22], Wc1T);
        k_expWc2<<<8192, 256, 0, stream>>>(flag, d_in[24], Wc2T);
        k_encoder<<<2048, 256, 0, stream>>>(flag, (const int*)d_in[0], d_in[1], d_in[5],
            d_in[6], d_in[7], d_in[8], d_in[9], d_in[10], d_in[11], gbuf);
        k_latent<<<2048, 64, 0, stream>>>(flag, d_in[2], d_in[4], d_in[3],
            d_in[12], d_in[13], d_in[14], d_in[15],
            d_in[16], d_in[17], d_in[18], d_in[19],
            d_in[28], d_in[29], d_in[30], d_in[31],
            gbuf, zbuf, zc, d_out);
        k_gemm_g<bf16,0><<<dim3(16,8),  256, 0, stream>>>(zc, BtW1, 160, biasf,       0, d0,   512);
        k_gemm_g<bf16,1><<<dim3(16,32), 256, 0, stream>>>(d0, Wc1T, 512, biasf+512,   6, c1,   2048);
        k_gemm_g<bf16,1><<<dim3(16,128),256, 0, stream>>>(c1, Wc2T, 2048, biasf+544,  9, Amat, 8192);
        k_gemm<<<dim3(16,43), 256, 0, stream>>>(flag, Amat, d_in[26], d_in[27], d_out);
        k_gat<<<2048, 256, 0, stream>>>(flag, d_in[5],
            d_in[32], d_in[33], d_in[34], d_in[35],
            d_in[36], d_in[37], d_in[38], d_in[39], d_out);
    } else {
        bf16*  Amat = (bf16*)(ws);
        float* gbuf = (float*)(ws + 33554432);
        float* zbuf = (float*)(ws + 34603008);
        int*   flag = (int*)  (ws + 35127296);

        k_detect<<<1, 64, 0, stream>>>(d_in[5], flag);
        k_encoder<<<2048, 256, 0, stream>>>(flag, (const int*)d_in[0], d_in[1], d_in[5],
            d_in[6], d_in[7], d_in[8], d_in[9], d_in[10], d_in[11], gbuf);
        k_latent<<<2048, 64, 0, stream>>>(flag, d_in[2], d_in[4], d_in[3],
            d_in[12], d_in[13], d_in[14], d_in[15],
            d_in[16], d_in[17], d_in[18], d_in[19],
            d_in[28], d_in[29], d_in[30], d_in[31],
            gbuf, zbuf, (bf16*)nullptr, d_out);
        k_conv<<<2048, 256, 0, stream>>>(flag, zbuf, d_in[3],
            d_in[20], d_in[21], d_in[22], d_in[23], d_in[24], d_in[25], Amat);
        k_gemm<<<dim3(16,43), 256, 0, stream>>>(flag, Amat, d_in[26], d_in[27], d_out);
        k_gat<<<2048, 256, 0, stream>>>(flag, d_in[5],
            d_in[32], d_in[33], d_in[34], d_in[35],
            d_in[36], d_in[37], d_in[38], d_in[39], d_out);
    }
}

// Round 4
// 795.654 us; speedup vs baseline: 2.5251x; 1.1161x over previous
//
#include <hip/hip_runtime.h>
#include <hip/hip_bf16.h>

typedef __hip_bfloat16 bf16;
typedef __attribute__((ext_vector_type(8))) __bf16 bf16x8;
typedef __attribute__((ext_vector_type(4))) float f32x4;

__device__ __forceinline__ float b2f(bf16 v){ return __bfloat162float(v); }
__device__ __forceinline__ bf16  f2b(float v){ return __float2bfloat16(v); }

template<typename T> __device__ __forceinline__ float ldf(const T* p, size_t i);
template<> __device__ __forceinline__ float ldf<float>(const float* p, size_t i){ return p[i]; }
template<> __device__ __forceinline__ float ldf<bf16 >(const bf16*  p, size_t i){ return b2f(p[i]); }

template<typename T> __device__ __forceinline__ void stf(T* p, size_t i, float v);
template<> __device__ __forceinline__ void stf<float>(float* p, size_t i, float v){ p[i] = v; }
template<> __device__ __forceinline__ void stf<bf16 >(bf16*  p, size_t i, float v){ p[i] = f2b(v); }

#define NATM 32
#define RECON_OFF 262144          // 2*2048*64 elements (mu, logvar)
#define RL_OFF    5898240         // + 2048*2752

// async global->LDS, 16B per lane, dest = wave-uniform base + lane*16
__device__ __forceinline__ void glds16(const bf16* g, bf16* l){
    __builtin_amdgcn_global_load_lds(
        (const __attribute__((address_space(1))) unsigned int*)g,
        (__attribute__((address_space(3))) unsigned int*)l,
        16, 0, 0);
}

// ---------------- K0: dtype detect ----------------
__global__ __launch_bounds__(64) void k_detect(const void* emb, int* flag)
{
    __shared__ int cnt[64];
    const int t = threadIdx.x;
    const unsigned short* p = (const unsigned short*)emb;
    int c = 0;
    for (int i = t; i < 256; i += 64){
        int e = (p[i] >> 7) & 0xFF;
        c += (e >= 110 && e <= 132) ? 1 : 0;
    }
    cnt[t] = c;
    __syncthreads();
    if (t == 0){
        int s = 0;
        for (int i = 0; i < 64; i++) s += cnt[i];
        *flag = (s >= 200) ? 1 : 0;   // 1 = bf16, 0 = f32
    }
}

// ---------------- K1: atom encoder + mean pool -> gbuf[b][128] ----------------
template<typename T>
__device__ __forceinline__ void enc_impl(
    const int* elements, const T* coords, const T* emb,
    const T* w1, const T* b1, const T* w2, const T* b2c,
    const T* w3, const T* b3, float* gbuf, char* smem)
{
    float (*af)[19]   = (float(*)[19])(smem);
    float (*h1)[256]  = (float(*)[256])(smem + 2432);
    float (*h2s)[128] = (float(*)[128])(smem + 35200);
    float* hsum       = (float*)(smem + 51584);
    const int b = blockIdx.x, t = threadIdx.x;

    for (int idx = t; idx < NATM*19; idx += 256){
        int n = idx/19, f = idx - n*19;
        af[n][f] = (f < 16) ? ldf(emb, (size_t)elements[b*NATM+n]*16 + f)
                            : ldf(coords, (size_t)(b*NATM+n)*3 + (f-16));
    }
    __syncthreads();
    {
        float wc[19];
        #pragma unroll
        for (int f=0; f<19; f++) wc[f] = ldf(w1, f*256 + t);
        float bb = ldf(b1, t);
        for (int n=0; n<NATM; n++){
            float a = bb;
            #pragma unroll
            for (int f=0; f<19; f++) a += af[n][f]*wc[f];
            h1[n][t] = fmaxf(a, 0.f);
        }
    }
    __syncthreads();
    {
        const int j = t & 127, half = t >> 7;
        float bb = ldf(b2c, j);
        float acc[16];
        #pragma unroll
        for (int n=0;n<16;n++) acc[n] = bb;
        for (int k=0;k<256;k+=4){
            float wa = ldf(w2, (k+0)*128+j);
            float wb = ldf(w2, (k+1)*128+j);
            float wcv= ldf(w2, (k+2)*128+j);
            float wd = ldf(w2, (k+3)*128+j);
            #pragma unroll
            for (int n=0;n<16;n++){
                float4 hv = *(const float4*)(&h1[half*16+n][k]);
                acc[n] += hv.x*wa + hv.y*wb + hv.z*wcv + hv.w*wd;
            }
        }
        #pragma unroll
        for (int n=0;n<16;n++) h2s[half*16+n][j] = fmaxf(acc[n], 0.f);
    }
    __syncthreads();
    if (t < 128){
        float s = 0.f;
        for (int n=0;n<NATM;n++) s += h2s[n][t];
        hsum[t] = s;
    }
    __syncthreads();
    if (t < 128){
        float a = 0.f;
        for (int k=0;k<128;k++) a += hsum[k]*ldf(w3, k*128+t);
        gbuf[b*128+t] = a*(1.f/32.f) + ldf(b3, t);
    }
}

__global__ __launch_bounds__(256) void k_encoder(
    const int* flag, const int* elements, const void* coords, const void* emb,
    const void* w1, const void* b1, const void* w2, const void* b2,
    const void* w3, const void* b3, float* gbuf)
{
    __shared__ __align__(16) char smem[52096];
    if (*flag) enc_impl<bf16>(elements,(const bf16*)coords,(const bf16*)emb,
        (const bf16*)w1,(const bf16*)b1,(const bf16*)w2,(const bf16*)b2,
        (const bf16*)w3,(const bf16*)b3, gbuf, smem);
    else       enc_impl<float>(elements,(const float*)coords,(const float*)emb,
        (const float*)w1,(const float*)b1,(const float*)w2,(const float*)b2,
        (const float*)w3,(const float*)b3, gbuf, smem);
}

// ---------------- K2: lattice enc + mu/logvar/z + recon_lattice (+ zc row) ----------------
template<typename T>
__device__ __forceinline__ void lat_impl(
    const T* lattice, const T* eps, const T* comp,
    const T* lw1, const T* lb1, const T* lw2, const T* lb2,
    const T* muw, const T* mub, const T* lvw, const T* lvb,
    const T* dw1, const T* db1, const T* dw2, const T* db2,
    const float* gbuf, float* zbuf, bf16* zc, void* d_out, char* smem)
{
    float* comb = (float*)(smem);
    float* lat  = (float*)(smem + 768);
    float* l1   = (float*)(smem + 832);
    float* zz   = (float*)(smem + 1088);
    float* r1   = (float*)(smem + 1344);
    T* out_mu = (T*)d_out;
    T* out_lv = out_mu + 131072;
    T* out_rl = out_mu + RL_OFF;
    const int b = blockIdx.x, t = threadIdx.x;
    comb[t]    = gbuf[b*128 + t];
    comb[64+t] = gbuf[b*128 + 64 + t];
    if (t < 9) lat[t] = ldf(lattice, b*9 + t);
    __syncthreads();
    {
        float a = ldf(lb1, t);
        #pragma unroll
        for (int f=0; f<9; f++) a += lat[f]*ldf(lw1, f*64+t);
        l1[t] = fmaxf(a, 0.f);
    }
    __syncthreads();
    {
        float a = ldf(lb2, t);
        for (int k=0;k<64;k++) a += l1[k]*ldf(lw2, k*64+t);
        comb[128+t] = a;
    }
    __syncthreads();
    float mu = ldf(mub, t), lv = ldf(lvb, t);
    for (int k=0;k<192;k++){
        float c = comb[k];
        mu += c*ldf(muw, k*64+t);
        lv += c*ldf(lvw, k*64+t);
    }
    float z = mu + ldf(eps, b*64+t)*expf(0.5f*lv);
    stf(out_mu, (size_t)b*64+t, mu);
    stf(out_lv, (size_t)b*64+t, lv);
    zbuf[b*64+t] = z;
    zz[t] = z;
    __syncthreads();
    if (zc){
        for (int i=t; i<160; i+=64){
            float v = (i<64) ? zz[i] : ((i<147) ? ldf(comp, b*83 + (i-64)) : 0.f);
            zc[(size_t)b*160 + i] = f2b(v);
        }
    }
    {
        float a = ldf(db1, t);
        for (int k=0;k<64;k++) a += zz[k]*ldf(dw1, k*64+t);
        r1[t] = fmaxf(a, 0.f);
    }
    __syncthreads();
    if (t < 9){
        float a = ldf(db2, t);
        for (int k=0;k<64;k++) a += r1[k]*ldf(dw2, k*9+t);
        stf(out_rl, (size_t)b*9+t, a);
    }
}

__global__ __launch_bounds__(64) void k_latent(
    const int* flag, const void* lattice, const void* eps, const void* comp,
    const void* lw1, const void* lb1, const void* lw2, const void* lb2,
    const void* muw, const void* mub, const void* lvw, const void* lvb,
    const void* dw1, const void* db1, const void* dw2, const void* db2,
    const float* gbuf, float* zbuf, bf16* zc, void* d_out)
{
    __shared__ __align__(16) char smem[1600];
    if (*flag) lat_impl<bf16>((const bf16*)lattice,(const bf16*)eps,(const bf16*)comp,
        (const bf16*)lw1,(const bf16*)lb1,(const bf16*)lw2,(const bf16*)lb2,
        (const bf16*)muw,(const bf16*)mub,(const bf16*)lvw,(const bf16*)lvb,
        (const bf16*)dw1,(const bf16*)db1,(const bf16*)dw2,(const bf16*)db2,
        gbuf, zbuf, zc, d_out, smem);
    else       lat_impl<float>((const float*)lattice,(const float*)eps,(const float*)comp,
        (const float*)lw1,(const float*)lb1,(const float*)lw2,(const float*)lb2,
        (const float*)muw,(const float*)mub,(const float*)lvw,(const float*)lvb,
        (const float*)dw1,(const float*)db1,(const float*)dw2,(const float*)db2,
        gbuf, zbuf, zc, d_out, smem);
}

// ---------------- K-prep: biases->f32, BtW1 (dec_w1 transposed, K-padded) ----------------
template<typename T>
__device__ __forceinline__ void prep_impl(
    const T* db1, const T* c1b, const T* c2b, const T* db2, const T* dw1,
    float* biasf, bf16* BtW1)
{
    const int gt = blockIdx.x*256 + threadIdx.x;
    const int gs = gridDim.x*256;
    for (int i = gt; i < 3376; i += gs){
        float v;
        if (i < 512)      v = ldf(db1, i);
        else if (i < 544) v = ldf(c1b, i-512);
        else if (i < 560) v = ldf(c2b, i-544);
        else              v = (i-560 < 2752) ? ldf(db2, i-560) : 0.f;
        biasf[i] = v;
    }
    for (int e = gt; e < 512*160; e += gs){
        int n = e/160, k = e - n*160;
        BtW1[e] = f2b((k < 147) ? ldf(dw1, (size_t)k*512 + n) : 0.f);
    }
}

__global__ __launch_bounds__(256) void k_prep(
    const int* flag, const void* db1, const void* c1b, const void* c2b,
    const void* db2, const void* dw1, float* biasf, bf16* BtW1)
{
    if (*flag) prep_impl<bf16>((const bf16*)db1,(const bf16*)c1b,(const bf16*)c2b,
        (const bf16*)db2,(const bf16*)dw1, biasf, BtW1);
    else       prep_impl<float>((const float*)db1,(const float*)c1b,(const float*)c2b,
        (const float*)db2,(const float*)dw1, biasf, BtW1);
}

// ---------------- K-exp1: Wc1T from ct1_w ----------------
template<typename T>
__device__ __forceinline__ void expWc1_impl(const T* w, bf16* Wc1T)
{
    const int t = threadIdx.x;
    const int n = blockIdx.x*4 + (t >> 6);
    const int k0 = (t & 63) << 3;
    const int o = n >> 6, spo = n & 63;
    const int zd = spo >> 4, zh = (spo >> 2) & 3, zw = spo & 3;
    bf16 v8[8];
    #pragma unroll
    for (int j = 0; j < 8; j++){
        int k = k0 + j;
        int i = k >> 3, sp = k & 7;
        int td = sp >> 2, th = (sp >> 1) & 1, tw = sp & 1;
        int kd = 2*td + 1 - zd, kh = 2*th + 1 - zh, kw = 2*tw + 1 - zw;
        float v = 0.f;
        if (kd >= 0 && kd < 3 && kh >= 0 && kh < 3 && kw >= 0 && kw < 3)
            v = ldf(w, (size_t)(o*64 + i)*27 + kd*9 + kh*3 + kw);
        v8[j] = f2b(v);
    }
    *(int4*)(&Wc1T[(size_t)n*512 + k0]) = *(int4*)v8;
}

__global__ __launch_bounds__(256) void k_expWc1(const int* flag, const void* w, bf16* Wc1T)
{
    if (*flag) expWc1_impl<bf16>((const bf16*)w, Wc1T);
    else       expWc1_impl<float>((const float*)w, Wc1T);
}

// ---------------- K-exp2: Wc2T from ct2_w ----------------
template<typename T>
__device__ __forceinline__ void expWc2_impl(const T* w, bf16* Wc2T)
{
    const int n = blockIdx.x;
    const int k0 = threadIdx.x << 3;
    const int o = n >> 9, spo = n & 511;
    const int zd = spo >> 6, zh = (spo >> 3) & 7, zw = spo & 7;
    bf16 v8[8];
    #pragma unroll
    for (int j = 0; j < 8; j++){
        int k = k0 + j;
        int i = k >> 6, sp = k & 63;
        int td = sp >> 4, th = (sp >> 2) & 3, tw = sp & 3;
        int kd = 2*td + 1 - zd, kh = 2*th + 1 - zh, kw = 2*tw + 1 - zw;
        float v = 0.f;
        if (kd >= 0 && kd < 3 && kh >= 0 && kh < 3 && kw >= 0 && kw < 3)
            v = ldf(w, (size_t)(o*32 + i)*27 + kd*9 + kh*3 + kw);
        v8[j] = f2b(v);
    }
    *(int4*)(&Wc2T[(size_t)n*2048 + k0]) = *(int4*)v8;
}

__global__ __launch_bounds__(256) void k_expWc2(const int* flag, const void* w, bf16* Wc2T)
{
    if (*flag) expWc2_impl<bf16>((const bf16*)w, Wc2T);
    else       expWc2_impl<float>((const float*)w, Wc2T);
}

// ---------------- K-transW: dec_w2 [8192][2752] -> BtW2 [2816][8192] ----------------
template<typename T>
__device__ __forceinline__ void transW_impl(const T* B, bf16* Bt)
{
    __shared__ bf16 tile[64][65];
    const int kb = blockIdx.x << 6;
    const int nb = blockIdx.y << 6;
    const int t = threadIdx.x;
    for (int idx=t; idx<4096; idx+=256){
        int k = idx>>6, n = idx&63;
        int col = nb + n;
        tile[k][n] = (col < 2752) ? f2b(ldf(B, (size_t)(kb+k)*2752 + col)) : f2b(0.f);
    }
    __syncthreads();
    for (int idx=t; idx<4096; idx+=256){
        int n = idx>>6, k = idx&63;
        Bt[(size_t)(nb+n)*8192 + kb + k] = tile[k][n];
    }
}

__global__ __launch_bounds__(256) void k_transW(const int* flag, const void* B, bf16* Bt)
{
    if (*flag) transW_impl<bf16>((const bf16*)B, Bt);
    else       transW_impl<float>((const float*)B, Bt);
}

// ---------------- k_gemm128 core (shared by plain + recon) ----------------
struct GemmAcc { f32x4 a[4][4]; };

__device__ __forceinline__ void gemm128_core(
    const bf16* __restrict__ A, const bf16* __restrict__ Bt, int K,
    int bm, int bn, bf16* As, bf16* Bs, GemmAcc& G)
{
    const int t = threadIdx.x;
    const int w = t >> 6, lane = t & 63;
    const int wm = w >> 1, wn = w & 1;
    const int ml = lane & 15, mq = lane >> 4;
    const int lrow = lane >> 2;
    const int gchunk = (lane & 3) ^ ((lane >> 3) & 3);
    const int rchunk = (mq ^ ((ml >> 1) & 3)) << 3;

    const size_t arow = (size_t)(bm + w*32 + lrow);
    const size_t brow = (size_t)(bn + w*32 + lrow);

    for (int kt = 0; kt < K; kt += 32){
        __syncthreads();
        #pragma unroll
        for (int c = 0; c < 2; c++){
            glds16(A  + (arow + c*16)*K + kt + gchunk*8, &As[(w*32 + c*16)*32]);
            glds16(Bt + (brow + c*16)*K + kt + gchunk*8, &Bs[(w*32 + c*16)*32]);
        }
        __syncthreads();
        bf16x8 af[4], bfr[4];
        #pragma unroll
        for (int i=0;i<4;i++) af[i]  = *(const bf16x8*)(&As[(wm*64 + i*16 + ml)*32 + rchunk]);
        #pragma unroll
        for (int j=0;j<4;j++) bfr[j] = *(const bf16x8*)(&Bs[(wn*64 + j*16 + ml)*32 + rchunk]);
        #pragma unroll
        for (int i=0;i<4;i++)
            #pragma unroll
            for (int j=0;j<4;j++)
                G.a[i][j] = __builtin_amdgcn_mfma_f32_16x16x32_bf16(af[i], bfr[j], G.a[i][j], 0,0,0);
    }
}

template<int ACT>   // 0 none, 1 relu
__global__ __launch_bounds__(256) void k_gemm128(
    const bf16* __restrict__ A, const bf16* __restrict__ Bt, int K,
    const float* __restrict__ biasf, int bshift,
    bf16* __restrict__ C, int ldc)
{
    __shared__ __align__(16) bf16 As[128*32];
    __shared__ __align__(16) bf16 Bs[128*32];
    const int t = threadIdx.x;
    const int bm = blockIdx.x << 7, bn = blockIdx.y << 7;
    const int w = t >> 6, lane = t & 63;
    const int wm = w >> 1, wn = w & 1;
    const int ml = lane & 15, mq = lane >> 4;
    GemmAcc G;
    #pragma unroll
    for (int i=0;i<4;i++)
        #pragma unroll
        for (int j=0;j<4;j++) G.a[i][j] = (f32x4){0.f,0.f,0.f,0.f};
    gemm128_core(A, Bt, K, bm, bn, As, Bs, G);
    #pragma unroll
    for (int j=0;j<4;j++){
        const int col = bn + wn*64 + (j<<4) + ml;
        const float bv = biasf[col >> bshift];
        #pragma unroll
        for (int i=0;i<4;i++){
            #pragma unroll
            for (int r=0;r<4;r++){
                const int row = bm + wm*64 + (i<<4) + (mq<<2) + r;
                float v = G.a[i][j][r] + bv;
                if (ACT == 1) v = fmaxf(v, 0.f);
                C[(size_t)row*ldc + col] = f2b(v);
            }
        }
    }
}

__global__ __launch_bounds__(256) void k_gemm128_recon(
    const int* __restrict__ flag,
    const bf16* __restrict__ A, const bf16* __restrict__ Bt,
    const float* __restrict__ biasf, void* __restrict__ d_out)
{
    __shared__ __align__(16) bf16 As[128*32];
    __shared__ __align__(16) bf16 Bs[128*32];
    const int t = threadIdx.x;
    const int bm = blockIdx.x << 7, bn = blockIdx.y << 7;
    const int w = t >> 6, lane = t & 63;
    const int wm = w >> 1, wn = w & 1;
    const int ml = lane & 15, mq = lane >> 4;
    GemmAcc G;
    #pragma unroll
    for (int i=0;i<4;i++)
        #pragma unroll
        for (int j=0;j<4;j++) G.a[i][j] = (f32x4){0.f,0.f,0.f,0.f};
    gemm128_core(A, Bt, 8192, bm, bn, As, Bs, G);
    const int fl = *flag;
    #pragma unroll
    for (int j=0;j<4;j++){
        const int col = bn + wn*64 + (j<<4) + ml;
        if (col >= 2752) continue;
        const int f = col % 86;
        const float bv = biasf[560 + col];
        #pragma unroll
        for (int i=0;i<4;i++){
            #pragma unroll
            for (int r=0;r<4;r++){
                const int row = bm + wm*64 + (i<<4) + (mq<<2) + r;
                float v = G.a[i][j][r] + bv;
                if (f >= 83) v = 1.f/(1.f + expf(-v));
                if (fl) stf((bf16*)d_out + RECON_OFF, (size_t)row*2752 + col, v);
                else    stf((float*)d_out + RECON_OFF, (size_t)row*2752 + col, v);
            }
        }
    }
}

// ---------------- K3 (fallback): conv chain ----------------
template<typename T>
__device__ __forceinline__ void conv_impl(
    const float* zbuf, const T* comp,
    const T* dw1, const T* db1, const T* c1w, const T* c1b,
    const T* c2w, const T* c2b, bf16* Amat, char* smem)
{
    float* zc        = (float*)(smem);
    float (*d0s)[8]  = (float(*)[8])(smem + 640);
    float (*c1s)[64] = (float(*)[64])(smem + 2688);
    bf16* w2s        = (bf16*)(smem + 10880);
    const int b = blockIdx.x, t = threadIdx.x;
    for (int i=t; i<16*32*27; i+=256) w2s[i] = f2b(ldf(c2w, i));
    if (t < 147) zc[t] = (t < 64) ? zbuf[b*64+t] : ldf(comp, b*83 + (t-64));
    __syncthreads();
    #pragma unroll
    for (int jj=0; jj<2; jj++){
        int j = t + (jj<<8);
        float a = ldf(db1, j);
        for (int k=0;k<147;k++) a += zc[k]*ldf(dw1, k*512+j);
        d0s[j>>3][j&7] = a;
    }
    __syncthreads();
    {
        const int o = t>>3;
        const float bias = ldf(c1b, o);
        const T* wb = c1w + o*64*27;
        for (int u=0; u<8; u++){
            int sp = (t&7) + (u<<3);
            int zd = sp>>4, zh = (sp>>2)&3, zw = sp&3;
            float acc = bias;
            for (int kd=0;kd<3;kd++){
                int qd = zd+kd-1; if (qd<0 || (qd&1) || qd>=4) continue; int td=qd>>1;
                for (int kh=0;kh<3;kh++){
                    int qh = zh+kh-1; if (qh<0 || (qh&1) || qh>=4) continue; int th=qh>>1;
                    for (int kw=0;kw<3;kw++){
                        int qw = zw+kw-1; if (qw<0 || (qw&1) || qw>=4) continue; int tw=qw>>1;
                        const int koff = kd*9+kh*3+kw;
                        const int spi = td*4+th*2+tw;
                        float s = 0.f;
                        #pragma unroll 8
                        for (int i=0;i<64;i++) s += ldf(wb, i*27+koff)*d0s[i][spi];
                        acc += s;
                    }
                }
            }
            c1s[o][sp] = fmaxf(acc, 0.f);
        }
    }
    __syncthreads();
    {
        const int o = t>>4;
        const float bias = ldf(c2b, o);
        for (int u=0; u<32; u++){
            int sp = (t&15) + (u<<4);
            int zd = sp>>6, zh=(sp>>3)&7, zw=sp&7;
            float acc = bias;
            for (int kd=0;kd<3;kd++){
                int qd = zd+kd-1; if (qd<0 || (qd&1) || qd>=8) continue; int td=qd>>1;
                for (int kh=0;kh<3;kh++){
                    int qh = zh+kh-1; if (qh<0 || (qh&1) || qh>=8) continue; int th=qh>>1;
                    for (int kw=0;kw<3;kw++){
                        int qw = zw+kw-1; if (qw<0 || (qw&1) || qw>=8) continue; int tw=qw>>1;
                        const int koff = kd*9+kh*3+kw;
                        const int spi = td*16+th*4+tw;
                        const int wbase = (o*32)*27 + koff;
                        float s = 0.f;
                        #pragma unroll 8
                        for (int i=0;i<32;i++) s += b2f(w2s[wbase + i*27])*c1s[i][spi];
                        acc += s;
                    }
                }
            }
            Amat[(size_t)b*8192 + o*512 + sp] = f2b(fmaxf(acc, 0.f));
        }
    }
}

__global__ __launch_bounds__(256) void k_conv(
    const int* flag, const float* zbuf, const void* comp,
    const void* dw1, const void* db1, const void* c1w, const void* c1b,
    const void* c2w, const void* c2b, bf16* Amat)
{
    __shared__ __align__(16) char smem[38528];
    if (*flag) conv_impl<bf16>(zbuf,(const bf16*)comp,(const bf16*)dw1,(const bf16*)db1,
        (const bf16*)c1w,(const bf16*)c1b,(const bf16*)c2w,(const bf16*)c2b, Amat, smem);
    else       conv_impl<float>(zbuf,(const float*)comp,(const float*)dw1,(const float*)db1,
        (const float*)c1w,(const float*)c1b,(const float*)c2w,(const float*)c2b, Amat, smem);
}

// ---------------- K4 (fallback): dec_w2 gemm with in-kernel transpose ----------------
template<typename T> struct BStage;
template<> struct BStage<bf16>{
    static __device__ __forceinline__ void go(const bf16* p, bf16* v8){
        union{ int4 q; bf16 e[8]; } u; u.q = *(const int4*)p;
        #pragma unroll
        for (int j=0;j<8;j++) v8[j] = u.e[j];
    }
};
template<> struct BStage<float>{
    static __device__ __forceinline__ void go(const float* p, bf16* v8){
        float4 a = *(const float4*)p, b = *(const float4*)(p+4);
        v8[0]=f2b(a.x); v8[1]=f2b(a.y); v8[2]=f2b(a.z); v8[3]=f2b(a.w);
        v8[4]=f2b(b.x); v8[5]=f2b(b.y); v8[6]=f2b(b.z); v8[7]=f2b(b.w);
    }
};

__device__ __forceinline__ bf16x8 readBfrag(const bf16 (*Bs)[42], int n, int k0){
    union { bf16x8 v; unsigned int u[4]; } r;
    const unsigned int* p = (const unsigned int*)(&Bs[n][k0]);
    r.u[0]=p[0]; r.u[1]=p[1]; r.u[2]=p[2]; r.u[3]=p[3];
    return r.v;
}

template<typename T>
__device__ __forceinline__ void gemm_impl(
    const bf16* A, const T* B, const T* bias, void* d_out, char* smem)
{
    bf16 (*As)[40] = (bf16(*)[40])(smem);
    bf16 (*Bs)[42] = (bf16(*)[42])(smem + 10240);
    T* out_recon = (T*)d_out + RECON_OFF;
    const int t = threadIdx.x;
    const int bm = blockIdx.x << 7;
    const int bn = blockIdx.y << 6;
    const int w = t >> 6, lane = t & 63;
    const int ml = lane & 15, mq = lane >> 4;
    f32x4 acc[2][4];
    #pragma unroll
    for (int i=0;i<2;i++)
        #pragma unroll
        for (int j=0;j<4;j++) acc[i][j] = (f32x4){0.f,0.f,0.f,0.f};

    const int sm = t >> 2;
    const int sk = (t & 3) << 3;
    const int kk = t >> 3;
    const int nn = (t & 7) << 3;

    for (int kt = 0; kt < 8192; kt += 32){
        __syncthreads();
        {
            int4 v0 = *(const int4*)(A + (size_t)(bm + sm     )*8192 + kt + sk);
            int4 v1 = *(const int4*)(A + (size_t)(bm + sm + 64)*8192 + kt + sk);
            *(int4*)(&As[sm][sk])    = v0;
            *(int4*)(&As[sm+64][sk]) = v1;
            bf16 bv[8];
            BStage<T>::go(B + (size_t)(kt + kk)*2752 + bn + nn, bv);
            #pragma unroll
            for (int j=0;j<8;j++) Bs[nn+j][kk] = bv[j];
        }
        __syncthreads();
        bf16x8 a0 = *(const bf16x8*)(&As[(w<<5) + ml     ][mq<<3]);
        bf16x8 a1 = *(const bf16x8*)(&As[(w<<5) + 16 + ml][mq<<3]);
        bf16x8 b0 = readBfrag(Bs, ml,      mq<<3);
        bf16x8 b1 = readBfrag(Bs, 16 + ml, mq<<3);
        bf16x8 b2 = readBfrag(Bs, 32 + ml, mq<<3);
        bf16x8 b3 = readBfrag(Bs, 48 + ml, mq<<3);
        acc[0][0] = __builtin_amdgcn_mfma_f32_16x16x32_bf16(a0,b0,acc[0][0],0,0,0);
        acc[0][1] = __builtin_amdgcn_mfma_f32_16x16x32_bf16(a0,b1,acc[0][1],0,0,0);
        acc[0][2] = __builtin_amdgcn_mfma_f32_16x16x32_bf16(a0,b2,acc[0][2],0,0,0);
        acc[0][3] = __builtin_amdgcn_mfma_f32_16x16x32_bf16(a0,b3,acc[0][3],0,0,0);
        acc[1][0] = __builtin_amdgcn_mfma_f32_16x16x32_bf16(a1,b0,acc[1][0],0,0,0);
        acc[1][1] = __builtin_amdgcn_mfma_f32_16x16x32_bf16(a1,b1,acc[1][1],0,0,0);
        acc[1][2] = __builtin_amdgcn_mfma_f32_16x16x32_bf16(a1,b2,acc[1][2],0,0,0);
        acc[1][3] = __builtin_amdgcn_mfma_f32_16x16x32_bf16(a1,b3,acc[1][3],0,0,0);
    }
    #pragma unroll
    for (int nt=0; nt<4; nt++){
        const int col = bn + (nt<<4) + ml;
        const int atom = col / 86;
        const int f = col - atom*86;
        const float bv = ldf(bias, col);
        #pragma unroll
        for (int mt=0; mt<2; mt++){
            #pragma unroll
            for (int r=0; r<4; r++){
                const int row = bm + (w<<5) + (mt<<4) + (mq<<2) + r;
                float v = acc[mt][nt][r] + bv;
                if (f >= 83) v = 1.f/(1.f + expf(-v));
                stf(out_recon, (size_t)row*2752 + col, v);
            }
        }
    }
}

__global__ __launch_bounds__(256) void k_gemm(
    const int* flag, const bf16* A, const void* B, const void* bias, void* d_out)
{
    __shared__ __align__(16) char smem[15616];
    if (*flag) gemm_impl<bf16>(A, (const bf16*)B, (const bf16*)bias, d_out, smem);
    else       gemm_impl<float>(A, (const float*)B, (const float*)bias, d_out, smem);
}

// ---------------- K5: argmax, GAT1, GAT2, coords out ----------------
template<typename T>
__device__ __forceinline__ void gat_impl(
    const T* emb, const T* g1w, const T* g1b, const T* g1as, const T* g1ad,
    const T* g2w, const T* g2b, const T* g2as, const T* g2ad,
    void* d_out, char* smem)
{
    float* ic    = (float*)(smem);
    int*   amaxs = (int*)  (smem + 384);
    float* hs    = (float*)(smem + 512);
    float* xs    = (float*)(smem + 25088);
    float* U     = (float*)(smem + 49664);
    float* sa    = (float*)(smem + 61952);
    float* da    = (float*)(smem + 62336);
    float* hh    = (float*)(smem + 62720);
    float* s2    = (float*)(smem + 63104);
    float* d2    = (float*)(smem + 63232);
    float* lg    = xs;
    float* node  = U;
    float* att   = U;
    float* att2  = U;

    T* out_recon = (T*)d_out + RECON_OFF;
    const int b = blockIdx.x, t = threadIdx.x;

    for (int i=t; i<2656; i+=256){
        int n = i/83, f = i - n*83;
        lg[i] = ldf(out_recon, (size_t)b*2752 + n*86 + f);
    }
    if (t < 96){
        int n = t/3, c = t - 3*(t/3);
        ic[t] = ldf(out_recon, (size_t)b*2752 + n*86 + 83 + c);
    }
    __syncthreads();
    if (t < 32){
        const float* lp = lg + t*83;
        float best = lp[0]; int bi = 0;
        for (int f=1; f<83; f++){ float v = lp[f]; if (v > best){ best=v; bi=f; } }
        amaxs[t] = bi;
    }
    __syncthreads();
    for (int i=t; i<608; i+=256){
        int n = i/19, f = i - n*19;
        node[n*19+f] = (f<16) ? ldf(emb, amaxs[n]*16+f) : ic[n*3 + (f-16)];
    }
    __syncthreads();
    if (t < 192){
        float wc[19];
        #pragma unroll
        for (int f=0;f<19;f++) wc[f] = ldf(g1w, f*192+t);
        for (int n=0;n<32;n++){
            float a = 0.f;
            #pragma unroll
            for (int f=0;f<19;f++) a += node[n*19+f]*wc[f];
            hs[n*192+t] = a;
        }
    }
    __syncthreads();
    if (t < 96){
        int n = t/3, hd = t - 3*(t/3);
        float s=0.f, d=0.f;
        for (int c=0;c<64;c++){
            float hv = hs[n*192 + hd*64 + c];
            s += hv*ldf(g1as, hd*64+c);
            d += hv*ldf(g1ad, hd*64+c);
        }
        sa[n*3+hd] = s; da[n*3+hd] = d;
    }
    __syncthreads();
    if (t < 96){
        int i = t/3, hd = t - 3*(t/3);
        float di = da[i*3+hd];
        float ev[32]; float m = -1e30f;
        for (int j=0;j<32;j++){
            float e = di + sa[j*3+hd];
            e = (e > 0.f) ? e : 0.2f*e;
            ev[j] = e; m = fmaxf(m, e);
        }
        float ssum = 0.f;
        for (int j=0;j<32;j++){ float p = expf(ev[j]-m); ev[j]=p; ssum += p; }
        float inv = 1.f/ssum;
        for (int j=0;j<32;j++) att[(i*3+hd)*32 + j] = ev[j]*inv;
    }
    __syncthreads();
    if (t < 192){
        int hd = t >> 6;
        float bb = ldf(g1b, t);
        for (int i=0;i<32;i++){
            float a = 0.f;
            for (int j=0;j<32;j++) a += att[(i*3+hd)*32 + j]*hs[j*192+t];
            a += bb;
            xs[i*192+t] = (a > 0.f) ? a : (expf(a) - 1.f);
        }
    }
    __syncthreads();
    if (t < 96){
        int n = t/3, c = t - 3*(t/3);
        float a = 0.f;
        for (int f=0;f<192;f++) a += xs[n*192+f]*ldf(g2w, f*3+c);
        hh[n*3+c] = a;
    }
    __syncthreads();
    if (t < 32){
        float s=0.f,d=0.f;
        #pragma unroll
        for (int c=0;c<3;c++){ s += hh[t*3+c]*ldf(g2as,c); d += hh[t*3+c]*ldf(g2ad,c); }
        s2[t]=s; d2[t]=d;
    }
    __syncthreads();
    if (t < 32){
        float di = d2[t];
        float ev[32]; float m=-1e30f;
        for (int j=0;j<32;j++){
            float e = di + s2[j]; e = (e>0.f)?e:0.2f*e; ev[j]=e; m=fmaxf(m,e);
        }
        float ssum=0.f;
        for (int j=0;j<32;j++){ float p=expf(ev[j]-m); ev[j]=p; ssum+=p; }
        float inv = 1.f/ssum;
        for (int j=0;j<32;j++) att2[t*32+j] = ev[j]*inv;
    }
    __syncthreads();
    if (t < 96){
        int i = t/3, c = t - 3*(t/3);
        float a = 0.f;
        for (int j=0;j<32;j++) a += att2[i*32+j]*hh[j*3+c];
        a += ldf(g2b, c);
        float adj = tanhf(a)*0.1f;
        float cr = ic[i*3+c] + adj;
        cr -= floorf(cr);
        stf(out_recon, (size_t)b*2752 + i*86 + 83 + c, cr);
    }
}

__global__ __launch_bounds__(256) void k_gat(
    const int* flag, const void* emb,
    const void* g1w, const void* g1b, const void* g1as, const void* g1ad,
    const void* g2w, const void* g2b, const void* g2as, const void* g2ad,
    void* d_out)
{
    __shared__ __align__(16) char smem[63360];
    if (*flag) gat_impl<bf16>((const bf16*)emb,(const bf16*)g1w,(const bf16*)g1b,
        (const bf16*)g1as,(const bf16*)g1ad,(const bf16*)g2w,(const bf16*)g2b,
        (const bf16*)g2as,(const bf16*)g2ad, d_out, smem);
    else       gat_impl<float>((const float*)emb,(const float*)g1w,(const float*)g1b,
        (const float*)g1as,(const float*)g1ad,(const float*)g2w,(const float*)g2b,
        (const float*)g2as,(const float*)g2ad, d_out, smem);
}

extern "C" void kernel_launch(void* const* d_in, const int* in_sizes, int n_in,
                              void* d_out, int out_size, void* d_ws, size_t ws_size,
                              hipStream_t stream)
{
    (void)in_sizes; (void)n_in; (void)out_size;
    char* ws = (char*)d_ws;
    const bool big = (ws_size >= 83000000ull);

    if (big){
        bf16*  Amat  = (bf16*)(ws);                    // 33,554,432
        bf16*  Wc2T  = (bf16*)(ws + 33554432);         // 33,554,432 (dead after gemm3)
        bf16*  BtW2  = (bf16*)(ws + 33554432);         // 46,137,344 (overlays Wc2T..Wc1T after gemm3)
        bf16*  c1    = (bf16*)(ws + 67108864);         //  8,388,608
        bf16*  d0    = (bf16*)(ws + 75497472);         //  2,097,152
        bf16*  Wc1T  = (bf16*)(ws + 77594624);         //  2,097,152
        bf16*  zc    = (bf16*)(ws + 79691776);         //    655,360
        bf16*  BtW1  = (bf16*)(ws + 80347136);         //    163,840
        float* biasf = (float*)(ws + 80510976);        //     13,504
        float* gbuf  = (float*)(ws + 80524480);        //  1,048,576
        float* zbuf  = (float*)(ws + 81573056);        //    524,288
        int*   flag  = (int*)  (ws + 82097344);

        k_detect<<<1, 64, 0, stream>>>(d_in[5], flag);
        k_prep<<<64, 256, 0, stream>>>(flag, d_in[21], d_in[23], d_in[25], d_in[27], d_in[20], biasf, BtW1);
        k_expWc1<<<512, 256, 0, stream>>>(flag, d_in[22], Wc1T);
        k_expWc2<<<8192, 256, 0, stream>>>(flag, d_in[24], Wc2T);
        k_encoder<<<2048, 256, 0, stream>>>(flag, (const int*)d_in[0], d_in[1], d_in[5],
            d_in[6], d_in[7], d_in[8], d_in[9], d_in[10], d_in[11], gbuf);
        k_latent<<<2048, 64, 0, stream>>>(flag, d_in[2], d_in[4], d_in[3],
            d_in[12], d_in[13], d_in[14], d_in[15],
            d_in[16], d_in[17], d_in[18], d_in[19],
            d_in[28], d_in[29], d_in[30], d_in[31],
            gbuf, zbuf, zc, d_out);
        k_gemm128<0><<<dim3(16,4),  256, 0, stream>>>(zc, BtW1, 160,  biasf,     0, d0,   512);
        k_gemm128<1><<<dim3(16,16), 256, 0, stream>>>(d0, Wc1T, 512,  biasf+512, 6, c1,   2048);
        k_gemm128<1><<<dim3(16,64), 256, 0, stream>>>(c1, Wc2T, 2048, biasf+544, 9, Amat, 8192);
        k_transW<<<dim3(128,44), 256, 0, stream>>>(flag, d_in[26], BtW2);
        k_gemm128_recon<<<dim3(16,22), 256, 0, stream>>>(flag, Amat, BtW2, biasf, d_out);
        k_gat<<<2048, 256, 0, stream>>>(flag, d_in[5],
            d_in[32], d_in[33], d_in[34], d_in[35],
            d_in[36], d_in[37], d_in[38], d_in[39], d_out);
    } else {
        bf16*  Amat = (bf16*)(ws);
        float* gbuf = (float*)(ws + 33554432);
        float* zbuf = (float*)(ws + 34603008);
        int*   flag = (int*)  (ws + 35127296);

        k_detect<<<1, 64, 0, stream>>>(d_in[5], flag);
        k_encoder<<<2048, 256, 0, stream>>>(flag, (const int*)d_in[0], d_in[1], d_in[5],
            d_in[6], d_in[7], d_in[8], d_in[9], d_in[10], d_in[11], gbuf);
        k_latent<<<2048, 64, 0, stream>>>(flag, d_in[2], d_in[4], d_in[3],
            d_in[12], d_in[13], d_in[14], d_in[15],
            d_in[16], d_in[17], d_in[18], d_in[19],
            d_in[28], d_in[29], d_in[30], d_in[31],
            gbuf, zbuf, (bf16*)nullptr, d_out);
        k_conv<<<2048, 256, 0, stream>>>(flag, zbuf, d_in[3],
            d_in[20], d_in[21], d_in[22], d_in[23], d_in[24], d_in[25], Amat);
        k_gemm<<<dim3(16,43), 256, 0, stream>>>(flag, Amat, d_in[26], d_in[27], d_out);
        k_gat<<<2048, 256, 0, stream>>>(flag, d_in[5],
            d_in[32], d_in[33], d_in[34], d_in[35],
            d_in[36], d_in[37], d_in[38], d_in[39], d_out);
    }
}

// Round 5
// 707.960 us; speedup vs baseline: 2.8379x; 1.1239x over previous
//
#include <hip/hip_runtime.h>
#include <hip/hip_bf16.h>

typedef __hip_bfloat16 bf16;
typedef __attribute__((ext_vector_type(8))) __bf16 bf16x8;
typedef __attribute__((ext_vector_type(4))) float f32x4;

__device__ __forceinline__ float b2f(bf16 v){ return __bfloat162float(v); }
__device__ __forceinline__ bf16  f2b(float v){ return __float2bfloat16(v); }

template<typename T> __device__ __forceinline__ float ldf(const T* p, size_t i);
template<> __device__ __forceinline__ float ldf<float>(const float* p, size_t i){ return p[i]; }
template<> __device__ __forceinline__ float ldf<bf16 >(const bf16*  p, size_t i){ return b2f(p[i]); }

template<typename T> __device__ __forceinline__ void stf(T* p, size_t i, float v);
template<> __device__ __forceinline__ void stf<float>(float* p, size_t i, float v){ p[i] = v; }
template<> __device__ __forceinline__ void stf<bf16 >(bf16*  p, size_t i, float v){ p[i] = f2b(v); }

#define NATM 32
#define RECON_OFF 262144          // 2*2048*64 elements (mu, logvar)
#define RL_OFF    5898240         // + 2048*2752

// async global->LDS, 16B per lane, dest = wave-uniform base + lane*16
__device__ __forceinline__ void glds16(const bf16* g, bf16* l){
    __builtin_amdgcn_global_load_lds(
        (const __attribute__((address_space(1))) unsigned int*)g,
        (__attribute__((address_space(3))) unsigned int*)l,
        16, 0, 0);
}

// ---------------- K0: dtype detect ----------------
__global__ __launch_bounds__(64) void k_detect(const void* emb, int* flag)
{
    __shared__ int cnt[64];
    const int t = threadIdx.x;
    const unsigned short* p = (const unsigned short*)emb;
    int c = 0;
    for (int i = t; i < 256; i += 64){
        int e = (p[i] >> 7) & 0xFF;
        c += (e >= 110 && e <= 132) ? 1 : 0;
    }
    cnt[t] = c;
    __syncthreads();
    if (t == 0){
        int s = 0;
        for (int i = 0; i < 64; i++) s += cnt[i];
        *flag = (s >= 200) ? 1 : 0;   // 1 = bf16, 0 = f32
    }
}

// ---------------- K-prepEnc: W1t[256][32], W2t[128][256], ebias[384] ----------------
template<typename T>
__device__ __forceinline__ void prepEnc_impl(
    const T* w1, const T* b1, const T* w2, const T* b2,
    bf16* W1t, bf16* W2t, float* ebias)
{
    const int gt = blockIdx.x*256 + threadIdx.x;
    const int gs = gridDim.x*256;
    for (int e = gt; e < 8192; e += gs){
        int n = e >> 5, k = e & 31;
        W1t[e] = (k < 19) ? f2b(ldf(w1, (size_t)k*256 + n)) : f2b(0.f);
    }
    for (int e = gt; e < 32768; e += gs){
        int n = e >> 8, k = e & 255;
        W2t[e] = f2b(ldf(w2, (size_t)k*128 + n));
    }
    for (int i = gt; i < 384; i += gs)
        ebias[i] = (i < 256) ? ldf(b1, i) : ldf(b2, i-256);
}

__global__ __launch_bounds__(256) void k_prepEnc(
    const int* flag, const void* w1, const void* b1, const void* w2, const void* b2,
    bf16* W1t, bf16* W2t, float* ebias)
{
    if (*flag) prepEnc_impl<bf16>((const bf16*)w1,(const bf16*)b1,(const bf16*)w2,(const bf16*)b2, W1t, W2t, ebias);
    else       prepEnc_impl<float>((const float*)w1,(const float*)b1,(const float*)w2,(const float*)b2, W1t, W2t, ebias);
}

// ---------------- K-buildA: Abuf[65536][32] = [emb[elements], coords, pad0] ----------------
template<typename T>
__device__ __forceinline__ void buildA_impl(
    const int* elements, const T* coords, const T* emb, bf16* Abuf)
{
    const int r = blockIdx.x*256 + threadIdx.x;   // 0..65535
    const int el = elements[r];
    bf16 row[32];
    #pragma unroll
    for (int f=0; f<16; f++) row[f] = f2b(ldf(emb, (size_t)el*16 + f));
    #pragma unroll
    for (int c=0; c<3; c++) row[16+c] = f2b(ldf(coords, (size_t)r*3 + c));
    #pragma unroll
    for (int f=19; f<32; f++) row[f] = f2b(0.f);
    *(int4*)(&Abuf[(size_t)r*32])      = *(int4*)(&row[0]);
    *(int4*)(&Abuf[(size_t)r*32 + 8])  = *(int4*)(&row[8]);
    *(int4*)(&Abuf[(size_t)r*32 + 16]) = *(int4*)(&row[16]);
    *(int4*)(&Abuf[(size_t)r*32 + 24]) = *(int4*)(&row[24]);
}

__global__ __launch_bounds__(256) void k_buildA(
    const int* flag, const int* elements, const void* coords, const void* emb, bf16* Abuf)
{
    if (*flag) buildA_impl<bf16>(elements,(const bf16*)coords,(const bf16*)emb, Abuf);
    else       buildA_impl<float>(elements,(const float*)coords,(const float*)emb, Abuf);
}

// ---------------- K-pool: gbuf[b][j] = mean_n(h2) @ w3 + b3 ----------------
template<typename T>
__device__ __forceinline__ void pool_impl(
    const float* h2, const T* w3, const T* b3, float* gbuf)
{
    __shared__ float hsum[128];
    const int b = blockIdx.x, t = threadIdx.x;
    float s = 0.f;
    for (int n=0; n<32; n++) s += h2[(size_t)(b*32+n)*128 + t];
    hsum[t] = s;
    __syncthreads();
    float a = 0.f;
    for (int k=0; k<128; k++) a += hsum[k]*ldf(w3, (size_t)k*128 + t);
    gbuf[b*128+t] = a*(1.f/32.f) + ldf(b3, t);
}

__global__ __launch_bounds__(128) void k_pool(
    const int* flag, const float* h2, const void* w3, const void* b3, float* gbuf)
{
    if (*flag) pool_impl<bf16>(h2, (const bf16*)w3, (const bf16*)b3, gbuf);
    else       pool_impl<float>(h2, (const float*)w3, (const float*)b3, gbuf);
}

// ---------------- K1 (fallback): atom encoder ----------------
template<typename T>
__device__ __forceinline__ void enc_impl(
    const int* elements, const T* coords, const T* emb,
    const T* w1, const T* b1, const T* w2, const T* b2c,
    const T* w3, const T* b3, float* gbuf, char* smem)
{
    float (*af)[19]   = (float(*)[19])(smem);
    float (*h1)[256]  = (float(*)[256])(smem + 2432);
    float (*h2s)[128] = (float(*)[128])(smem + 35200);
    float* hsum       = (float*)(smem + 51584);
    const int b = blockIdx.x, t = threadIdx.x;

    for (int idx = t; idx < NATM*19; idx += 256){
        int n = idx/19, f = idx - n*19;
        af[n][f] = (f < 16) ? ldf(emb, (size_t)elements[b*NATM+n]*16 + f)
                            : ldf(coords, (size_t)(b*NATM+n)*3 + (f-16));
    }
    __syncthreads();
    {
        float wc[19];
        #pragma unroll
        for (int f=0; f<19; f++) wc[f] = ldf(w1, f*256 + t);
        float bb = ldf(b1, t);
        for (int n=0; n<NATM; n++){
            float a = bb;
            #pragma unroll
            for (int f=0; f<19; f++) a += af[n][f]*wc[f];
            h1[n][t] = fmaxf(a, 0.f);
        }
    }
    __syncthreads();
    {
        const int j = t & 127, half = t >> 7;
        float bb = ldf(b2c, j);
        float acc[16];
        #pragma unroll
        for (int n=0;n<16;n++) acc[n] = bb;
        for (int k=0;k<256;k+=4){
            float wa = ldf(w2, (k+0)*128+j);
            float wb = ldf(w2, (k+1)*128+j);
            float wcv= ldf(w2, (k+2)*128+j);
            float wd = ldf(w2, (k+3)*128+j);
            #pragma unroll
            for (int n=0;n<16;n++){
                float4 hv = *(const float4*)(&h1[half*16+n][k]);
                acc[n] += hv.x*wa + hv.y*wb + hv.z*wcv + hv.w*wd;
            }
        }
        #pragma unroll
        for (int n=0;n<16;n++) h2s[half*16+n][j] = fmaxf(acc[n], 0.f);
    }
    __syncthreads();
    if (t < 128){
        float s = 0.f;
        for (int n=0;n<NATM;n++) s += h2s[n][t];
        hsum[t] = s;
    }
    __syncthreads();
    if (t < 128){
        float a = 0.f;
        for (int k=0;k<128;k++) a += hsum[k]*ldf(w3, k*128+t);
        gbuf[b*128+t] = a*(1.f/32.f) + ldf(b3, t);
    }
}

__global__ __launch_bounds__(256) void k_encoder(
    const int* flag, const int* elements, const void* coords, const void* emb,
    const void* w1, const void* b1, const void* w2, const void* b2,
    const void* w3, const void* b3, float* gbuf)
{
    __shared__ __align__(16) char smem[52096];
    if (*flag) enc_impl<bf16>(elements,(const bf16*)coords,(const bf16*)emb,
        (const bf16*)w1,(const bf16*)b1,(const bf16*)w2,(const bf16*)b2,
        (const bf16*)w3,(const bf16*)b3, gbuf, smem);
    else       enc_impl<float>(elements,(const float*)coords,(const float*)emb,
        (const float*)w1,(const float*)b1,(const float*)w2,(const float*)b2,
        (const float*)w3,(const float*)b3, gbuf, smem);
}

// ---------------- K2: lattice enc + mu/logvar/z + recon_lattice (+ zc row) ----------------
template<typename T>
__device__ __forceinline__ void lat_impl(
    const T* lattice, const T* eps, const T* comp,
    const T* lw1, const T* lb1, const T* lw2, const T* lb2,
    const T* muw, const T* mub, const T* lvw, const T* lvb,
    const T* dw1, const T* db1, const T* dw2, const T* db2,
    const float* gbuf, float* zbuf, bf16* zc, void* d_out, char* smem)
{
    float* comb = (float*)(smem);
    float* lat  = (float*)(smem + 768);
    float* l1   = (float*)(smem + 832);
    float* zz   = (float*)(smem + 1088);
    float* r1   = (float*)(smem + 1344);
    T* out_mu = (T*)d_out;
    T* out_lv = out_mu + 131072;
    T* out_rl = out_mu + RL_OFF;
    const int b = blockIdx.x, t = threadIdx.x;
    comb[t]    = gbuf[b*128 + t];
    comb[64+t] = gbuf[b*128 + 64 + t];
    if (t < 9) lat[t] = ldf(lattice, b*9 + t);
    __syncthreads();
    {
        float a = ldf(lb1, t);
        #pragma unroll
        for (int f=0; f<9; f++) a += lat[f]*ldf(lw1, f*64+t);
        l1[t] = fmaxf(a, 0.f);
    }
    __syncthreads();
    {
        float a = ldf(lb2, t);
        for (int k=0;k<64;k++) a += l1[k]*ldf(lw2, k*64+t);
        comb[128+t] = a;
    }
    __syncthreads();
    float mu = ldf(mub, t), lv = ldf(lvb, t);
    for (int k=0;k<192;k++){
        float c = comb[k];
        mu += c*ldf(muw, k*64+t);
        lv += c*ldf(lvw, k*64+t);
    }
    float z = mu + ldf(eps, b*64+t)*expf(0.5f*lv);
    stf(out_mu, (size_t)b*64+t, mu);
    stf(out_lv, (size_t)b*64+t, lv);
    zbuf[b*64+t] = z;
    zz[t] = z;
    __syncthreads();
    if (zc){
        for (int i=t; i<160; i+=64){
            float v = (i<64) ? zz[i] : ((i<147) ? ldf(comp, b*83 + (i-64)) : 0.f);
            zc[(size_t)b*160 + i] = f2b(v);
        }
    }
    {
        float a = ldf(db1, t);
        for (int k=0;k<64;k++) a += zz[k]*ldf(dw1, k*64+t);
        r1[t] = fmaxf(a, 0.f);
    }
    __syncthreads();
    if (t < 9){
        float a = ldf(db2, t);
        for (int k=0;k<64;k++) a += r1[k]*ldf(dw2, k*9+t);
        stf(out_rl, (size_t)b*9+t, a);
    }
}

__global__ __launch_bounds__(64) void k_latent(
    const int* flag, const void* lattice, const void* eps, const void* comp,
    const void* lw1, const void* lb1, const void* lw2, const void* lb2,
    const void* muw, const void* mub, const void* lvw, const void* lvb,
    const void* dw1, const void* db1, const void* dw2, const void* db2,
    const float* gbuf, float* zbuf, bf16* zc, void* d_out)
{
    __shared__ __align__(16) char smem[1600];
    if (*flag) lat_impl<bf16>((const bf16*)lattice,(const bf16*)eps,(const bf16*)comp,
        (const bf16*)lw1,(const bf16*)lb1,(const bf16*)lw2,(const bf16*)lb2,
        (const bf16*)muw,(const bf16*)mub,(const bf16*)lvw,(const bf16*)lvb,
        (const bf16*)dw1,(const bf16*)db1,(const bf16*)dw2,(const bf16*)db2,
        gbuf, zbuf, zc, d_out, smem);
    else       lat_impl<float>((const float*)lattice,(const float*)eps,(const float*)comp,
        (const float*)lw1,(const float*)lb1,(const float*)lw2,(const float*)lb2,
        (const float*)muw,(const float*)mub,(const float*)lvw,(const float*)lvb,
        (const float*)dw1,(const float*)db1,(const float*)dw2,(const float*)db2,
        gbuf, zbuf, zc, d_out, smem);
}

// ---------------- K-prep: biases->f32, BtW1 ----------------
template<typename T>
__device__ __forceinline__ void prep_impl(
    const T* db1, const T* c1b, const T* c2b, const T* db2, const T* dw1,
    float* biasf, bf16* BtW1)
{
    const int gt = blockIdx.x*256 + threadIdx.x;
    const int gs = gridDim.x*256;
    for (int i = gt; i < 3376; i += gs){
        float v;
        if (i < 512)      v = ldf(db1, i);
        else if (i < 544) v = ldf(c1b, i-512);
        else if (i < 560) v = ldf(c2b, i-544);
        else              v = (i-560 < 2752) ? ldf(db2, i-560) : 0.f;
        biasf[i] = v;
    }
    for (int e = gt; e < 512*160; e += gs){
        int n = e/160, k = e - n*160;
        BtW1[e] = f2b((k < 147) ? ldf(dw1, (size_t)k*512 + n) : 0.f);
    }
}

__global__ __launch_bounds__(256) void k_prep(
    const int* flag, const void* db1, const void* c1b, const void* c2b,
    const void* db2, const void* dw1, float* biasf, bf16* BtW1)
{
    if (*flag) prep_impl<bf16>((const bf16*)db1,(const bf16*)c1b,(const bf16*)c2b,
        (const bf16*)db2,(const bf16*)dw1, biasf, BtW1);
    else       prep_impl<float>((const float*)db1,(const float*)c1b,(const float*)c2b,
        (const float*)db2,(const float*)dw1, biasf, BtW1);
}

// ---------------- K-exp1: Wc1T from ct1_w ----------------
template<typename T>
__device__ __forceinline__ void expWc1_impl(const T* w, bf16* Wc1T)
{
    const int t = threadIdx.x;
    const int n = blockIdx.x*4 + (t >> 6);
    const int k0 = (t & 63) << 3;
    const int o = n >> 6, spo = n & 63;
    const int zd = spo >> 4, zh = (spo >> 2) & 3, zw = spo & 3;
    bf16 v8[8];
    #pragma unroll
    for (int j = 0; j < 8; j++){
        int k = k0 + j;
        int i = k >> 3, sp = k & 7;
        int td = sp >> 2, th = (sp >> 1) & 1, tw = sp & 1;
        int kd = 2*td + 1 - zd, kh = 2*th + 1 - zh, kw = 2*tw + 1 - zw;
        float v = 0.f;
        if (kd >= 0 && kd < 3 && kh >= 0 && kh < 3 && kw >= 0 && kw < 3)
            v = ldf(w, (size_t)(o*64 + i)*27 + kd*9 + kh*3 + kw);
        v8[j] = f2b(v);
    }
    *(int4*)(&Wc1T[(size_t)n*512 + k0]) = *(int4*)v8;
}

__global__ __launch_bounds__(256) void k_expWc1(const int* flag, const void* w, bf16* Wc1T)
{
    if (*flag) expWc1_impl<bf16>((const bf16*)w, Wc1T);
    else       expWc1_impl<float>((const float*)w, Wc1T);
}

// ---------------- K-exp2: Wc2T from ct2_w ----------------
template<typename T>
__device__ __forceinline__ void expWc2_impl(const T* w, bf16* Wc2T)
{
    const int n = blockIdx.x;
    const int k0 = threadIdx.x << 3;
    const int o = n >> 9, spo = n & 511;
    const int zd = spo >> 6, zh = (spo >> 3) & 7, zw = spo & 7;
    bf16 v8[8];
    #pragma unroll
    for (int j = 0; j < 8; j++){
        int k = k0 + j;
        int i = k >> 6, sp = k & 63;
        int td = sp >> 4, th = (sp >> 2) & 3, tw = sp & 3;
        int kd = 2*td + 1 - zd, kh = 2*th + 1 - zh, kw = 2*tw + 1 - zw;
        float v = 0.f;
        if (kd >= 0 && kd < 3 && kh >= 0 && kh < 3 && kw >= 0 && kw < 3)
            v = ldf(w, (size_t)(o*32 + i)*27 + kd*9 + kh*3 + kw);
        v8[j] = f2b(v);
    }
    *(int4*)(&Wc2T[(size_t)n*2048 + k0]) = *(int4*)v8;
}

__global__ __launch_bounds__(256) void k_expWc2(const int* flag, const void* w, bf16* Wc2T)
{
    if (*flag) expWc2_impl<bf16>((const bf16*)w, Wc2T);
    else       expWc2_impl<float>((const float*)w, Wc2T);
}

// ---------------- K-transW: dec_w2 [8192][2752] -> BtW2 [2816][8192] ----------------
template<typename T>
__device__ __forceinline__ void transW_impl(const T* B, bf16* Bt)
{
    __shared__ bf16 tile[64][65];
    const int kb = blockIdx.x << 6;
    const int nb = blockIdx.y << 6;
    const int t = threadIdx.x;
    for (int idx=t; idx<4096; idx+=256){
        int k = idx>>6, n = idx&63;
        int col = nb + n;
        tile[k][n] = (col < 2752) ? f2b(ldf(B, (size_t)(kb+k)*2752 + col)) : f2b(0.f);
    }
    __syncthreads();
    for (int idx=t; idx<4096; idx+=256){
        int n = idx>>6, k = idx&63;
        Bt[(size_t)(nb+n)*8192 + kb + k] = tile[k][n];
    }
}

__global__ __launch_bounds__(256) void k_transW(const int* flag, const void* B, bf16* Bt)
{
    if (*flag) transW_impl<bf16>((const bf16*)B, Bt);
    else       transW_impl<float>((const float*)B, Bt);
}

// ---------------- k_gemm128: 128x128 tile, glds staging, swizzled LDS ----------------
struct GemmAcc { f32x4 a[4][4]; };

__device__ __forceinline__ void gemm128_core(
    const bf16* __restrict__ A, const bf16* __restrict__ Bt, int K,
    int bm, int bn, bf16* As, bf16* Bs, GemmAcc& G)
{
    const int t = threadIdx.x;
    const int w = t >> 6, lane = t & 63;
    const int wm = w >> 1, wn = w & 1;
    const int ml = lane & 15, mq = lane >> 4;
    const int lrow = lane >> 2;
    const int gchunk = (lane & 3) ^ ((lane >> 3) & 3);
    const int rchunk = (mq ^ ((ml >> 1) & 3)) << 3;

    const size_t arow = (size_t)(bm + w*32 + lrow);
    const size_t brow = (size_t)(bn + w*32 + lrow);

    for (int kt = 0; kt < K; kt += 32){
        __syncthreads();
        #pragma unroll
        for (int c = 0; c < 2; c++){
            glds16(A  + (arow + c*16)*K + kt + gchunk*8, &As[(w*32 + c*16)*32]);
            glds16(Bt + (brow + c*16)*K + kt + gchunk*8, &Bs[(w*32 + c*16)*32]);
        }
        __syncthreads();
        bf16x8 af[4], bfr[4];
        #pragma unroll
        for (int i=0;i<4;i++) af[i]  = *(const bf16x8*)(&As[(wm*64 + i*16 + ml)*32 + rchunk]);
        #pragma unroll
        for (int j=0;j<4;j++) bfr[j] = *(const bf16x8*)(&Bs[(wn*64 + j*16 + ml)*32 + rchunk]);
        #pragma unroll
        for (int i=0;i<4;i++)
            #pragma unroll
            for (int j=0;j<4;j++)
                G.a[i][j] = __builtin_amdgcn_mfma_f32_16x16x32_bf16(af[i], bfr[j], G.a[i][j], 0,0,0);
    }
}

template<typename OutT, int ACT>   // ACT: 0 none, 1 relu
__global__ __launch_bounds__(256) void k_gemm128(
    const bf16* __restrict__ A, const bf16* __restrict__ Bt, int K,
    const float* __restrict__ biasf, int bshift,
    OutT* __restrict__ C, int ldc)
{
    __shared__ __align__(16) bf16 As[128*32];
    __shared__ __align__(16) bf16 Bs[128*32];
    const int t = threadIdx.x;
    const int bm = blockIdx.x << 7, bn = blockIdx.y << 7;
    const int w = t >> 6, lane = t & 63;
    const int wm = w >> 1, wn = w & 1;
    const int ml = lane & 15, mq = lane >> 4;
    GemmAcc G;
    #pragma unroll
    for (int i=0;i<4;i++)
        #pragma unroll
        for (int j=0;j<4;j++) G.a[i][j] = (f32x4){0.f,0.f,0.f,0.f};
    gemm128_core(A, Bt, K, bm, bn, As, Bs, G);
    #pragma unroll
    for (int j=0;j<4;j++){
        const int col = bn + wn*64 + (j<<4) + ml;
        const float bv = biasf[col >> bshift];
        #pragma unroll
        for (int i=0;i<4;i++){
            #pragma unroll
            for (int r=0;r<4;r++){
                const int row = bm + wm*64 + (i<<4) + (mq<<2) + r;
                float v = G.a[i][j][r] + bv;
                if (ACT == 1) v = fmaxf(v, 0.f);
                stf(C, (size_t)row*ldc + col, v);
            }
        }
    }
}

// ---------------- k_gemm_recon64: 64x128 tile (grid-limited recon GEMM) ----------------
__global__ __launch_bounds__(256) void k_gemm_recon64(
    const int* __restrict__ flag,
    const bf16* __restrict__ A, const bf16* __restrict__ Bt,
    const float* __restrict__ biasf, void* __restrict__ d_out)
{
    __shared__ __align__(16) bf16 As[64*32];
    __shared__ __align__(16) bf16 Bs[128*32];
    const int K = 8192;
    const int t = threadIdx.x;
    const int bm = blockIdx.x << 6, bn = blockIdx.y << 7;
    const int w = t >> 6, lane = t & 63;
    const int wm = w >> 1, wn = w & 1;
    const int ml = lane & 15, mq = lane >> 4;
    const int lrow = lane >> 2;
    const int gchunk = (lane & 3) ^ ((lane >> 3) & 3);
    const int rchunk = (mq ^ ((ml >> 1) & 3)) << 3;

    f32x4 acc[2][4];
    #pragma unroll
    for (int i=0;i<2;i++)
        #pragma unroll
        for (int j=0;j<4;j++) acc[i][j] = (f32x4){0.f,0.f,0.f,0.f};

    const size_t arow = (size_t)(bm + w*16 + lrow);
    const size_t brow = (size_t)(bn + w*32 + lrow);

    for (int kt = 0; kt < K; kt += 32){
        __syncthreads();
        glds16(A + arow*K + kt + gchunk*8, &As[(w*16)*32]);
        #pragma unroll
        for (int c = 0; c < 2; c++)
            glds16(Bt + (brow + c*16)*K + kt + gchunk*8, &Bs[(w*32 + c*16)*32]);
        __syncthreads();
        bf16x8 af[2], bfr[4];
        #pragma unroll
        for (int i=0;i<2;i++) af[i]  = *(const bf16x8*)(&As[(wm*32 + i*16 + ml)*32 + rchunk]);
        #pragma unroll
        for (int j=0;j<4;j++) bfr[j] = *(const bf16x8*)(&Bs[(wn*64 + j*16 + ml)*32 + rchunk]);
        #pragma unroll
        for (int i=0;i<2;i++)
            #pragma unroll
            for (int j=0;j<4;j++)
                acc[i][j] = __builtin_amdgcn_mfma_f32_16x16x32_bf16(af[i], bfr[j], acc[i][j], 0,0,0);
    }
    const int fl = *flag;
    #pragma unroll
    for (int j=0;j<4;j++){
        const int col = bn + wn*64 + (j<<4) + ml;
        if (col >= 2752) continue;
        const int f = col % 86;
        const float bv = biasf[560 + col];
        #pragma unroll
        for (int i=0;i<2;i++){
            #pragma unroll
            for (int r=0;r<4;r++){
                const int row = bm + wm*32 + (i<<4) + (mq<<2) + r;
                float v = acc[i][j][r] + bv;
                if (f >= 83) v = 1.f/(1.f + expf(-v));
                if (fl) stf((bf16*)d_out + RECON_OFF, (size_t)row*2752 + col, v);
                else    stf((float*)d_out + RECON_OFF, (size_t)row*2752 + col, v);
            }
        }
    }
}

// ---------------- K3 (fallback): conv chain ----------------
template<typename T>
__device__ __forceinline__ void conv_impl(
    const float* zbuf, const T* comp,
    const T* dw1, const T* db1, const T* c1w, const T* c1b,
    const T* c2w, const T* c2b, bf16* Amat, char* smem)
{
    float* zc        = (float*)(smem);
    float (*d0s)[8]  = (float(*)[8])(smem + 640);
    float (*c1s)[64] = (float(*)[64])(smem + 2688);
    bf16* w2s        = (bf16*)(smem + 10880);
    const int b = blockIdx.x, t = threadIdx.x;
    for (int i=t; i<16*32*27; i+=256) w2s[i] = f2b(ldf(c2w, i));
    if (t < 147) zc[t] = (t < 64) ? zbuf[b*64+t] : ldf(comp, b*83 + (t-64));
    __syncthreads();
    #pragma unroll
    for (int jj=0; jj<2; jj++){
        int j = t + (jj<<8);
        float a = ldf(db1, j);
        for (int k=0;k<147;k++) a += zc[k]*ldf(dw1, k*512+j);
        d0s[j>>3][j&7] = a;
    }
    __syncthreads();
    {
        const int o = t>>3;
        const float bias = ldf(c1b, o);
        const T* wb = c1w + o*64*27;
        for (int u=0; u<8; u++){
            int sp = (t&7) + (u<<3);
            int zd = sp>>4, zh = (sp>>2)&3, zw = sp&3;
            float acc = bias;
            for (int kd=0;kd<3;kd++){
                int qd = zd+kd-1; if (qd<0 || (qd&1) || qd>=4) continue; int td=qd>>1;
                for (int kh=0;kh<3;kh++){
                    int qh = zh+kh-1; if (qh<0 || (qh&1) || qh>=4) continue; int th=qh>>1;
                    for (int kw=0;kw<3;kw++){
                        int qw = zw+kw-1; if (qw<0 || (qw&1) || qw>=4) continue; int tw=qw>>1;
                        const int koff = kd*9+kh*3+kw;
                        const int spi = td*4+th*2+tw;
                        float s = 0.f;
                        #pragma unroll 8
                        for (int i=0;i<64;i++) s += ldf(wb, i*27+koff)*d0s[i][spi];
                        acc += s;
                    }
                }
            }
            c1s[o][sp] = fmaxf(acc, 0.f);
        }
    }
    __syncthreads();
    {
        const int o = t>>4;
        const float bias = ldf(c2b, o);
        for (int u=0; u<32; u++){
            int sp = (t&15) + (u<<4);
            int zd = sp>>6, zh=(sp>>3)&7, zw=sp&7;
            float acc = bias;
            for (int kd=0;kd<3;kd++){
                int qd = zd+kd-1; if (qd<0 || (qd&1) || qd>=8) continue; int td=qd>>1;
                for (int kh=0;kh<3;kh++){
                    int qh = zh+kh-1; if (qh<0 || (qh&1) || qh>=8) continue; int th=qh>>1;
                    for (int kw=0;kw<3;kw++){
                        int qw = zw+kw-1; if (qw<0 || (qw&1) || qw>=8) continue; int tw=qw>>1;
                        const int koff = kd*9+kh*3+kw;
                        const int spi = td*16+th*4+tw;
                        const int wbase = (o*32)*27 + koff;
                        float s = 0.f;
                        #pragma unroll 8
                        for (int i=0;i<32;i++) s += b2f(w2s[wbase + i*27])*c1s[i][spi];
                        acc += s;
                    }
                }
            }
            Amat[(size_t)b*8192 + o*512 + sp] = f2b(fmaxf(acc, 0.f));
        }
    }
}

__global__ __launch_bounds__(256) void k_conv(
    const int* flag, const float* zbuf, const void* comp,
    const void* dw1, const void* db1, const void* c1w, const void* c1b,
    const void* c2w, const void* c2b, bf16* Amat)
{
    __shared__ __align__(16) char smem[38528];
    if (*flag) conv_impl<bf16>(zbuf,(const bf16*)comp,(const bf16*)dw1,(const bf16*)db1,
        (const bf16*)c1w,(const bf16*)c1b,(const bf16*)c2w,(const bf16*)c2b, Amat, smem);
    else       conv_impl<float>(zbuf,(const float*)comp,(const float*)dw1,(const float*)db1,
        (const float*)c1w,(const float*)c1b,(const float*)c2w,(const float*)c2b, Amat, smem);
}

// ---------------- K4 (fallback): dec_w2 gemm with in-kernel transpose ----------------
template<typename T> struct BStage;
template<> struct BStage<bf16>{
    static __device__ __forceinline__ void go(const bf16* p, bf16* v8){
        union{ int4 q; bf16 e[8]; } u; u.q = *(const int4*)p;
        #pragma unroll
        for (int j=0;j<8;j++) v8[j] = u.e[j];
    }
};
template<> struct BStage<float>{
    static __device__ __forceinline__ void go(const float* p, bf16* v8){
        float4 a = *(const float4*)p, b = *(const float4*)(p+4);
        v8[0]=f2b(a.x); v8[1]=f2b(a.y); v8[2]=f2b(a.z); v8[3]=f2b(a.w);
        v8[4]=f2b(b.x); v8[5]=f2b(b.y); v8[6]=f2b(b.z); v8[7]=f2b(b.w);
    }
};

__device__ __forceinline__ bf16x8 readBfrag(const bf16 (*Bs)[42], int n, int k0){
    union { bf16x8 v; unsigned int u[4]; } r;
    const unsigned int* p = (const unsigned int*)(&Bs[n][k0]);
    r.u[0]=p[0]; r.u[1]=p[1]; r.u[2]=p[2]; r.u[3]=p[3];
    return r.v;
}

template<typename T>
__device__ __forceinline__ void gemm_impl(
    const bf16* A, const T* B, const T* bias, void* d_out, char* smem)
{
    bf16 (*As)[40] = (bf16(*)[40])(smem);
    bf16 (*Bs)[42] = (bf16(*)[42])(smem + 10240);
    T* out_recon = (T*)d_out + RECON_OFF;
    const int t = threadIdx.x;
    const int bm = blockIdx.x << 7;
    const int bn = blockIdx.y << 6;
    const int w = t >> 6, lane = t & 63;
    const int ml = lane & 15, mq = lane >> 4;
    f32x4 acc[2][4];
    #pragma unroll
    for (int i=0;i<2;i++)
        #pragma unroll
        for (int j=0;j<4;j++) acc[i][j] = (f32x4){0.f,0.f,0.f,0.f};

    const int sm = t >> 2;
    const int sk = (t & 3) << 3;
    const int kk = t >> 3;
    const int nn = (t & 7) << 3;

    for (int kt = 0; kt < 8192; kt += 32){
        __syncthreads();
        {
            int4 v0 = *(const int4*)(A + (size_t)(bm + sm     )*8192 + kt + sk);
            int4 v1 = *(const int4*)(A + (size_t)(bm + sm + 64)*8192 + kt + sk);
            *(int4*)(&As[sm][sk])    = v0;
            *(int4*)(&As[sm+64][sk]) = v1;
            bf16 bv[8];
            BStage<T>::go(B + (size_t)(kt + kk)*2752 + bn + nn, bv);
            #pragma unroll
            for (int j=0;j<8;j++) Bs[nn+j][kk] = bv[j];
        }
        __syncthreads();
        bf16x8 a0 = *(const bf16x8*)(&As[(w<<5) + ml     ][mq<<3]);
        bf16x8 a1 = *(const bf16x8*)(&As[(w<<5) + 16 + ml][mq<<3]);
        bf16x8 b0 = readBfrag(Bs, ml,      mq<<3);
        bf16x8 b1 = readBfrag(Bs, 16 + ml, mq<<3);
        bf16x8 b2 = readBfrag(Bs, 32 + ml, mq<<3);
        bf16x8 b3 = readBfrag(Bs, 48 + ml, mq<<3);
        acc[0][0] = __builtin_amdgcn_mfma_f32_16x16x32_bf16(a0,b0,acc[0][0],0,0,0);
        acc[0][1] = __builtin_amdgcn_mfma_f32_16x16x32_bf16(a0,b1,acc[0][1],0,0,0);
        acc[0][2] = __builtin_amdgcn_mfma_f32_16x16x32_bf16(a0,b2,acc[0][2],0,0,0);
        acc[0][3] = __builtin_amdgcn_mfma_f32_16x16x32_bf16(a0,b3,acc[0][3],0,0,0);
        acc[1][0] = __builtin_amdgcn_mfma_f32_16x16x32_bf16(a1,b0,acc[1][0],0,0,0);
        acc[1][1] = __builtin_amdgcn_mfma_f32_16x16x32_bf16(a1,b1,acc[1][1],0,0,0);
        acc[1][2] = __builtin_amdgcn_mfma_f32_16x16x32_bf16(a1,b2,acc[1][2],0,0,0);
        acc[1][3] = __builtin_amdgcn_mfma_f32_16x16x32_bf16(a1,b3,acc[1][3],0,0,0);
    }
    #pragma unroll
    for (int nt=0; nt<4; nt++){
        const int col = bn + (nt<<4) + ml;
        const int atom = col / 86;
        const int f = col - atom*86;
        const float bv = ldf(bias, col);
        #pragma unroll
        for (int mt=0; mt<2; mt++){
            #pragma unroll
            for (int r=0; r<4; r++){
                const int row = bm + (w<<5) + (mt<<4) + (mq<<2) + r;
                float v = acc[mt][nt][r] + bv;
                if (f >= 83) v = 1.f/(1.f + expf(-v));
                stf(out_recon, (size_t)row*2752 + col, v);
            }
        }
    }
}

__global__ __launch_bounds__(256) void k_gemm(
    const int* flag, const bf16* A, const void* B, const void* bias, void* d_out)
{
    __shared__ __align__(16) char smem[15616];
    if (*flag) gemm_impl<bf16>(A, (const bf16*)B, (const bf16*)bias, d_out, smem);
    else       gemm_impl<float>(A, (const float*)B, (const float*)bias, d_out, smem);
}

// ---------------- K5: argmax, GAT1, GAT2, coords out ----------------
template<typename T>
__device__ __forceinline__ void gat_impl(
    const T* emb, const T* g1w, const T* g1b, const T* g1as, const T* g1ad,
    const T* g2w, const T* g2b, const T* g2as, const T* g2ad,
    void* d_out, char* smem)
{
    float* ic    = (float*)(smem);
    int*   amaxs = (int*)  (smem + 384);
    float* hs    = (float*)(smem + 512);
    float* xs    = (float*)(smem + 25088);
    float* U     = (float*)(smem + 49664);
    float* sa    = (float*)(smem + 61952);
    float* da    = (float*)(smem + 62336);
    float* hh    = (float*)(smem + 62720);
    float* s2    = (float*)(smem + 63104);
    float* d2    = (float*)(smem + 63232);
    float* lg    = xs;
    float* node  = U;
    float* att   = U;
    float* att2  = U;

    T* out_recon = (T*)d_out + RECON_OFF;
    const int b = blockIdx.x, t = threadIdx.x;

    for (int i=t; i<2656; i+=256){
        int n = i/83, f = i - n*83;
        lg[i] = ldf(out_recon, (size_t)b*2752 + n*86 + f);
    }
    if (t < 96){
        int n = t/3, c = t - 3*(t/3);
        ic[t] = ldf(out_recon, (size_t)b*2752 + n*86 + 83 + c);
    }
    __syncthreads();
    if (t < 32){
        const float* lp = lg + t*83;
        float best = lp[0]; int bi = 0;
        for (int f=1; f<83; f++){ float v = lp[f]; if (v > best){ best=v; bi=f; } }
        amaxs[t] = bi;
    }
    __syncthreads();
    for (int i=t; i<608; i+=256){
        int n = i/19, f = i - n*19;
        node[n*19+f] = (f<16) ? ldf(emb, amaxs[n]*16+f) : ic[n*3 + (f-16)];
    }
    __syncthreads();
    if (t < 192){
        float wc[19];
        #pragma unroll
        for (int f=0;f<19;f++) wc[f] = ldf(g1w, f*192+t);
        for (int n=0;n<32;n++){
            float a = 0.f;
            #pragma unroll
            for (int f=0;f<19;f++) a += node[n*19+f]*wc[f];
            hs[n*192+t] = a;
        }
    }
    __syncthreads();
    if (t < 96){
        int n = t/3, hd = t - 3*(t/3);
        float s=0.f, d=0.f;
        for (int c=0;c<64;c++){
            float hv = hs[n*192 + hd*64 + c];
            s += hv*ldf(g1as, hd*64+c);
            d += hv*ldf(g1ad, hd*64+c);
        }
        sa[n*3+hd] = s; da[n*3+hd] = d;
    }
    __syncthreads();
    if (t < 96){
        int i = t/3, hd = t - 3*(t/3);
        float di = da[i*3+hd];
        float ev[32]; float m = -1e30f;
        for (int j=0;j<32;j++){
            float e = di + sa[j*3+hd];
            e = (e > 0.f) ? e : 0.2f*e;
            ev[j] = e; m = fmaxf(m, e);
        }
        float ssum = 0.f;
        for (int j=0;j<32;j++){ float p = expf(ev[j]-m); ev[j]=p; ssum += p; }
        float inv = 1.f/ssum;
        for (int j=0;j<32;j++) att[(i*3+hd)*32 + j] = ev[j]*inv;
    }
    __syncthreads();
    if (t < 192){   // P6: xs = elu(att @ hs + b), j-outer with 32 accumulators
        const int hd = t >> 6;
        float bb = ldf(g1b, t);
        float a[32];
        #pragma unroll
        for (int i=0;i<32;i++) a[i] = 0.f;
        for (int j=0;j<32;j++){
            float hv = hs[j*192+t];
            #pragma unroll
            for (int i=0;i<32;i++) a[i] += att[(i*3+hd)*32 + j]*hv;
        }
        for (int i=0;i<32;i++){
            float v = a[i] + bb;
            xs[i*192+t] = (v > 0.f) ? v : (expf(v) - 1.f);
        }
    }
    __syncthreads();
    if (t < 96){
        int n = t/3, c = t - 3*(t/3);
        float a = 0.f;
        for (int f=0;f<192;f++) a += xs[n*192+f]*ldf(g2w, f*3+c);
        hh[n*3+c] = a;
    }
    __syncthreads();
    if (t < 32){
        float s=0.f,d=0.f;
        #pragma unroll
        for (int c=0;c<3;c++){ s += hh[t*3+c]*ldf(g2as,c); d += hh[t*3+c]*ldf(g2ad,c); }
        s2[t]=s; d2[t]=d;
    }
    __syncthreads();
    if (t < 32){
        float di = d2[t];
        float ev[32]; float m=-1e30f;
        for (int j=0;j<32;j++){
            float e = di + s2[j]; e = (e>0.f)?e:0.2f*e; ev[j]=e; m=fmaxf(m,e);
        }
        float ssum=0.f;
        for (int j=0;j<32;j++){ float p=expf(ev[j]-m); ev[j]=p; ssum+=p; }
        float inv = 1.f/ssum;
        for (int j=0;j<32;j++) att2[t*32+j] = ev[j]*inv;
    }
    __syncthreads();
    if (t < 96){
        int i = t/3, c = t - 3*(t/3);
        float a = 0.f;
        for (int j=0;j<32;j++) a += att2[i*32+j]*hh[j*3+c];
        a += ldf(g2b, c);
        float adj = tanhf(a)*0.1f;
        float cr = ic[i*3+c] + adj;
        cr -= floorf(cr);
        stf(out_recon, (size_t)b*2752 + i*86 + 83 + c, cr);
    }
}

__global__ __launch_bounds__(256) void k_gat(
    const int* flag, const void* emb,
    const void* g1w, const void* g1b, const void* g1as, const void* g1ad,
    const void* g2w, const void* g2b, const void* g2as, const void* g2ad,
    void* d_out)
{
    __shared__ __align__(16) char smem[63360];
    if (*flag) gat_impl<bf16>((const bf16*)emb,(const bf16*)g1w,(const bf16*)g1b,
        (const bf16*)g1as,(const bf16*)g1ad,(const bf16*)g2w,(const bf16*)g2b,
        (const bf16*)g2as,(const bf16*)g2ad, d_out, smem);
    else       gat_impl<float>((const float*)emb,(const float*)g1w,(const float*)g1b,
        (const float*)g1as,(const float*)g1ad,(const float*)g2w,(const float*)g2b,
        (const float*)g2as,(const float*)g2ad, d_out, smem);
}

extern "C" void kernel_launch(void* const* d_in, const int* in_sizes, int n_in,
                              void* d_out, int out_size, void* d_ws, size_t ws_size,
                              hipStream_t stream)
{
    (void)in_sizes; (void)n_in; (void)out_size;
    char* ws = (char*)d_ws;
    const bool big = (ws_size >= 83000000ull);

    if (big){
        // encoder-phase overlays (die after k_pool):
        bf16*  Abuf  = (bf16*)(ws);                    //  4,194,304  @ 0
        bf16*  h1    = (bf16*)(ws + 4194304);          // 33,554,432
        float* h2    = (float*)(ws + 37748736);        // 33,554,432 (ends 71,303,168)
        // conv/recon-phase:
        bf16*  Amat  = (bf16*)(ws);                    // 33,554,432
        bf16*  Wc2T  = (bf16*)(ws + 33554432);         // 33,554,432 (dead after gemm3)
        bf16*  BtW2  = (bf16*)(ws + 33554432);         // 46,137,344 (overlays Wc2T..Wc1T)
        bf16*  c1    = (bf16*)(ws + 67108864);         //  8,388,608
        bf16*  d0    = (bf16*)(ws + 75497472);         //  2,097,152
        bf16*  Wc1T  = (bf16*)(ws + 77594624);         //  2,097,152
        // persistent tail:
        bf16*  zc    = (bf16*)(ws + 79691776);         //    655,360
        bf16*  BtW1  = (bf16*)(ws + 80347136);         //    163,840
        float* biasf = (float*)(ws + 80510976);        //     13,504
        float* gbuf  = (float*)(ws + 80524480);        //  1,048,576
        float* zbuf  = (float*)(ws + 81573056);        //    524,288
        int*   flag  = (int*)  (ws + 82097344);        //         64
        bf16*  W1t   = (bf16*)(ws + 82097408);         //     16,384
        bf16*  W2t   = (bf16*)(ws + 82113792);         //     65,536
        float* ebias = (float*)(ws + 82179328);        //      1,536  (end 82,180,864)

        k_detect<<<1, 64, 0, stream>>>(d_in[5], flag);
        // ---- encoder phase (MFMA) ----
        k_prepEnc<<<64, 256, 0, stream>>>(flag, d_in[6], d_in[7], d_in[8], d_in[9], W1t, W2t, ebias);
        k_buildA<<<256, 256, 0, stream>>>(flag, (const int*)d_in[0], d_in[1], d_in[5], Abuf);
        k_gemm128<bf16,1> <<<dim3(512,2), 256, 0, stream>>>(Abuf, W1t, 32,  ebias,     0, h1, 256);
        k_gemm128<float,1><<<dim3(512,1), 256, 0, stream>>>(h1,   W2t, 256, ebias+256, 0, h2, 128);
        k_pool<<<2048, 128, 0, stream>>>(flag, h2, d_in[10], d_in[11], gbuf);
        // ---- latent ----
        k_latent<<<2048, 64, 0, stream>>>(flag, d_in[2], d_in[4], d_in[3],
            d_in[12], d_in[13], d_in[14], d_in[15],
            d_in[16], d_in[17], d_in[18], d_in[19],
            d_in[28], d_in[29], d_in[30], d_in[31],
            gbuf, zbuf, zc, d_out);
        // ---- conv-as-GEMM phase (overwrites encoder buffers) ----
        k_prep<<<64, 256, 0, stream>>>(flag, d_in[21], d_in[23], d_in[25], d_in[27], d_in[20], biasf, BtW1);
        k_expWc1<<<512, 256, 0, stream>>>(flag, d_in[22], Wc1T);
        k_expWc2<<<8192, 256, 0, stream>>>(flag, d_in[24], Wc2T);
        k_gemm128<bf16,0><<<dim3(16,4),  256, 0, stream>>>(zc, BtW1, 160,  biasf,     0, d0,   512);
        k_gemm128<bf16,1><<<dim3(16,16), 256, 0, stream>>>(d0, Wc1T, 512,  biasf+512, 6, c1,   2048);
        k_gemm128<bf16,1><<<dim3(16,64), 256, 0, stream>>>(c1, Wc2T, 2048, biasf+544, 9, Amat, 8192);
        // ---- recon GEMM ----
        k_transW<<<dim3(128,44), 256, 0, stream>>>(flag, d_in[26], BtW2);
        k_gemm_recon64<<<dim3(32,22), 256, 0, stream>>>(flag, Amat, BtW2, biasf, d_out);
        // ---- GAT ----
        k_gat<<<2048, 256, 0, stream>>>(flag, d_in[5],
            d_in[32], d_in[33], d_in[34], d_in[35],
            d_in[36], d_in[37], d_in[38], d_in[39], d_out);
    } else {
        bf16*  Amat = (bf16*)(ws);
        float* gbuf = (float*)(ws + 33554432);
        float* zbuf = (float*)(ws + 34603008);
        int*   flag = (int*)  (ws + 35127296);

        k_detect<<<1, 64, 0, stream>>>(d_in[5], flag);
        k_encoder<<<2048, 256, 0, stream>>>(flag, (const int*)d_in[0], d_in[1], d_in[5],
            d_in[6], d_in[7], d_in[8], d_in[9], d_in[10], d_in[11], gbuf);
        k_latent<<<2048, 64, 0, stream>>>(flag, d_in[2], d_in[4], d_in[3],
            d_in[12], d_in[13], d_in[14], d_in[15],
            d_in[16], d_in[17], d_in[18], d_in[19],
            d_in[28], d_in[29], d_in[30], d_in[31],
            gbuf, zbuf, (bf16*)nullptr, d_out);
        k_conv<<<2048, 256, 0, stream>>>(flag, zbuf, d_in[3],
            d_in[20], d_in[21], d_in[22], d_in[23], d_in[24], d_in[25], Amat);
        k_gemm<<<dim3(16,43), 256, 0, stream>>>(flag, Amat, d_in[26], d_in[27], d_out);
        k_gat<<<2048, 256, 0, stream>>>(flag, d_in[5],
            d_in[32], d_in[33], d_in[34], d_in[35],
            d_in[36], d_in[37], d_in[38], d_in[39], d_out);
    }
}

// Round 6
// 638.995 us; speedup vs baseline: 3.1441x; 1.1079x over previous
//
#include <hip/hip_runtime.h>
#include <hip/hip_bf16.h>

typedef __hip_bfloat16 bf16;
typedef __attribute__((ext_vector_type(8))) __bf16 bf16x8;
typedef __attribute__((ext_vector_type(4))) float f32x4;

__device__ __forceinline__ float b2f(bf16 v){ return __bfloat162float(v); }
__device__ __forceinline__ bf16  f2b(float v){ return __float2bfloat16(v); }

template<typename T> __device__ __forceinline__ float ldf(const T* p, size_t i);
template<> __device__ __forceinline__ float ldf<float>(const float* p, size_t i){ return p[i]; }
template<> __device__ __forceinline__ float ldf<bf16 >(const bf16*  p, size_t i){ return b2f(p[i]); }

template<typename T> __device__ __forceinline__ void stf(T* p, size_t i, float v);
template<> __device__ __forceinline__ void stf<float>(float* p, size_t i, float v){ p[i] = v; }
template<> __device__ __forceinline__ void stf<bf16 >(bf16*  p, size_t i, float v){ p[i] = f2b(v); }

#define NATM 32
#define RECON_OFF 262144
#define RL_OFF    5898240

__device__ __forceinline__ void glds16(const bf16* g, bf16* l){
    __builtin_amdgcn_global_load_lds(
        (const __attribute__((address_space(1))) unsigned int*)g,
        (__attribute__((address_space(3))) unsigned int*)l,
        16, 0, 0);
}

// ---------------- K0: dtype detect ----------------
__global__ __launch_bounds__(64) void k_detect(const void* emb, int* flag)
{
    __shared__ int cnt[64];
    const int t = threadIdx.x;
    const unsigned short* p = (const unsigned short*)emb;
    int c = 0;
    for (int i = t; i < 256; i += 64){
        int e = (p[i] >> 7) & 0xFF;
        c += (e >= 110 && e <= 132) ? 1 : 0;
    }
    cnt[t] = c;
    __syncthreads();
    if (t == 0){
        int s = 0;
        for (int i = 0; i < 64; i++) s += cnt[i];
        *flag = (s >= 200) ? 1 : 0;
    }
}

// ---------------- K-prepAll: enc weights + conv biases + BtW1 + Wc1T ----------------
template<typename T>
__device__ __forceinline__ void prepAll_impl(
    const T* w1, const T* b1, const T* w2, const T* b2,
    const T* db1, const T* c1b, const T* c2b, const T* db2, const T* dw1,
    const T* c1w,
    bf16* W1t, bf16* W2t, float* ebias, float* biasf, bf16* BtW1, bf16* Wc1T)
{
    const int gt = blockIdx.x*256 + threadIdx.x;
    const int gs = gridDim.x*256;
    for (int e = gt; e < 8192; e += gs){
        int n = e >> 5, k = e & 31;
        W1t[e] = (k < 19) ? f2b(ldf(w1, (size_t)k*256 + n)) : f2b(0.f);
    }
    for (int e = gt; e < 32768; e += gs){
        int n = e >> 8, k = e & 255;
        W2t[e] = f2b(ldf(w2, (size_t)k*128 + n));
    }
    for (int i = gt; i < 384; i += gs)
        ebias[i] = (i < 256) ? ldf(b1, i) : ldf(b2, i-256);
    for (int i = gt; i < 3376; i += gs){
        float v;
        if (i < 512)      v = ldf(db1, i);
        else if (i < 544) v = ldf(c1b, i-512);
        else if (i < 560) v = ldf(c2b, i-544);
        else              v = (i-560 < 2752) ? ldf(db2, i-560) : 0.f;
        biasf[i] = v;
    }
    for (int e = gt; e < 512*160; e += gs){
        int n = e/160, k = e - n*160;
        BtW1[e] = f2b((k < 147) ? ldf(dw1, (size_t)k*512 + n) : 0.f);
    }
    for (int g = gt; g < 2048*64; g += gs){
        const int n = g >> 6;
        const int k0 = (g & 63) << 3;
        const int o = n >> 6, spo = n & 63;
        const int zd = spo >> 4, zh = (spo >> 2) & 3, zw = spo & 3;
        bf16 v8[8];
        #pragma unroll
        for (int j = 0; j < 8; j++){
            int k = k0 + j;
            int i = k >> 3, sp = k & 7;
            int td = sp >> 2, th = (sp >> 1) & 1, tw = sp & 1;
            int kd = 2*td + 1 - zd, kh = 2*th + 1 - zh, kw = 2*tw + 1 - zw;
            float v = 0.f;
            if (kd >= 0 && kd < 3 && kh >= 0 && kh < 3 && kw >= 0 && kw < 3)
                v = ldf(c1w, (size_t)(o*64 + i)*27 + kd*9 + kh*3 + kw);
            v8[j] = f2b(v);
        }
        *(int4*)(&Wc1T[(size_t)n*512 + k0]) = *(int4*)v8;
    }
}

__global__ __launch_bounds__(256) void k_prepAll(
    const int* flag,
    const void* w1, const void* b1, const void* w2, const void* b2,
    const void* db1, const void* c1b, const void* c2b, const void* db2, const void* dw1,
    const void* c1w,
    bf16* W1t, bf16* W2t, float* ebias, float* biasf, bf16* BtW1, bf16* Wc1T)
{
    if (*flag) prepAll_impl<bf16>((const bf16*)w1,(const bf16*)b1,(const bf16*)w2,(const bf16*)b2,
        (const bf16*)db1,(const bf16*)c1b,(const bf16*)c2b,(const bf16*)db2,(const bf16*)dw1,
        (const bf16*)c1w, W1t, W2t, ebias, biasf, BtW1, Wc1T);
    else       prepAll_impl<float>((const float*)w1,(const float*)b1,(const float*)w2,(const float*)b2,
        (const float*)db1,(const float*)c1b,(const float*)c2b,(const float*)db2,(const float*)dw1,
        (const float*)c1w, W1t, W2t, ebias, biasf, BtW1, Wc1T);
}

// ---------------- K-buildA ----------------
template<typename T>
__device__ __forceinline__ void buildA_impl(
    const int* elements, const T* coords, const T* emb, bf16* Abuf)
{
    const int r = blockIdx.x*256 + threadIdx.x;
    const int el = elements[r];
    bf16 row[32];
    #pragma unroll
    for (int f=0; f<16; f++) row[f] = f2b(ldf(emb, (size_t)el*16 + f));
    #pragma unroll
    for (int c=0; c<3; c++) row[16+c] = f2b(ldf(coords, (size_t)r*3 + c));
    #pragma unroll
    for (int f=19; f<32; f++) row[f] = f2b(0.f);
    *(int4*)(&Abuf[(size_t)r*32])      = *(int4*)(&row[0]);
    *(int4*)(&Abuf[(size_t)r*32 + 8])  = *(int4*)(&row[8]);
    *(int4*)(&Abuf[(size_t)r*32 + 16]) = *(int4*)(&row[16]);
    *(int4*)(&Abuf[(size_t)r*32 + 24]) = *(int4*)(&row[24]);
}

__global__ __launch_bounds__(256) void k_buildA(
    const int* flag, const int* elements, const void* coords, const void* emb, bf16* Abuf)
{
    if (*flag) buildA_impl<bf16>(elements,(const bf16*)coords,(const bf16*)emb, Abuf);
    else       buildA_impl<float>(elements,(const float*)coords,(const float*)emb, Abuf);
}

// ---------------- K-pool ----------------
template<typename T>
__device__ __forceinline__ void pool_impl(
    const float* h2, const T* w3, const T* b3, float* gbuf)
{
    __shared__ float hsum[128];
    const int b = blockIdx.x, t = threadIdx.x;
    float s = 0.f;
    for (int n=0; n<32; n++) s += h2[(size_t)(b*32+n)*128 + t];
    hsum[t] = s;
    __syncthreads();
    float a = 0.f;
    for (int k=0; k<128; k++) a += hsum[k]*ldf(w3, (size_t)k*128 + t);
    gbuf[b*128+t] = a*(1.f/32.f) + ldf(b3, t);
}

__global__ __launch_bounds__(128) void k_pool(
    const int* flag, const float* h2, const void* w3, const void* b3, float* gbuf)
{
    if (*flag) pool_impl<bf16>(h2, (const bf16*)w3, (const bf16*)b3, gbuf);
    else       pool_impl<float>(h2, (const float*)w3, (const float*)b3, gbuf);
}

// ---------------- K1 (fallback): atom encoder ----------------
template<typename T>
__device__ __forceinline__ void enc_impl(
    const int* elements, const T* coords, const T* emb,
    const T* w1, const T* b1, const T* w2, const T* b2c,
    const T* w3, const T* b3, float* gbuf, char* smem)
{
    float (*af)[19]   = (float(*)[19])(smem);
    float (*h1)[256]  = (float(*)[256])(smem + 2432);
    float (*h2s)[128] = (float(*)[128])(smem + 35200);
    float* hsum       = (float*)(smem + 51584);
    const int b = blockIdx.x, t = threadIdx.x;

    for (int idx = t; idx < NATM*19; idx += 256){
        int n = idx/19, f = idx - n*19;
        af[n][f] = (f < 16) ? ldf(emb, (size_t)elements[b*NATM+n]*16 + f)
                            : ldf(coords, (size_t)(b*NATM+n)*3 + (f-16));
    }
    __syncthreads();
    {
        float wc[19];
        #pragma unroll
        for (int f=0; f<19; f++) wc[f] = ldf(w1, f*256 + t);
        float bb = ldf(b1, t);
        for (int n=0; n<NATM; n++){
            float a = bb;
            #pragma unroll
            for (int f=0; f<19; f++) a += af[n][f]*wc[f];
            h1[n][t] = fmaxf(a, 0.f);
        }
    }
    __syncthreads();
    {
        const int j = t & 127, half = t >> 7;
        float bb = ldf(b2c, j);
        float acc[16];
        #pragma unroll
        for (int n=0;n<16;n++) acc[n] = bb;
        for (int k=0;k<256;k+=4){
            float wa = ldf(w2, (k+0)*128+j);
            float wb = ldf(w2, (k+1)*128+j);
            float wcv= ldf(w2, (k+2)*128+j);
            float wd = ldf(w2, (k+3)*128+j);
            #pragma unroll
            for (int n=0;n<16;n++){
                float4 hv = *(const float4*)(&h1[half*16+n][k]);
                acc[n] += hv.x*wa + hv.y*wb + hv.z*wcv + hv.w*wd;
            }
        }
        #pragma unroll
        for (int n=0;n<16;n++) h2s[half*16+n][j] = fmaxf(acc[n], 0.f);
    }
    __syncthreads();
    if (t < 128){
        float s = 0.f;
        for (int n=0;n<NATM;n++) s += h2s[n][t];
        hsum[t] = s;
    }
    __syncthreads();
    if (t < 128){
        float a = 0.f;
        for (int k=0;k<128;k++) a += hsum[k]*ldf(w3, k*128+t);
        gbuf[b*128+t] = a*(1.f/32.f) + ldf(b3, t);
    }
}

__global__ __launch_bounds__(256) void k_encoder(
    const int* flag, const int* elements, const void* coords, const void* emb,
    const void* w1, const void* b1, const void* w2, const void* b2,
    const void* w3, const void* b3, float* gbuf)
{
    __shared__ __align__(16) char smem[52096];
    if (*flag) enc_impl<bf16>(elements,(const bf16*)coords,(const bf16*)emb,
        (const bf16*)w1,(const bf16*)b1,(const bf16*)w2,(const bf16*)b2,
        (const bf16*)w3,(const bf16*)b3, gbuf, smem);
    else       enc_impl<float>(elements,(const float*)coords,(const float*)emb,
        (const float*)w1,(const float*)b1,(const float*)w2,(const float*)b2,
        (const float*)w3,(const float*)b3, gbuf, smem);
}

// ---------------- K2: latent ----------------
template<typename T>
__device__ __forceinline__ void lat_impl(
    const T* lattice, const T* eps, const T* comp,
    const T* lw1, const T* lb1, const T* lw2, const T* lb2,
    const T* muw, const T* mub, const T* lvw, const T* lvb,
    const T* dw1, const T* db1, const T* dw2, const T* db2,
    const float* gbuf, float* zbuf, bf16* zc, void* d_out, char* smem)
{
    float* comb = (float*)(smem);
    float* lat  = (float*)(smem + 768);
    float* l1   = (float*)(smem + 832);
    float* zz   = (float*)(smem + 1088);
    float* r1   = (float*)(smem + 1344);
    T* out_mu = (T*)d_out;
    T* out_lv = out_mu + 131072;
    T* out_rl = out_mu + RL_OFF;
    const int b = blockIdx.x, t = threadIdx.x;
    comb[t]    = gbuf[b*128 + t];
    comb[64+t] = gbuf[b*128 + 64 + t];
    if (t < 9) lat[t] = ldf(lattice, b*9 + t);
    __syncthreads();
    {
        float a = ldf(lb1, t);
        #pragma unroll
        for (int f=0; f<9; f++) a += lat[f]*ldf(lw1, f*64+t);
        l1[t] = fmaxf(a, 0.f);
    }
    __syncthreads();
    {
        float a = ldf(lb2, t);
        for (int k=0;k<64;k++) a += l1[k]*ldf(lw2, k*64+t);
        comb[128+t] = a;
    }
    __syncthreads();
    float mu = ldf(mub, t), lv = ldf(lvb, t);
    for (int k=0;k<192;k++){
        float c = comb[k];
        mu += c*ldf(muw, k*64+t);
        lv += c*ldf(lvw, k*64+t);
    }
    float z = mu + ldf(eps, b*64+t)*expf(0.5f*lv);
    stf(out_mu, (size_t)b*64+t, mu);
    stf(out_lv, (size_t)b*64+t, lv);
    zbuf[b*64+t] = z;
    zz[t] = z;
    __syncthreads();
    if (zc){
        for (int i=t; i<160; i+=64){
            float v = (i<64) ? zz[i] : ((i<147) ? ldf(comp, b*83 + (i-64)) : 0.f);
            zc[(size_t)b*160 + i] = f2b(v);
        }
    }
    {
        float a = ldf(db1, t);
        for (int k=0;k<64;k++) a += zz[k]*ldf(dw1, k*64+t);
        r1[t] = fmaxf(a, 0.f);
    }
    __syncthreads();
    if (t < 9){
        float a = ldf(db2, t);
        for (int k=0;k<64;k++) a += r1[k]*ldf(dw2, k*9+t);
        stf(out_rl, (size_t)b*9+t, a);
    }
}

__global__ __launch_bounds__(64) void k_latent(
    const int* flag, const void* lattice, const void* eps, const void* comp,
    const void* lw1, const void* lb1, const void* lw2, const void* lb2,
    const void* muw, const void* mub, const void* lvw, const void* lvb,
    const void* dw1, const void* db1, const void* dw2, const void* db2,
    const float* gbuf, float* zbuf, bf16* zc, void* d_out)
{
    __shared__ __align__(16) char smem[1600];
    if (*flag) lat_impl<bf16>((const bf16*)lattice,(const bf16*)eps,(const bf16*)comp,
        (const bf16*)lw1,(const bf16*)lb1,(const bf16*)lw2,(const bf16*)lb2,
        (const bf16*)muw,(const bf16*)mub,(const bf16*)lvw,(const bf16*)lvb,
        (const bf16*)dw1,(const bf16*)db1,(const bf16*)dw2,(const bf16*)db2,
        gbuf, zbuf, zc, d_out, smem);
    else       lat_impl<float>((const float*)lattice,(const float*)eps,(const float*)comp,
        (const float*)lw1,(const float*)lb1,(const float*)lw2,(const float*)lb2,
        (const float*)muw,(const float*)mub,(const float*)lvw,(const float*)lvb,
        (const float*)dw1,(const float*)db1,(const float*)dw2,(const float*)db2,
        gbuf, zbuf, zc, d_out, smem);
}

// ---------------- K-exp2: Wc2T from ct2_w ----------------
template<typename T>
__device__ __forceinline__ void expWc2_impl(const T* w, bf16* Wc2T)
{
    const int n = blockIdx.x;
    const int k0 = threadIdx.x << 3;
    const int o = n >> 9, spo = n & 511;
    const int zd = spo >> 6, zh = (spo >> 3) & 7, zw = spo & 7;
    bf16 v8[8];
    #pragma unroll
    for (int j = 0; j < 8; j++){
        int k = k0 + j;
        int i = k >> 6, sp = k & 63;
        int td = sp >> 4, th = (sp >> 2) & 3, tw = sp & 3;
        int kd = 2*td + 1 - zd, kh = 2*th + 1 - zh, kw = 2*tw + 1 - zw;
        float v = 0.f;
        if (kd >= 0 && kd < 3 && kh >= 0 && kh < 3 && kw >= 0 && kw < 3)
            v = ldf(w, (size_t)(o*32 + i)*27 + kd*9 + kh*3 + kw);
        v8[j] = f2b(v);
    }
    *(int4*)(&Wc2T[(size_t)n*2048 + k0]) = *(int4*)v8;
}

__global__ __launch_bounds__(256) void k_expWc2(const int* flag, const void* w, bf16* Wc2T)
{
    if (*flag) expWc2_impl<bf16>((const bf16*)w, Wc2T);
    else       expWc2_impl<float>((const float*)w, Wc2T);
}

// ---------------- K-transW ----------------
template<typename T>
__device__ __forceinline__ void transW_impl(const T* B, bf16* Bt)
{
    __shared__ bf16 tile[64][65];
    const int kb = blockIdx.x << 6;
    const int nb = blockIdx.y << 6;
    const int t = threadIdx.x;
    for (int idx=t; idx<4096; idx+=256){
        int k = idx>>6, n = idx&63;
        int col = nb + n;
        tile[k][n] = (col < 2752) ? f2b(ldf(B, (size_t)(kb+k)*2752 + col)) : f2b(0.f);
    }
    __syncthreads();
    for (int idx=t; idx<4096; idx+=256){
        int n = idx>>6, k = idx&63;
        Bt[(size_t)(nb+n)*8192 + kb + k] = tile[k][n];
    }
}

__global__ __launch_bounds__(256) void k_transW(const int* flag, const void* B, bf16* Bt)
{
    if (*flag) transW_impl<bf16>((const bf16*)B, Bt);
    else       transW_impl<float>((const float*)B, Bt);
}

// ---------------- BK=32 gemm (for K not divisible by 64: K=32, K=160) ----------------
struct GemmAcc { f32x4 a[4][4]; };

__device__ __forceinline__ void gemm128_core(
    const bf16* __restrict__ A, const bf16* __restrict__ Bt, int K,
    int bm, int bn, bf16* As, bf16* Bs, GemmAcc& G)
{
    const int t = threadIdx.x;
    const int w = t >> 6, lane = t & 63;
    const int wm = w >> 1, wn = w & 1;
    const int ml = lane & 15, mq = lane >> 4;
    const int lrow = lane >> 2;
    const int gchunk = (lane & 3) ^ ((lane >> 3) & 3);
    const int rchunk = (mq ^ ((ml >> 1) & 3)) << 3;

    const size_t arow = (size_t)(bm + w*32 + lrow);
    const size_t brow = (size_t)(bn + w*32 + lrow);

    for (int kt = 0; kt < K; kt += 32){
        __syncthreads();
        #pragma unroll
        for (int c = 0; c < 2; c++){
            glds16(A  + (arow + c*16)*K + kt + gchunk*8, &As[(w*32 + c*16)*32]);
            glds16(Bt + (brow + c*16)*K + kt + gchunk*8, &Bs[(w*32 + c*16)*32]);
        }
        __syncthreads();
        bf16x8 af[4], bfr[4];
        #pragma unroll
        for (int i=0;i<4;i++) af[i]  = *(const bf16x8*)(&As[(wm*64 + i*16 + ml)*32 + rchunk]);
        #pragma unroll
        for (int j=0;j<4;j++) bfr[j] = *(const bf16x8*)(&Bs[(wn*64 + j*16 + ml)*32 + rchunk]);
        #pragma unroll
        for (int i=0;i<4;i++)
            #pragma unroll
            for (int j=0;j<4;j++)
                G.a[i][j] = __builtin_amdgcn_mfma_f32_16x16x32_bf16(af[i], bfr[j], G.a[i][j], 0,0,0);
    }
}

template<typename OutT, int ACT>
__global__ __launch_bounds__(256) void k_gemm128(
    const bf16* __restrict__ A, const bf16* __restrict__ Bt, int K,
    const float* __restrict__ biasf, int bshift,
    OutT* __restrict__ C, int ldc)
{
    __shared__ __align__(16) bf16 As[128*32];
    __shared__ __align__(16) bf16 Bs[128*32];
    const int t = threadIdx.x;
    const int bm = blockIdx.x << 7, bn = blockIdx.y << 7;
    const int w = t >> 6, lane = t & 63;
    const int wm = w >> 1, wn = w & 1;
    const int ml = lane & 15, mq = lane >> 4;
    GemmAcc G;
    #pragma unroll
    for (int i=0;i<4;i++)
        #pragma unroll
        for (int j=0;j<4;j++) G.a[i][j] = (f32x4){0.f,0.f,0.f,0.f};
    gemm128_core(A, Bt, K, bm, bn, As, Bs, G);
    #pragma unroll
    for (int j=0;j<4;j++){
        const int col = bn + wn*64 + (j<<4) + ml;
        const float bv = biasf[col >> bshift];
        #pragma unroll
        for (int i=0;i<4;i++){
            #pragma unroll
            for (int r=0;r<4;r++){
                const int row = bm + wm*64 + (i<<4) + (mq<<2) + r;
                float v = G.a[i][j][r] + bv;
                if (ACT == 1) v = fmaxf(v, 0.f);
                stf(C, (size_t)row*ldc + col, v);
            }
        }
    }
}

// ---------------- BK=64 gemm core: BM x 128 tile, 64-wide K-steps ----------------
// LDS layout: row-major [rows][64], logical chunk q (8 elems) of row r stored at
// physical chunk q ^ (r&7). glds dest = base + lane*16 covers [8 rows][8 chunks];
// source address carries the swizzle: gch = (lane&7) ^ (lane>>3).
template<int BM>
__device__ __forceinline__ void gemm64_core(
    const bf16* __restrict__ A, const bf16* __restrict__ Bt, int K,
    int bm, int bn, bf16* As, bf16* Bs, f32x4 acc[][4])
{
    const int t = threadIdx.x;
    const int w = t >> 6, lane = t & 63;
    const int wm = w >> 1, wn = w & 1;
    const int ml = lane & 15, mq = lane >> 4;
    const int lrow = lane >> 3;              // 0..7
    const int gch  = (lane & 7) ^ lrow;      // swizzled source chunk
    const int mswz = ml & 7;

    const size_t abase = (size_t)(bm + w*(BM/4) + lrow);
    const size_t bbase = (size_t)(bn + w*32 + lrow);

    for (int kt = 0; kt < K; kt += 64){
        __syncthreads();
        #pragma unroll
        for (int c = 0; c < BM/32; c++)
            glds16(A + (abase + c*8)*K + kt + gch*8, &As[(w*(BM/4) + c*8)*64]);
        #pragma unroll
        for (int c = 0; c < 4; c++)
            glds16(Bt + (bbase + c*8)*K + kt + gch*8, &Bs[(w*32 + c*8)*64]);
        __syncthreads();
        bf16x8 af[2][BM/32], bfr[2][4];
        #pragma unroll
        for (int ks=0; ks<2; ks++){
            #pragma unroll
            for (int i=0;i<BM/32;i++){
                const int r = wm*(BM/2) + i*16 + ml;
                af[ks][i] = *(const bf16x8*)(&As[r*64 + (((ks<<2)+mq) ^ mswz)*8]);
            }
            #pragma unroll
            for (int j=0;j<4;j++){
                const int r = wn*64 + j*16 + ml;
                bfr[ks][j] = *(const bf16x8*)(&Bs[r*64 + (((ks<<2)+mq) ^ mswz)*8]);
            }
        }
        #pragma unroll
        for (int ks=0; ks<2; ks++)
            #pragma unroll
            for (int i=0;i<BM/32;i++)
                #pragma unroll
                for (int j=0;j<4;j++)
                    acc[i][j] = __builtin_amdgcn_mfma_f32_16x16x32_bf16(af[ks][i], bfr[ks][j], acc[i][j], 0,0,0);
    }
}

template<typename OutT, int ACT>   // 128 x 128 tile, BK=64
__global__ __launch_bounds__(256) void k_gemm64(
    const bf16* __restrict__ A, const bf16* __restrict__ Bt, int K,
    const float* __restrict__ biasf, int bshift,
    OutT* __restrict__ C, int ldc)
{
    __shared__ __align__(16) bf16 As[128*64];
    __shared__ __align__(16) bf16 Bs[128*64];
    const int t = threadIdx.x;
    const int bm = blockIdx.x << 7, bn = blockIdx.y << 7;
    const int w = t >> 6, lane = t & 63;
    const int wm = w >> 1, wn = w & 1;
    const int ml = lane & 15, mq = lane >> 4;
    f32x4 acc[4][4];
    #pragma unroll
    for (int i=0;i<4;i++)
        #pragma unroll
        for (int j=0;j<4;j++) acc[i][j] = (f32x4){0.f,0.f,0.f,0.f};
    gemm64_core<128>(A, Bt, K, bm, bn, As, Bs, acc);
    #pragma unroll
    for (int j=0;j<4;j++){
        const int col = bn + wn*64 + (j<<4) + ml;
        const float bv = biasf[col >> bshift];
        #pragma unroll
        for (int i=0;i<4;i++){
            #pragma unroll
            for (int r=0;r<4;r++){
                const int row = bm + wm*64 + (i<<4) + (mq<<2) + r;
                float v = acc[i][j][r] + bv;
                if (ACT == 1) v = fmaxf(v, 0.f);
                stf(C, (size_t)row*ldc + col, v);
            }
        }
    }
}

// 64 x 128 recon variant, BK=64, sigmoid epilogue
__global__ __launch_bounds__(256) void k_gemm64_recon(
    const int* __restrict__ flag,
    const bf16* __restrict__ A, const bf16* __restrict__ Bt,
    const float* __restrict__ biasf, void* __restrict__ d_out)
{
    __shared__ __align__(16) bf16 As[64*64];
    __shared__ __align__(16) bf16 Bs[128*64];
    const int K = 8192;
    const int t = threadIdx.x;
    const int bm = blockIdx.x << 6, bn = blockIdx.y << 7;
    const int w = t >> 6, lane = t & 63;
    const int wm = w >> 1, wn = w & 1;
    const int ml = lane & 15, mq = lane >> 4;
    f32x4 acc[2][4];
    #pragma unroll
    for (int i=0;i<2;i++)
        #pragma unroll
        for (int j=0;j<4;j++) acc[i][j] = (f32x4){0.f,0.f,0.f,0.f};
    gemm64_core<64>(A, Bt, K, bm, bn, As, Bs, acc);
    const int fl = *flag;
    #pragma unroll
    for (int j=0;j<4;j++){
        const int col = bn + wn*64 + (j<<4) + ml;
        if (col >= 2752) continue;
        const int f = col % 86;
        const float bv = biasf[560 + col];
        #pragma unroll
        for (int i=0;i<2;i++){
            #pragma unroll
            for (int r=0;r<4;r++){
                const int row = bm + wm*32 + (i<<4) + (mq<<2) + r;
                float v = acc[i][j][r] + bv;
                if (f >= 83) v = 1.f/(1.f + expf(-v));
                if (fl) stf((bf16*)d_out + RECON_OFF, (size_t)row*2752 + col, v);
                else    stf((float*)d_out + RECON_OFF, (size_t)row*2752 + col, v);
            }
        }
    }
}

// ---------------- K3 (fallback): conv chain ----------------
template<typename T>
__device__ __forceinline__ void conv_impl(
    const float* zbuf, const T* comp,
    const T* dw1, const T* db1, const T* c1w, const T* c1b,
    const T* c2w, const T* c2b, bf16* Amat, char* smem)
{
    float* zc        = (float*)(smem);
    float (*d0s)[8]  = (float(*)[8])(smem + 640);
    float (*c1s)[64] = (float(*)[64])(smem + 2688);
    bf16* w2s        = (bf16*)(smem + 10880);
    const int b = blockIdx.x, t = threadIdx.x;
    for (int i=t; i<16*32*27; i+=256) w2s[i] = f2b(ldf(c2w, i));
    if (t < 147) zc[t] = (t < 64) ? zbuf[b*64+t] : ldf(comp, b*83 + (t-64));
    __syncthreads();
    #pragma unroll
    for (int jj=0; jj<2; jj++){
        int j = t + (jj<<8);
        float a = ldf(db1, j);
        for (int k=0;k<147;k++) a += zc[k]*ldf(dw1, k*512+j);
        d0s[j>>3][j&7] = a;
    }
    __syncthreads();
    {
        const int o = t>>3;
        const float bias = ldf(c1b, o);
        const T* wb = c1w + o*64*27;
        for (int u=0; u<8; u++){
            int sp = (t&7) + (u<<3);
            int zd = sp>>4, zh = (sp>>2)&3, zw = sp&3;
            float acc = bias;
            for (int kd=0;kd<3;kd++){
                int qd = zd+kd-1; if (qd<0 || (qd&1) || qd>=4) continue; int td=qd>>1;
                for (int kh=0;kh<3;kh++){
                    int qh = zh+kh-1; if (qh<0 || (qh&1) || qh>=4) continue; int th=qh>>1;
                    for (int kw=0;kw<3;kw++){
                        int qw = zw+kw-1; if (qw<0 || (qw&1) || qw>=4) continue; int tw=qw>>1;
                        const int koff = kd*9+kh*3+kw;
                        const int spi = td*4+th*2+tw;
                        float s = 0.f;
                        #pragma unroll 8
                        for (int i=0;i<64;i++) s += ldf(wb, i*27+koff)*d0s[i][spi];
                        acc += s;
                    }
                }
            }
            c1s[o][sp] = fmaxf(acc, 0.f);
        }
    }
    __syncthreads();
    {
        const int o = t>>4;
        const float bias = ldf(c2b, o);
        for (int u=0; u<32; u++){
            int sp = (t&15) + (u<<4);
            int zd = sp>>6, zh=(sp>>3)&7, zw=sp&7;
            float acc = bias;
            for (int kd=0;kd<3;kd++){
                int qd = zd+kd-1; if (qd<0 || (qd&1) || qd>=8) continue; int td=qd>>1;
                for (int kh=0;kh<3;kh++){
                    int qh = zh+kh-1; if (qh<0 || (qh&1) || qh>=8) continue; int th=qh>>1;
                    for (int kw=0;kw<3;kw++){
                        int qw = zw+kw-1; if (qw<0 || (qw&1) || qw>=8) continue; int tw=qw>>1;
                        const int koff = kd*9+kh*3+kw;
                        const int spi = td*16+th*4+tw;
                        const int wbase = (o*32)*27 + koff;
                        float s = 0.f;
                        #pragma unroll 8
                        for (int i=0;i<32;i++) s += b2f(w2s[wbase + i*27])*c1s[i][spi];
                        acc += s;
                    }
                }
            }
            Amat[(size_t)b*8192 + o*512 + sp] = f2b(fmaxf(acc, 0.f));
        }
    }
}

__global__ __launch_bounds__(256) void k_conv(
    const int* flag, const float* zbuf, const void* comp,
    const void* dw1, const void* db1, const void* c1w, const void* c1b,
    const void* c2w, const void* c2b, bf16* Amat)
{
    __shared__ __align__(16) char smem[38528];
    if (*flag) conv_impl<bf16>(zbuf,(const bf16*)comp,(const bf16*)dw1,(const bf16*)db1,
        (const bf16*)c1w,(const bf16*)c1b,(const bf16*)c2w,(const bf16*)c2b, Amat, smem);
    else       conv_impl<float>(zbuf,(const float*)comp,(const float*)dw1,(const float*)db1,
        (const float*)c1w,(const float*)c1b,(const float*)c2w,(const float*)c2b, Amat, smem);
}

// ---------------- K4 (fallback): dec_w2 gemm with in-kernel transpose ----------------
template<typename T> struct BStage;
template<> struct BStage<bf16>{
    static __device__ __forceinline__ void go(const bf16* p, bf16* v8){
        union{ int4 q; bf16 e[8]; } u; u.q = *(const int4*)p;
        #pragma unroll
        for (int j=0;j<8;j++) v8[j] = u.e[j];
    }
};
template<> struct BStage<float>{
    static __device__ __forceinline__ void go(const float* p, bf16* v8){
        float4 a = *(const float4*)p, b = *(const float4*)(p+4);
        v8[0]=f2b(a.x); v8[1]=f2b(a.y); v8[2]=f2b(a.z); v8[3]=f2b(a.w);
        v8[4]=f2b(b.x); v8[5]=f2b(b.y); v8[6]=f2b(b.z); v8[7]=f2b(b.w);
    }
};

__device__ __forceinline__ bf16x8 readBfrag(const bf16 (*Bs)[42], int n, int k0){
    union { bf16x8 v; unsigned int u[4]; } r;
    const unsigned int* p = (const unsigned int*)(&Bs[n][k0]);
    r.u[0]=p[0]; r.u[1]=p[1]; r.u[2]=p[2]; r.u[3]=p[3];
    return r.v;
}

template<typename T>
__device__ __forceinline__ void gemm_impl(
    const bf16* A, const T* B, const T* bias, void* d_out, char* smem)
{
    bf16 (*As)[40] = (bf16(*)[40])(smem);
    bf16 (*Bs)[42] = (bf16(*)[42])(smem + 10240);
    T* out_recon = (T*)d_out + RECON_OFF;
    const int t = threadIdx.x;
    const int bm = blockIdx.x << 7;
    const int bn = blockIdx.y << 6;
    const int w = t >> 6, lane = t & 63;
    const int ml = lane & 15, mq = lane >> 4;
    f32x4 acc[2][4];
    #pragma unroll
    for (int i=0;i<2;i++)
        #pragma unroll
        for (int j=0;j<4;j++) acc[i][j] = (f32x4){0.f,0.f,0.f,0.f};

    const int sm = t >> 2;
    const int sk = (t & 3) << 3;
    const int kk = t >> 3;
    const int nn = (t & 7) << 3;

    for (int kt = 0; kt < 8192; kt += 32){
        __syncthreads();
        {
            int4 v0 = *(const int4*)(A + (size_t)(bm + sm     )*8192 + kt + sk);
            int4 v1 = *(const int4*)(A + (size_t)(bm + sm + 64)*8192 + kt + sk);
            *(int4*)(&As[sm][sk])    = v0;
            *(int4*)(&As[sm+64][sk]) = v1;
            bf16 bv[8];
            BStage<T>::go(B + (size_t)(kt + kk)*2752 + bn + nn, bv);
            #pragma unroll
            for (int j=0;j<8;j++) Bs[nn+j][kk] = bv[j];
        }
        __syncthreads();
        bf16x8 a0 = *(const bf16x8*)(&As[(w<<5) + ml     ][mq<<3]);
        bf16x8 a1 = *(const bf16x8*)(&As[(w<<5) + 16 + ml][mq<<3]);
        bf16x8 b0 = readBfrag(Bs, ml,      mq<<3);
        bf16x8 b1 = readBfrag(Bs, 16 + ml, mq<<3);
        bf16x8 b2 = readBfrag(Bs, 32 + ml, mq<<3);
        bf16x8 b3 = readBfrag(Bs, 48 + ml, mq<<3);
        acc[0][0] = __builtin_amdgcn_mfma_f32_16x16x32_bf16(a0,b0,acc[0][0],0,0,0);
        acc[0][1] = __builtin_amdgcn_mfma_f32_16x16x32_bf16(a0,b1,acc[0][1],0,0,0);
        acc[0][2] = __builtin_amdgcn_mfma_f32_16x16x32_bf16(a0,b2,acc[0][2],0,0,0);
        acc[0][3] = __builtin_amdgcn_mfma_f32_16x16x32_bf16(a0,b3,acc[0][3],0,0,0);
        acc[1][0] = __builtin_amdgcn_mfma_f32_16x16x32_bf16(a1,b0,acc[1][0],0,0,0);
        acc[1][1] = __builtin_amdgcn_mfma_f32_16x16x32_bf16(a1,b1,acc[1][1],0,0,0);
        acc[1][2] = __builtin_amdgcn_mfma_f32_16x16x32_bf16(a1,b2,acc[1][2],0,0,0);
        acc[1][3] = __builtin_amdgcn_mfma_f32_16x16x32_bf16(a1,b3,acc[1][3],0,0,0);
    }
    #pragma unroll
    for (int nt=0; nt<4; nt++){
        const int col = bn + (nt<<4) + ml;
        const int atom = col / 86;
        const int f = col - atom*86;
        const float bv = ldf(bias, col);
        #pragma unroll
        for (int mt=0; mt<2; mt++){
            #pragma unroll
            for (int r=0; r<4; r++){
                const int row = bm + (w<<5) + (mt<<4) + (mq<<2) + r;
                float v = acc[mt][nt][r] + bv;
                if (f >= 83) v = 1.f/(1.f + expf(-v));
                stf(out_recon, (size_t)row*2752 + col, v);
            }
        }
    }
}

__global__ __launch_bounds__(256) void k_gemm(
    const int* flag, const bf16* A, const void* B, const void* bias, void* d_out)
{
    __shared__ __align__(16) char smem[15616];
    if (*flag) gemm_impl<bf16>(A, (const bf16*)B, (const bf16*)bias, d_out, smem);
    else       gemm_impl<float>(A, (const float*)B, (const float*)bias, d_out, smem);
}

// ---------------- K5: argmax, GAT1, GAT2, coords out ----------------
template<typename T>
__device__ __forceinline__ void gat_impl(
    const T* emb, const T* g1w, const T* g1b, const T* g1as, const T* g1ad,
    const T* g2w, const T* g2b, const T* g2as, const T* g2ad,
    void* d_out, char* smem)
{
    float* ic    = (float*)(smem);
    int*   amaxs = (int*)  (smem + 384);
    float* hs    = (float*)(smem + 512);
    float* xs    = (float*)(smem + 25088);
    float* U     = (float*)(smem + 49664);
    float* sa    = (float*)(smem + 61952);
    float* da    = (float*)(smem + 62336);
    float* hh    = (float*)(smem + 62720);
    float* s2    = (float*)(smem + 63104);
    float* d2    = (float*)(smem + 63232);
    float* lg    = xs;
    float* node  = U;
    float* att   = U;
    float* att2  = U;

    T* out_recon = (T*)d_out + RECON_OFF;
    const int b = blockIdx.x, t = threadIdx.x;

    for (int i=t; i<2656; i+=256){
        int n = i/83, f = i - n*83;
        lg[i] = ldf(out_recon, (size_t)b*2752 + n*86 + f);
    }
    if (t < 96){
        int n = t/3, c = t - 3*(t/3);
        ic[t] = ldf(out_recon, (size_t)b*2752 + n*86 + 83 + c);
    }
    __syncthreads();
    if (t < 32){
        const float* lp = lg + t*83;
        float best = lp[0]; int bi = 0;
        for (int f=1; f<83; f++){ float v = lp[f]; if (v > best){ best=v; bi=f; } }
        amaxs[t] = bi;
    }
    __syncthreads();
    for (int i=t; i<608; i+=256){
        int n = i/19, f = i - n*19;
        node[n*19+f] = (f<16) ? ldf(emb, amaxs[n]*16+f) : ic[n*3 + (f-16)];
    }
    __syncthreads();
    if (t < 192){
        float wc[19];
        #pragma unroll
        for (int f=0;f<19;f++) wc[f] = ldf(g1w, f*192+t);
        for (int n=0;n<32;n++){
            float a = 0.f;
            #pragma unroll
            for (int f=0;f<19;f++) a += node[n*19+f]*wc[f];
            hs[n*192+t] = a;
        }
    }
    __syncthreads();
    if (t < 96){
        int n = t/3, hd = t - 3*(t/3);
        float s=0.f, d=0.f;
        for (int c=0;c<64;c++){
            float hv = hs[n*192 + hd*64 + c];
            s += hv*ldf(g1as, hd*64+c);
            d += hv*ldf(g1ad, hd*64+c);
        }
        sa[n*3+hd] = s; da[n*3+hd] = d;
    }
    __syncthreads();
    if (t < 96){
        int i = t/3, hd = t - 3*(t/3);
        float di = da[i*3+hd];
        float ev[32]; float m = -1e30f;
        for (int j=0;j<32;j++){
            float e = di + sa[j*3+hd];
            e = (e > 0.f) ? e : 0.2f*e;
            ev[j] = e; m = fmaxf(m, e);
        }
        float ssum = 0.f;
        for (int j=0;j<32;j++){ float p = expf(ev[j]-m); ev[j]=p; ssum += p; }
        float inv = 1.f/ssum;
        for (int j=0;j<32;j++) att[(i*3+hd)*32 + j] = ev[j]*inv;
    }
    __syncthreads();
    if (t < 192){
        const int hd = t >> 6;
        float bb = ldf(g1b, t);
        float a[32];
        #pragma unroll
        for (int i=0;i<32;i++) a[i] = 0.f;
        for (int j=0;j<32;j++){
            float hv = hs[j*192+t];
            #pragma unroll
            for (int i=0;i<32;i++) a[i] += att[(i*3+hd)*32 + j]*hv;
        }
        for (int i=0;i<32;i++){
            float v = a[i] + bb;
            xs[i*192+t] = (v > 0.f) ? v : (expf(v) - 1.f);
        }
    }
    __syncthreads();
    if (t < 96){
        int n = t/3, c = t - 3*(t/3);
        float a = 0.f;
        for (int f=0;f<192;f++) a += xs[n*192+f]*ldf(g2w, f*3+c);
        hh[n*3+c] = a;
    }
    __syncthreads();
    if (t < 32){
        float s=0.f,d=0.f;
        #pragma unroll
        for (int c=0;c<3;c++){ s += hh[t*3+c]*ldf(g2as,c); d += hh[t*3+c]*ldf(g2ad,c); }
        s2[t]=s; d2[t]=d;
    }
    __syncthreads();
    if (t < 32){
        float di = d2[t];
        float ev[32]; float m=-1e30f;
        for (int j=0;j<32;j++){
            float e = di + s2[j]; e = (e>0.f)?e:0.2f*e; ev[j]=e; m=fmaxf(m,e);
        }
        float ssum=0.f;
        for (int j=0;j<32;j++){ float p=expf(ev[j]-m); ev[j]=p; ssum+=p; }
        float inv = 1.f/ssum;
        for (int j=0;j<32;j++) att2[t*32+j] = ev[j]*inv;
    }
    __syncthreads();
    if (t < 96){
        int i = t/3, c = t - 3*(t/3);
        float a = 0.f;
        for (int j=0;j<32;j++) a += att2[i*32+j]*hh[j*3+c];
        a += ldf(g2b, c);
        float adj = tanhf(a)*0.1f;
        float cr = ic[i*3+c] + adj;
        cr -= floorf(cr);
        stf(out_recon, (size_t)b*2752 + i*86 + 83 + c, cr);
    }
}

__global__ __launch_bounds__(256) void k_gat(
    const int* flag, const void* emb,
    const void* g1w, const void* g1b, const void* g1as, const void* g1ad,
    const void* g2w, const void* g2b, const void* g2as, const void* g2ad,
    void* d_out)
{
    __shared__ __align__(16) char smem[63360];
    if (*flag) gat_impl<bf16>((const bf16*)emb,(const bf16*)g1w,(const bf16*)g1b,
        (const bf16*)g1as,(const bf16*)g1ad,(const bf16*)g2w,(const bf16*)g2b,
        (const bf16*)g2as,(const bf16*)g2ad, d_out, smem);
    else       gat_impl<float>((const float*)emb,(const float*)g1w,(const float*)g1b,
        (const float*)g1as,(const float*)g1ad,(const float*)g2w,(const float*)g2b,
        (const float*)g2as,(const float*)g2ad, d_out, smem);
}

extern "C" void kernel_launch(void* const* d_in, const int* in_sizes, int n_in,
                              void* d_out, int out_size, void* d_ws, size_t ws_size,
                              hipStream_t stream)
{
    (void)in_sizes; (void)n_in; (void)out_size;
    char* ws = (char*)d_ws;
    const bool big = (ws_size >= 83000000ull);

    if (big){
        // encoder-phase overlays (die after k_pool):
        bf16*  Abuf  = (bf16*)(ws);                    //  4,194,304
        bf16*  h1    = (bf16*)(ws + 4194304);          // 33,554,432
        float* h2    = (float*)(ws + 37748736);        // 33,554,432 (ends 71,303,168)
        // conv/recon-phase:
        bf16*  Amat  = (bf16*)(ws);                    // 33,554,432
        bf16*  Wc2T  = (bf16*)(ws + 33554432);         // 33,554,432 (dead after gemm3)
        bf16*  BtW2  = (bf16*)(ws + 33554432);         // 46,137,344 (overlays Wc2T..Wc1T)
        bf16*  c1    = (bf16*)(ws + 67108864);         //  8,388,608
        bf16*  d0    = (bf16*)(ws + 75497472);         //  2,097,152
        bf16*  Wc1T  = (bf16*)(ws + 77594624);         //  2,097,152
        // persistent tail:
        bf16*  zc    = (bf16*)(ws + 79691776);         //    655,360
        bf16*  BtW1  = (bf16*)(ws + 80347136);         //    163,840
        float* biasf = (float*)(ws + 80510976);        //     13,504
        float* gbuf  = (float*)(ws + 80524480);        //  1,048,576
        float* zbuf  = (float*)(ws + 81573056);        //    524,288
        int*   flag  = (int*)  (ws + 82097344);        //         64
        bf16*  W1t   = (bf16*)(ws + 82097408);         //     16,384
        bf16*  W2t   = (bf16*)(ws + 82113792);         //     65,536
        float* ebias = (float*)(ws + 82179328);        //      1,536

        k_detect<<<1, 64, 0, stream>>>(d_in[5], flag);
        k_prepAll<<<512, 256, 0, stream>>>(flag,
            d_in[6], d_in[7], d_in[8], d_in[9],
            d_in[21], d_in[23], d_in[25], d_in[27], d_in[20],
            d_in[22],
            W1t, W2t, ebias, biasf, BtW1, Wc1T);
        // ---- encoder phase (MFMA) ----
        k_buildA<<<256, 256, 0, stream>>>(flag, (const int*)d_in[0], d_in[1], d_in[5], Abuf);
        k_gemm128<bf16,1><<<dim3(512,2), 256, 0, stream>>>(Abuf, W1t, 32,  ebias,     0, h1, 256);
        k_gemm64<float,1><<<dim3(512,1), 256, 0, stream>>>(h1,   W2t, 256, ebias+256, 0, h2, 128);
        k_pool<<<2048, 128, 0, stream>>>(flag, h2, d_in[10], d_in[11], gbuf);
        // ---- latent ----
        k_latent<<<2048, 64, 0, stream>>>(flag, d_in[2], d_in[4], d_in[3],
            d_in[12], d_in[13], d_in[14], d_in[15],
            d_in[16], d_in[17], d_in[18], d_in[19],
            d_in[28], d_in[29], d_in[30], d_in[31],
            gbuf, zbuf, zc, d_out);
        // ---- conv-as-GEMM phase (Wc2T overwrites encoder buffers; must be after pool) ----
        k_expWc2<<<8192, 256, 0, stream>>>(flag, d_in[24], Wc2T);
        k_gemm128<bf16,0><<<dim3(16,4),  256, 0, stream>>>(zc, BtW1, 160,  biasf,     0, d0,   512);
        k_gemm64<bf16,1><<<dim3(16,16),  256, 0, stream>>>(d0, Wc1T, 512,  biasf+512, 6, c1,   2048);
        k_gemm64<bf16,1><<<dim3(16,64),  256, 0, stream>>>(c1, Wc2T, 2048, biasf+544, 9, Amat, 8192);
        // ---- recon GEMM ----
        k_transW<<<dim3(128,44), 256, 0, stream>>>(flag, d_in[26], BtW2);
        k_gemm64_recon<<<dim3(32,22), 256, 0, stream>>>(flag, Amat, BtW2, biasf, d_out);
        // ---- GAT ----
        k_gat<<<2048, 256, 0, stream>>>(flag, d_in[5],
            d_in[32], d_in[33], d_in[34], d_in[35],
            d_in[36], d_in[37], d_in[38], d_in[39], d_out);
    } else {
        bf16*  Amat = (bf16*)(ws);
        float* gbuf = (float*)(ws + 33554432);
        float* zbuf = (float*)(ws + 34603008);
        int*   flag = (int*)  (ws + 35127296);

        k_detect<<<1, 64, 0, stream>>>(d_in[5], flag);
        k_encoder<<<2048, 256, 0, stream>>>(flag, (const int*)d_in[0], d_in[1], d_in[5],
            d_in[6], d_in[7], d_in[8], d_in[9], d_in[10], d_in[11], gbuf);
        k_latent<<<2048, 64, 0, stream>>>(flag, d_in[2], d_in[4], d_in[3],
            d_in[12], d_in[13], d_in[14], d_in[15],
            d_in[16], d_in[17], d_in[18], d_in[19],
            d_in[28], d_in[29], d_in[30], d_in[31],
            gbuf, zbuf, (bf16*)nullptr, d_out);
        k_conv<<<2048, 256, 0, stream>>>(flag, zbuf, d_in[3],
            d_in[20], d_in[21], d_in[22], d_in[23], d_in[24], d_in[25], Amat);
        k_gemm<<<dim3(16,43), 256, 0, stream>>>(flag, Amat, d_in[26], d_in[27], d_out);
        k_gat<<<2048, 256, 0, stream>>>(flag, d_in[5],
            d_in[32], d_in[33], d_in[34], d_in[35],
            d_in[36], d_in[37], d_in[38], d_in[39], d_out);
    }
}